// Round 4
// baseline (703.107 us; speedup 1.0000x reference)
//
#include <hip/hip_runtime.h>
#include <hip/hip_bf16.h>
#include <math.h>

typedef unsigned short u16;
typedef unsigned int u32;

#define N_NODES 50000
#define N_EDGES 1600000
#define DIM     512
#define DOUT    40
#define MPAD    50048   // 391 * 128
#define NBLK    196     // ceil(N_NODES/256)

typedef __bf16 bf16x8 __attribute__((ext_vector_type(8)));
typedef float  f32x4  __attribute__((ext_vector_type(4)));

__device__ inline float bf2f(u16 u) {
    union { u32 i; float f; } v; v.i = ((u32)u) << 16; return v.f;
}
__device__ inline u16 f2bf(float f) {
    union { float f; u32 u; } v; v.f = f;
    u32 u = v.u;
    u32 r = u + 0x7fffu + ((u >> 16) & 1u);   // RNE
    return (u16)(r >> 16);
}
__device__ inline float2 bfpair(u32 u) {
    float2 r;
    union { u32 i; float f; } lo, hi;
    lo.i = u << 16; hi.i = u & 0xffff0000u;
    r.x = lo.f; r.y = hi.f; return r;
}
__device__ inline float wave_sum(float v) {
    #pragma unroll
    for (int o = 32; o > 0; o >>= 1) v += __shfl_xor(v, o);
    return v;
}
__device__ inline float wave_max(float v) {
    #pragma unroll
    for (int o = 32; o > 0; o >>= 1) v = fmaxf(v, __shfl_xor(v, o));
    return v;
}
__device__ inline int wave_sum_i(int v) {
    #pragma unroll
    for (int o = 32; o > 0; o >>= 1) v += __shfl_xor(v, o);
    return v;
}
#if __has_builtin(__builtin_amdgcn_sdot4)
__device__ inline int dot4(int a, int b, int c) {
    return __builtin_amdgcn_sdot4(a, b, c, false);
}
#else
__device__ inline int dot4(int a, int b, int c) {
    return c + (int)(char)(a) * (int)(char)(b)
             + (int)(char)(a >> 8)  * (int)(char)(b >> 8)
             + (int)(char)(a >> 16) * (int)(char)(b >> 16)
             + (int)(char)(a >> 24) * (int)(char)(b >> 24);
}
#endif
// inclusive scan over a 256-thread block
__device__ inline int block_incl_scan(int v, int tid) {
    int lane = tid & 63, w = tid >> 6;
    #pragma unroll
    for (int o = 1; o < 64; o <<= 1) {
        int t = __shfl_up(v, o);
        if (lane >= o) v += t;
    }
    __shared__ int wsum[4];
    if (lane == 63) wsum[w] = v;
    __syncthreads();
    if (w > 0) v += wsum[0];
    if (w > 1) v += wsum[1];
    if (w > 2) v += wsum[2];
    return v;
}

// ---------------- x f32 -> bf16 (padded rows zeroed) ----------------
__global__ __launch_bounds__(256) void k_conv_x(const float* __restrict__ x,
                                                u16* __restrict__ xb) {
    long idx = (long)blockIdx.x * 256 + threadIdx.x;
    long base = idx * 4;
    if (base >= (long)MPAD * DIM) return;
    long row = base >> 9;  // /512
    float4 v;
    if (row < N_NODES) v = *(const float4*)(x + base);
    else { v.x = v.y = v.z = v.w = 0.f; }
    ushort4 o;
    o.x = f2bf(v.x); o.y = f2bf(v.y); o.z = f2bf(v.z); o.w = f2bf(v.w);
    *(ushort4*)(xb + base) = o;
}

// ---------------- weight transposes ----------------
__global__ __launch_bounds__(256) void k_transpose_bf16(const float* __restrict__ W,
                                                        u16* __restrict__ Wt,
                                                        int K, int N) {
    int n = blockIdx.x * 16 + threadIdx.x;
    int k = blockIdx.y * 16 + threadIdx.y;
    if (k < K && n < N) Wt[(long)n * K + k] = f2bf(W[(long)k * N + n]);
}
// cW2 [512][40] f32 -> W2b [48][512] bf16, rows 40..47 zeroed
__global__ __launch_bounds__(256) void k_prep_w2(const float* __restrict__ cW2,
                                                 u16* __restrict__ W2b) {
    int idx = blockIdx.x * 256 + threadIdx.x;   // 0 .. 48*512-1
    if (idx >= 48 * DIM) return;
    int n = idx >> 9;        // out col (0..47)
    int k = idx & 511;       // in dim
    float v = (n < DOUT) ? cW2[(long)k * DOUT + n] : 0.f;
    W2b[idx] = f2bf(v);
}

// ---------------- degree / dinv ----------------
__global__ __launch_bounds__(256) void k_deg(const int* __restrict__ esrc, int* __restrict__ deg) {
    int e = blockIdx.x * 256 + threadIdx.x;
    if (e < N_EDGES) atomicAdd(&deg[esrc[e]], 1);
}
__global__ __launch_bounds__(256) void k_dinv(const int* __restrict__ deg, float* __restrict__ dinv) {
    int i = blockIdx.x * 256 + threadIdx.x;
    if (i < N_NODES) {
        int d = deg[i];
        dinv[i] = (d > 0) ? (1.0f / sqrtf((float)d)) : 0.0f;
    }
}

// ---------------- CSR build: psum -> pbase -> rowptr -> scatter ----------------
__global__ __launch_bounds__(256) void k_csr_partial(const int* __restrict__ deg,
                                                     int* __restrict__ psum) {
    int idx = blockIdx.x * 256 + threadIdx.x;
    int v = (idx < N_NODES) ? deg[idx] : 0;
    int t = wave_sum_i(v);
    __shared__ int ws[4];
    int lane = threadIdx.x & 63, w = threadIdx.x >> 6;
    if (lane == 0) ws[w] = t;
    __syncthreads();
    if (threadIdx.x == 0) psum[blockIdx.x] = ws[0] + ws[1] + ws[2] + ws[3];
}
__global__ __launch_bounds__(256) void k_csr_base(const int* __restrict__ psum,
                                                  int* __restrict__ pbase,
                                                  int* __restrict__ rowptr) {
    int tid = threadIdx.x;
    int v = (tid < NBLK) ? psum[tid] : 0;
    int incl = block_incl_scan(v, tid);
    if (tid < NBLK) pbase[tid] = incl - v;   // exclusive
    if (tid == 0) rowptr[N_NODES] = N_EDGES;
}
__global__ __launch_bounds__(256) void k_csr_rowptr(const int* __restrict__ deg,
                                                    const int* __restrict__ pbase,
                                                    int* __restrict__ rowptr,
                                                    int* __restrict__ cnt) {
    int idx = blockIdx.x * 256 + threadIdx.x;
    int v = (idx < N_NODES) ? deg[idx] : 0;
    int incl = block_incl_scan(v, threadIdx.x);
    if (idx < N_NODES) {
        rowptr[idx] = pbase[blockIdx.x] + incl - v;
        cnt[idx] = 0;
    }
}
__global__ __launch_bounds__(256) void k_scatter(const int* __restrict__ esrc,
                                                 const int* __restrict__ edst,
                                                 const int* __restrict__ rowptr,
                                                 int* __restrict__ cnt,
                                                 int* __restrict__ edst_s) {
    int e = blockIdx.x * 256 + threadIdx.x;
    if (e >= N_EDGES) return;
    int s = esrc[e];
    int pos = rowptr[s] + atomicAdd(&cnt[s], 1);
    edst_s[pos] = edst[e];
}

// ---------------- bf16 MFMA GEMM: out = epilogue(A @ Bt^T) ----------------
template<int EPI>
__global__ __launch_bounds__(256) void k_gemm(const u16* __restrict__ A,
                                              const u16* __restrict__ Bt,
                                              u16* __restrict__ outB,
                                              const float* __restrict__ bias,
                                              const float* __restrict__ bn_g,
                                              const float* __restrict__ bn_b,
                                              const float* __restrict__ bn_mean,
                                              const float* __restrict__ bn_var) {
    __shared__ u16 lds[2 * 128 * 64];  // 32 KB: A tile then B tile
    char* ldsA = (char*)lds;
    char* ldsB = (char*)lds + 16384;

    const int tid = threadIdx.x;
    const int tm = blockIdx.x, tn = blockIdx.y;
    const int l = tid & 63, wid = tid >> 6;
    const int wr = wid >> 1, wc = wid & 1;
    const int lm = l & 15, lk = l >> 4;

    const int srow0 = tid >> 3;            // staging row base (0..31)
    const int scole = (tid & 7) * 8;       // staging elem col (0..56)
    const int scolb = scole * 2;           // byte col

    f32x4 acc[4][4] = {};

    for (int kt = 0; kt < 8; ++kt) {
        const int k0 = kt * 64;
        #pragma unroll
        for (int r = 0; r < 4; ++r) {
            int row = r * 32 + srow0;
            uint4 va = *(const uint4*)(A + ((long)tm * 128 + row) * DIM + k0 + scole);
            *(uint4*)(ldsA + row * 128 + (scolb ^ ((row & 7) << 4))) = va;
            uint4 vb = *(const uint4*)(Bt + ((long)tn * 128 + row) * DIM + k0 + scole);
            *(uint4*)(ldsB + row * 128 + (scolb ^ ((row & 7) << 4))) = vb;
        }
        __syncthreads();
        #pragma unroll
        for (int kk = 0; kk < 2; ++kk) {
            bf16x8 af[4], bfr[4];
            #pragma unroll
            for (int m = 0; m < 4; ++m) {
                int ar = wr * 64 + m * 16 + lm;
                af[m] = *(const bf16x8*)(ldsA + ar * 128 + ((kk * 64 + lk * 16) ^ ((ar & 7) << 4)));
            }
            #pragma unroll
            for (int n = 0; n < 4; ++n) {
                int br = wc * 64 + n * 16 + lm;
                bfr[n] = *(const bf16x8*)(ldsB + br * 128 + ((kk * 64 + lk * 16) ^ ((br & 7) << 4)));
            }
            #pragma unroll
            for (int m = 0; m < 4; ++m)
                #pragma unroll
                for (int n = 0; n < 4; ++n)
                    acc[m][n] = __builtin_amdgcn_mfma_f32_16x16x32_bf16(af[m], bfr[n], acc[m][n], 0, 0, 0);
        }
        __syncthreads();
    }

    #pragma unroll
    for (int n = 0; n < 4; ++n) {
        int col = tn * 128 + wc * 64 + n * 16 + lm;
        float bc = bias[col];
        float scale = 0.f, shift = 0.f;
        if (EPI == 1) {
            scale = bn_g[col] / sqrtf(bn_var[col] + 1e-5f);
            shift = bn_b[col] - bn_mean[col] * scale;
        }
        #pragma unroll
        for (int m = 0; m < 4; ++m) {
            f32x4 v = acc[m][n];
            #pragma unroll
            for (int r = 0; r < 4; ++r) {
                long row = (long)tm * 128 + wr * 64 + m * 16 + lk * 4 + r;
                float val = fmaxf(v[r] + bc, 0.f);
                if (EPI == 1) val = val * scale + shift;
                outB[row * DIM + col] = f2bf(val);
            }
        }
    }
}

// ---------------- LayerNorm (in-place on hb) + int8-quantized normalized row ----------------
// hq[row][512] int8 (dims 0,1 zeroed), stepr[row] = dequant step, a0/a1/invn f32.
__global__ __launch_bounds__(256) void k_ln(u16* __restrict__ hb,
                                            char* __restrict__ hq,
                                            float* __restrict__ stepr,
                                            const float* __restrict__ g,
                                            const float* __restrict__ b,
                                            float* __restrict__ a0,
                                            float* __restrict__ a1,
                                            float* __restrict__ inv_nrm) {
    int row = blockIdx.x * 4 + (threadIdx.x >> 6);
    int l = threadIdx.x & 63;
    u16* prow = hb + (long)row * DIM + l * 8;
    if (row >= N_NODES) {
        if (row < MPAD) { uint4 z; z.x = z.y = z.z = z.w = 0u; *(uint4*)prow = z; }
        return;
    }
    uint4 v = *(const uint4*)prow;
    float x[8];
    { float2 p;
      p = bfpair(v.x); x[0] = p.x; x[1] = p.y;
      p = bfpair(v.y); x[2] = p.x; x[3] = p.y;
      p = bfpair(v.z); x[4] = p.x; x[5] = p.y;
      p = bfpair(v.w); x[6] = p.x; x[7] = p.y; }
    float s = 0.f, sq = 0.f;
    #pragma unroll
    for (int j = 0; j < 8; ++j) { s += x[j]; sq += x[j] * x[j]; }
    #pragma unroll
    for (int o = 32; o > 0; o >>= 1) { s += __shfl_xor(s, o); sq += __shfl_xor(sq, o); }
    float mean = s * (1.f / DIM);
    float var = sq * (1.f / DIM) - mean * mean;
    float rstd = 1.f / sqrtf(var + 1e-5f);
    float y[8];
    #pragma unroll
    for (int j = 0; j < 8; ++j) {
        int c = l * 8 + j;
        y[j] = (x[j] - mean) * rstd * g[c] + b[c];
    }
    float s2 = 0.f;
    #pragma unroll
    for (int j = 0; j < 8; ++j) s2 += y[j] * y[j];
    s2 = wave_sum(s2);
    float nrm = sqrtf(s2);
    float inv = 1.f / (nrm + 1e-4f);
    // write LN output (bf16) for GEMM2
    ushort4 oh;
    oh.x = f2bf(y[0]); oh.y = f2bf(y[1]); oh.z = f2bf(y[2]); oh.w = f2bf(y[3]);
    *(ushort4*)prow = oh;
    oh.x = f2bf(y[4]); oh.y = f2bf(y[5]); oh.z = f2bf(y[6]); oh.w = f2bf(y[7]);
    *(ushort4*)(prow + 4) = oh;
    // quantize normalized row to int8 with per-row scale
    float nv[8];
    float mx = 0.f;
    #pragma unroll
    for (int j = 0; j < 8; ++j) { nv[j] = y[j] * inv; mx = fmaxf(mx, fabsf(nv[j])); }
    mx = wave_max(mx);
    float qs = (mx > 0.f) ? (127.f / mx) : 0.f;
    if (l == 0) { nv[0] = 0.f; nv[1] = 0.f; }   // exclude dims 0,1 from rest
    u32 w0 = 0, w1 = 0;
    #pragma unroll
    for (int j = 0; j < 4; ++j) {
        int q = (int)rintf(nv[j] * qs);
        w0 |= ((u32)(q & 0xff)) << (8 * j);
    }
    #pragma unroll
    for (int j = 0; j < 4; ++j) {
        int q = (int)rintf(nv[4 + j] * qs);
        w1 |= ((u32)(q & 0xff)) << (8 * j);
    }
    uint2 wq; wq.x = w0; wq.y = w1;
    *(uint2*)(hq + (long)row * DIM + l * 8) = wq;
    if (l == 0) {
        stepr[row] = (mx > 0.f) ? (mx * (1.f / 127.f)) : 0.f;
        a0[row] = y[0]; a1[row] = y[1]; inv_nrm[row] = inv;
    }
}

// ---------------- per-edge partial dot over dims 2..511, int8, CSR order ----------------
__global__ __launch_bounds__(256) void k_edge_dot(const int* __restrict__ rowptr,
                                                  const int* __restrict__ edst_s,
                                                  const char* __restrict__ hq,
                                                  const float* __restrict__ stepr,
                                                  float* __restrict__ rest) {
    int node = blockIdx.x * 4 + (threadIdx.x >> 6);
    if (node >= N_NODES) return;
    int l = threadIdx.x & 63;
    int p0 = rowptr[node], p1 = rowptr[node + 1];
    if (p0 == p1) return;
    int2 sa = *(const int2*)(hq + (long)node * DIM + l * 8);
    float ss = stepr[node];
    #pragma unroll 2
    for (int p = p0; p < p1; ++p) {
        int d = edst_s[p];
        int2 da = *(const int2*)(hq + (long)d * DIM + l * 8);
        int acc = dot4(sa.y, da.y, dot4(sa.x, da.x, 0));
        acc = wave_sum_i(acc);
        if (l == 0) rest[p] = ss * stepr[d] * (float)acc;
    }
}

// ---------------- fused per-layer: segment-sum + rotate ----------------
template<int WRITE_HB>
__global__ __launch_bounds__(256) void k_layer(const int* __restrict__ rowptr,
                                               const int* __restrict__ edst_s,
                                               const float* __restrict__ rest,
                                               const float* __restrict__ a0i,
                                               const float* __restrict__ a1i,
                                               const float* __restrict__ invn,
                                               const float* __restrict__ dinv,
                                               float* __restrict__ a0o,
                                               float* __restrict__ a1o,
                                               u16* __restrict__ hb) {
    int node = blockIdx.x * 4 + (threadIdx.x >> 6);
    if (node >= N_NODES) return;
    int l = threadIdx.x & 63;
    int p0 = rowptr[node], p1 = rowptr[node + 1];
    float x = a0i[node], y = a1i[node];
    float si = invn[node];
    float sa0 = x * si, sa1 = y * si;
    float accum = 0.f;
    for (int p = p0 + l; p < p1; p += 64) {
        int d = edst_s[p];
        float c = rest[p] + (sa0 * a0i[d] + sa1 * a1i[d]) * invn[d];
        c = fminf(1.f, fmaxf(-1.f, c));
        accum += dinv[d] * c;
    }
    accum = wave_sum(accum);
    if (l == 0) {
        float ang = dinv[node] * accum;
        float sn, cs;
        sincosf(ang, &sn, &cs);
        float r0 = cs * x - sn * y;
        float r1 = sn * x + cs * y;
        a0o[node] = r0;
        a1o[node] = r1;
        if (WRITE_HB) {
            hb[(long)node * DIM + 0] = f2bf(r0);
            hb[(long)node * DIM + 1] = f2bf(r1);
        }
    }
}

// ---------------- final: logits (MFMA skinny GEMM) + log_softmax ----------------
__global__ __launch_bounds__(256) void k_final(const u16* __restrict__ zb,
                                               const u16* __restrict__ W2b,
                                               const float* __restrict__ cb2,
                                               float* __restrict__ out) {
    __shared__ char ldsB[48 * 1024];   // 48 KB, XOR-swizzled rows
    const int tid = threadIdx.x;
    #pragma unroll
    for (int i = 0; i < 12; ++i) {
        int unit = i * 256 + tid;          // 3072 x 16B units
        int byte = unit * 16;
        int row = byte >> 10;
        int colb = byte & 1023;
        uint4 v = *(const uint4*)((const char*)W2b + byte);
        *(uint4*)(ldsB + row * 1024 + (colb ^ ((row & 7) << 4))) = v;
    }
    __syncthreads();

    const int l = tid & 63, wid = tid >> 6;
    const int lm = l & 15, lk = l >> 4;
    const long m0 = (long)blockIdx.x * 128 + wid * 32;

    f32x4 acc[2][3] = {};
    for (int kt = 0; kt < 16; ++kt) {
        const int k0 = kt * 32;
        bf16x8 af[2], bfr[3];
        #pragma unroll
        for (int m = 0; m < 2; ++m)
            af[m] = *(const bf16x8*)(zb + (m0 + m * 16 + lm) * DIM + k0 + lk * 8);
        #pragma unroll
        for (int n = 0; n < 3; ++n) {
            int br = n * 16 + lm;
            bfr[n] = *(const bf16x8*)(ldsB + br * 1024 + ((k0 * 2 + lk * 16) ^ ((br & 7) << 4)));
        }
        #pragma unroll
        for (int m = 0; m < 2; ++m)
            #pragma unroll
            for (int n = 0; n < 3; ++n)
                acc[m][n] = __builtin_amdgcn_mfma_f32_16x16x32_bf16(af[m], bfr[n], acc[m][n], 0, 0, 0);
    }

    float bc[3];
    #pragma unroll
    for (int n = 0; n < 3; ++n) {
        int col = n * 16 + lm;
        bc[n] = (col < DOUT) ? cb2[col] : 0.f;
    }

    #pragma unroll
    for (int m = 0; m < 2; ++m) {
        #pragma unroll
        for (int r = 0; r < 4; ++r) {
            long row = m0 + m * 16 + lk * 4 + r;
            float v[3];
            float mv = -1e30f;
            #pragma unroll
            for (int n = 0; n < 3; ++n) {
                int col = n * 16 + lm;
                float t = (col < DOUT) ? (acc[m][n][r] + bc[n]) : -1e30f;
                v[n] = t;
                mv = fmaxf(mv, t);
            }
            #pragma unroll
            for (int o = 8; o > 0; o >>= 1) mv = fmaxf(mv, __shfl_xor(mv, o));
            float es = 0.f;
            #pragma unroll
            for (int n = 0; n < 3; ++n) {
                int col = n * 16 + lm;
                if (col < DOUT) es += expf(v[n] - mv);
            }
            #pragma unroll
            for (int o = 8; o > 0; o >>= 1) es += __shfl_xor(es, o);
            float lse = logf(es);
            if (row < N_NODES) {
                #pragma unroll
                for (int n = 0; n < 3; ++n) {
                    int col = n * 16 + lm;
                    if (col < DOUT) out[row * DOUT + col] = v[n] - mv - lse;
                }
            }
        }
    }
}

extern "C" void kernel_launch(void* const* d_in, const int* in_sizes, int n_in,
                              void* d_out, int out_size, void* d_ws, size_t ws_size,
                              hipStream_t stream) {
    const float* x       = (const float*)d_in[0];
    const int*   esrc    = (const int*)d_in[1];
    const int*   edst    = (const int*)d_in[2];
    const float* W_in    = (const float*)d_in[3];
    const float* b_in    = (const float*)d_in[4];
    const float* ln_g    = (const float*)d_in[5];
    const float* ln_b    = (const float*)d_in[6];
    const float* cW1     = (const float*)d_in[7];
    const float* cb1     = (const float*)d_in[8];
    const float* bn_g    = (const float*)d_in[9];
    const float* bn_b    = (const float*)d_in[10];
    const float* bn_mean = (const float*)d_in[11];
    const float* bn_var  = (const float*)d_in[12];
    const float* cW2     = (const float*)d_in[13];
    const float* cb2     = (const float*)d_in[14];
    float* out = (float*)d_out;

    char* ws = (char*)d_ws;
    size_t off = 0;
    auto take = [&](size_t bytes) -> char* {
        char* p = ws + off;
        off = (off + bytes + 255) & ~(size_t)255;
        return p;
    };
    u16*   xb     = (u16*)take((size_t)MPAD * DIM * 2);   // later reused as zb
    u16*   hb     = (u16*)take((size_t)MPAD * DIM * 2);
    char*  hq     = (char*)take((size_t)N_NODES * DIM);
    float* stepr  = (float*)take((size_t)N_NODES * 4);
    u16*   WtIn   = (u16*)take((size_t)512 * 512 * 2);
    u16*   W1t    = (u16*)take((size_t)512 * 512 * 2);
    u16*   W2b    = (u16*)take((size_t)48 * 512 * 2);
    int*   deg    = (int*)take((size_t)N_NODES * 4);
    float* dinv   = (float*)take((size_t)N_NODES * 4);
    float* a0A    = (float*)take((size_t)N_NODES * 4);
    float* a1A    = (float*)take((size_t)N_NODES * 4);
    float* a0B    = (float*)take((size_t)N_NODES * 4);
    float* a1B    = (float*)take((size_t)N_NODES * 4);
    float* invn   = (float*)take((size_t)N_NODES * 4);
    float* rest   = (float*)take((size_t)N_EDGES * 4);
    int*   rowptr = (int*)take((size_t)(N_NODES + 1) * 4);
    int*   cnt    = (int*)take((size_t)N_NODES * 4);
    int*   edst_s = (int*)take((size_t)N_EDGES * 4);
    int*   psum   = (int*)take((size_t)NBLK * 4);
    int*   pbase  = (int*)take((size_t)NBLK * 4);
    u16*   zb     = xb;

    hipMemsetAsync(deg, 0, (size_t)N_NODES * 4, stream);

    k_conv_x<<<(MPAD * DIM / 4 + 255) / 256, 256, 0, stream>>>(x, xb);
    k_transpose_bf16<<<dim3(32, 32), dim3(16, 16), 0, stream>>>(W_in, WtIn, 512, 512);
    k_transpose_bf16<<<dim3(32, 32), dim3(16, 16), 0, stream>>>(cW1, W1t, 512, 512);
    k_prep_w2<<<(48 * DIM + 255) / 256, 256, 0, stream>>>(cW2, W2b);

    k_deg<<<N_EDGES / 256, 256, 0, stream>>>(esrc, deg);
    k_dinv<<<(N_NODES + 255) / 256, 256, 0, stream>>>(deg, dinv);
    k_csr_partial<<<NBLK, 256, 0, stream>>>(deg, psum);
    k_csr_base<<<1, 256, 0, stream>>>(psum, pbase, rowptr);
    k_csr_rowptr<<<NBLK, 256, 0, stream>>>(deg, pbase, rowptr, cnt);
    k_scatter<<<N_EDGES / 256, 256, 0, stream>>>(esrc, edst, rowptr, cnt, edst_s);

    k_gemm<0><<<dim3(MPAD / 128, 4), 256, 0, stream>>>(xb, WtIn, hb, b_in,
                                                       nullptr, nullptr, nullptr, nullptr);
    k_ln<<<MPAD / 4, 256, 0, stream>>>(hb, hq, stepr, ln_g, ln_b, a0A, a1A, invn);
    k_edge_dot<<<(N_NODES + 3) / 4, 256, 0, stream>>>(rowptr, edst_s, hq, stepr, rest);

    k_layer<0><<<(N_NODES + 3) / 4, 256, 0, stream>>>(rowptr, edst_s, rest,
                                                      a0A, a1A, invn, dinv, a0B, a1B, nullptr);
    k_layer<0><<<(N_NODES + 3) / 4, 256, 0, stream>>>(rowptr, edst_s, rest,
                                                      a0B, a1B, invn, dinv, a0A, a1A, nullptr);
    k_layer<1><<<(N_NODES + 3) / 4, 256, 0, stream>>>(rowptr, edst_s, rest,
                                                      a0A, a1A, invn, dinv, a0B, a1B, hb);

    k_gemm<1><<<dim3(MPAD / 128, 4), 256, 0, stream>>>(hb, W1t, zb, cb1,
                                                       bn_g, bn_b, bn_mean, bn_var);
    k_final<<<MPAD / 128, 256, 0, stream>>>(zb, W2b, cb2, out);
}

// Round 5
// 540.706 us; speedup vs baseline: 1.3003x; 1.3003x over previous
//
#include <hip/hip_runtime.h>
#include <hip/hip_bf16.h>
#include <math.h>

typedef unsigned short u16;
typedef unsigned int u32;

#define N_NODES 50000
#define N_EDGES 1600000
#define DIM     512
#define DOUT    40
#define MPAD    50048   // 391 * 128
#define NBLK    196     // ceil(N_NODES/256)

typedef __bf16 bf16x8 __attribute__((ext_vector_type(8)));
typedef float  f32x4  __attribute__((ext_vector_type(4)));

__device__ inline float bf2f(u16 u) {
    union { u32 i; float f; } v; v.i = ((u32)u) << 16; return v.f;
}
__device__ inline u16 f2bf(float f) {
    union { float f; u32 u; } v; v.f = f;
    u32 u = v.u;
    u32 r = u + 0x7fffu + ((u >> 16) & 1u);   // RNE
    return (u16)(r >> 16);
}
__device__ inline float2 bfpair(u32 u) {
    float2 r;
    union { u32 i; float f; } lo, hi;
    lo.i = u << 16; hi.i = u & 0xffff0000u;
    r.x = lo.f; r.y = hi.f; return r;
}
__device__ inline float wave_sum(float v) {
    #pragma unroll
    for (int o = 32; o > 0; o >>= 1) v += __shfl_xor(v, o);
    return v;
}
__device__ inline float wave_max(float v) {
    #pragma unroll
    for (int o = 32; o > 0; o >>= 1) v = fmaxf(v, __shfl_xor(v, o));
    return v;
}
__device__ inline int wave_sum_i(int v) {
    #pragma unroll
    for (int o = 32; o > 0; o >>= 1) v += __shfl_xor(v, o);
    return v;
}
#if __has_builtin(__builtin_amdgcn_sdot4)
__device__ inline int dot4(int a, int b, int c) {
    return __builtin_amdgcn_sdot4(a, b, c, false);
}
#else
__device__ inline int dot4(int a, int b, int c) {
    return c + (int)(char)(a) * (int)(char)(b)
             + (int)(char)(a >> 8)  * (int)(char)(b >> 8)
             + (int)(char)(a >> 16) * (int)(char)(b >> 16)
             + (int)(char)(a >> 24) * (int)(char)(b >> 24);
}
#endif
// inclusive scan over a 256-thread block
__device__ inline int block_incl_scan(int v, int tid) {
    int lane = tid & 63, w = tid >> 6;
    #pragma unroll
    for (int o = 1; o < 64; o <<= 1) {
        int t = __shfl_up(v, o);
        if (lane >= o) v += t;
    }
    __shared__ int wsum[4];
    if (lane == 63) wsum[w] = v;
    __syncthreads();
    if (w > 0) v += wsum[0];
    if (w > 1) v += wsum[1];
    if (w > 2) v += wsum[2];
    return v;
}

// ---------------- x f32 -> bf16 (padded rows zeroed) ----------------
__global__ __launch_bounds__(256) void k_conv_x(const float* __restrict__ x,
                                                u16* __restrict__ xb) {
    long idx = (long)blockIdx.x * 256 + threadIdx.x;
    long base = idx * 4;
    if (base >= (long)MPAD * DIM) return;
    long row = base >> 9;  // /512
    float4 v;
    if (row < N_NODES) v = *(const float4*)(x + base);
    else { v.x = v.y = v.z = v.w = 0.f; }
    ushort4 o;
    o.x = f2bf(v.x); o.y = f2bf(v.y); o.z = f2bf(v.z); o.w = f2bf(v.w);
    *(ushort4*)(xb + base) = o;
}

// ---------------- weight transposes ----------------
__global__ __launch_bounds__(256) void k_transpose_bf16(const float* __restrict__ W,
                                                        u16* __restrict__ Wt,
                                                        int K, int N) {
    int n = blockIdx.x * 16 + threadIdx.x;
    int k = blockIdx.y * 16 + threadIdx.y;
    if (k < K && n < N) Wt[(long)n * K + k] = f2bf(W[(long)k * N + n]);
}
// cW2 [512][40] f32 -> W2b [48][512] bf16, rows 40..47 zeroed
__global__ __launch_bounds__(256) void k_prep_w2(const float* __restrict__ cW2,
                                                 u16* __restrict__ W2b) {
    int idx = blockIdx.x * 256 + threadIdx.x;   // 0 .. 48*512-1
    if (idx >= 48 * DIM) return;
    int n = idx >> 9;        // out col (0..47)
    int k = idx & 511;       // in dim
    float v = (n < DOUT) ? cW2[(long)k * DOUT + n] : 0.f;
    W2b[idx] = f2bf(v);
}

// ---------------- degree / dinv ----------------
__global__ __launch_bounds__(256) void k_deg(const int* __restrict__ esrc, int* __restrict__ deg) {
    int e = blockIdx.x * 256 + threadIdx.x;
    if (e < N_EDGES) atomicAdd(&deg[esrc[e]], 1);
}
__global__ __launch_bounds__(256) void k_dinv(const int* __restrict__ deg, float* __restrict__ dinv) {
    int i = blockIdx.x * 256 + threadIdx.x;
    if (i < N_NODES) {
        int d = deg[i];
        dinv[i] = (d > 0) ? (1.0f / sqrtf((float)d)) : 0.0f;
    }
}

// ---------------- CSR build: psum -> pbase -> rowptr -> scatter ----------------
__global__ __launch_bounds__(256) void k_csr_partial(const int* __restrict__ deg,
                                                     int* __restrict__ psum) {
    int idx = blockIdx.x * 256 + threadIdx.x;
    int v = (idx < N_NODES) ? deg[idx] : 0;
    int t = wave_sum_i(v);
    __shared__ int ws[4];
    int lane = threadIdx.x & 63, w = threadIdx.x >> 6;
    if (lane == 0) ws[w] = t;
    __syncthreads();
    if (threadIdx.x == 0) psum[blockIdx.x] = ws[0] + ws[1] + ws[2] + ws[3];
}
__global__ __launch_bounds__(256) void k_csr_base(const int* __restrict__ psum,
                                                  int* __restrict__ pbase,
                                                  int* __restrict__ rowptr) {
    int tid = threadIdx.x;
    int v = (tid < NBLK) ? psum[tid] : 0;
    int incl = block_incl_scan(v, tid);
    if (tid < NBLK) pbase[tid] = incl - v;   // exclusive
    if (tid == 0) rowptr[N_NODES] = N_EDGES;
}
__global__ __launch_bounds__(256) void k_csr_rowptr(const int* __restrict__ deg,
                                                    const int* __restrict__ pbase,
                                                    int* __restrict__ rowptr,
                                                    int* __restrict__ cnt) {
    int idx = blockIdx.x * 256 + threadIdx.x;
    int v = (idx < N_NODES) ? deg[idx] : 0;
    int incl = block_incl_scan(v, threadIdx.x);
    if (idx < N_NODES) {
        rowptr[idx] = pbase[blockIdx.x] + incl - v;
        cnt[idx] = 0;
    }
}
__global__ __launch_bounds__(256) void k_scatter(const int* __restrict__ esrc,
                                                 const int* __restrict__ edst,
                                                 const int* __restrict__ rowptr,
                                                 int* __restrict__ cnt,
                                                 int* __restrict__ edst_s) {
    int e = blockIdx.x * 256 + threadIdx.x;
    if (e >= N_EDGES) return;
    int s = esrc[e];
    int pos = rowptr[s] + atomicAdd(&cnt[s], 1);
    edst_s[pos] = edst[e];
}

// ---------------- bf16 MFMA GEMM: out = epilogue(A @ Bt^T) ----------------
template<int EPI>
__global__ __launch_bounds__(256) void k_gemm(const u16* __restrict__ A,
                                              const u16* __restrict__ Bt,
                                              u16* __restrict__ outB,
                                              const float* __restrict__ bias,
                                              const float* __restrict__ bn_g,
                                              const float* __restrict__ bn_b,
                                              const float* __restrict__ bn_mean,
                                              const float* __restrict__ bn_var) {
    __shared__ u16 lds[2 * 128 * 64];  // 32 KB: A tile then B tile
    char* ldsA = (char*)lds;
    char* ldsB = (char*)lds + 16384;

    const int tid = threadIdx.x;
    const int tm = blockIdx.x, tn = blockIdx.y;
    const int l = tid & 63, wid = tid >> 6;
    const int wr = wid >> 1, wc = wid & 1;
    const int lm = l & 15, lk = l >> 4;

    const int srow0 = tid >> 3;            // staging row base (0..31)
    const int scole = (tid & 7) * 8;       // staging elem col (0..56)
    const int scolb = scole * 2;           // byte col

    f32x4 acc[4][4] = {};

    for (int kt = 0; kt < 8; ++kt) {
        const int k0 = kt * 64;
        #pragma unroll
        for (int r = 0; r < 4; ++r) {
            int row = r * 32 + srow0;
            uint4 va = *(const uint4*)(A + ((long)tm * 128 + row) * DIM + k0 + scole);
            *(uint4*)(ldsA + row * 128 + (scolb ^ ((row & 7) << 4))) = va;
            uint4 vb = *(const uint4*)(Bt + ((long)tn * 128 + row) * DIM + k0 + scole);
            *(uint4*)(ldsB + row * 128 + (scolb ^ ((row & 7) << 4))) = vb;
        }
        __syncthreads();
        #pragma unroll
        for (int kk = 0; kk < 2; ++kk) {
            bf16x8 af[4], bfr[4];
            #pragma unroll
            for (int m = 0; m < 4; ++m) {
                int ar = wr * 64 + m * 16 + lm;
                af[m] = *(const bf16x8*)(ldsA + ar * 128 + ((kk * 64 + lk * 16) ^ ((ar & 7) << 4)));
            }
            #pragma unroll
            for (int n = 0; n < 4; ++n) {
                int br = wc * 64 + n * 16 + lm;
                bfr[n] = *(const bf16x8*)(ldsB + br * 128 + ((kk * 64 + lk * 16) ^ ((br & 7) << 4)));
            }
            #pragma unroll
            for (int m = 0; m < 4; ++m)
                #pragma unroll
                for (int n = 0; n < 4; ++n)
                    acc[m][n] = __builtin_amdgcn_mfma_f32_16x16x32_bf16(af[m], bfr[n], acc[m][n], 0, 0, 0);
        }
        __syncthreads();
    }

    #pragma unroll
    for (int n = 0; n < 4; ++n) {
        int col = tn * 128 + wc * 64 + n * 16 + lm;
        float bc = bias[col];
        float scale = 0.f, shift = 0.f;
        if (EPI == 1) {
            scale = bn_g[col] / sqrtf(bn_var[col] + 1e-5f);
            shift = bn_b[col] - bn_mean[col] * scale;
        }
        #pragma unroll
        for (int m = 0; m < 4; ++m) {
            f32x4 v = acc[m][n];
            #pragma unroll
            for (int r = 0; r < 4; ++r) {
                long row = (long)tm * 128 + wr * 64 + m * 16 + lk * 4 + r;
                float val = fmaxf(v[r] + bc, 0.f);
                if (EPI == 1) val = val * scale + shift;
                outB[row * DIM + col] = f2bf(val);
            }
        }
    }
}

// ---------------- LayerNorm (in-place on hb) + int8-quantized normalized row ----------------
// hq[row][512] int8 (dims 0,1 zeroed), stepr[row] = dequant step, a0/a1/invn f32.
__global__ __launch_bounds__(256) void k_ln(u16* __restrict__ hb,
                                            char* __restrict__ hq,
                                            float* __restrict__ stepr,
                                            const float* __restrict__ g,
                                            const float* __restrict__ b,
                                            float* __restrict__ a0,
                                            float* __restrict__ a1,
                                            float* __restrict__ inv_nrm) {
    int row = blockIdx.x * 4 + (threadIdx.x >> 6);
    int l = threadIdx.x & 63;
    u16* prow = hb + (long)row * DIM + l * 8;
    if (row >= N_NODES) {
        if (row < MPAD) { uint4 z; z.x = z.y = z.z = z.w = 0u; *(uint4*)prow = z; }
        return;
    }
    uint4 v = *(const uint4*)prow;
    float x[8];
    { float2 p;
      p = bfpair(v.x); x[0] = p.x; x[1] = p.y;
      p = bfpair(v.y); x[2] = p.x; x[3] = p.y;
      p = bfpair(v.z); x[4] = p.x; x[5] = p.y;
      p = bfpair(v.w); x[6] = p.x; x[7] = p.y; }
    float s = 0.f, sq = 0.f;
    #pragma unroll
    for (int j = 0; j < 8; ++j) { s += x[j]; sq += x[j] * x[j]; }
    #pragma unroll
    for (int o = 32; o > 0; o >>= 1) { s += __shfl_xor(s, o); sq += __shfl_xor(sq, o); }
    float mean = s * (1.f / DIM);
    float var = sq * (1.f / DIM) - mean * mean;
    float rstd = 1.f / sqrtf(var + 1e-5f);
    float y[8];
    #pragma unroll
    for (int j = 0; j < 8; ++j) {
        int c = l * 8 + j;
        y[j] = (x[j] - mean) * rstd * g[c] + b[c];
    }
    float s2 = 0.f;
    #pragma unroll
    for (int j = 0; j < 8; ++j) s2 += y[j] * y[j];
    s2 = wave_sum(s2);
    float nrm = sqrtf(s2);
    float inv = 1.f / (nrm + 1e-4f);
    // write LN output (bf16) for GEMM2
    ushort4 oh;
    oh.x = f2bf(y[0]); oh.y = f2bf(y[1]); oh.z = f2bf(y[2]); oh.w = f2bf(y[3]);
    *(ushort4*)prow = oh;
    oh.x = f2bf(y[4]); oh.y = f2bf(y[5]); oh.z = f2bf(y[6]); oh.w = f2bf(y[7]);
    *(ushort4*)(prow + 4) = oh;
    // quantize normalized row to int8 with per-row scale
    float nv[8];
    float mx = 0.f;
    #pragma unroll
    for (int j = 0; j < 8; ++j) { nv[j] = y[j] * inv; mx = fmaxf(mx, fabsf(nv[j])); }
    mx = wave_max(mx);
    float qs = (mx > 0.f) ? (127.f / mx) : 0.f;
    if (l == 0) { nv[0] = 0.f; nv[1] = 0.f; }   // exclude dims 0,1 from rest
    u32 w0 = 0, w1 = 0;
    #pragma unroll
    for (int j = 0; j < 4; ++j) {
        int q = (int)rintf(nv[j] * qs);
        w0 |= ((u32)(q & 0xff)) << (8 * j);
    }
    #pragma unroll
    for (int j = 0; j < 4; ++j) {
        int q = (int)rintf(nv[4 + j] * qs);
        w1 |= ((u32)(q & 0xff)) << (8 * j);
    }
    uint2 wq; wq.x = w0; wq.y = w1;
    *(uint2*)(hq + (long)row * DIM + l * 8) = wq;
    if (l == 0) {
        stepr[row] = (mx > 0.f) ? (mx * (1.f / 127.f)) : 0.f;
        a0[row] = y[0]; a1[row] = y[1]; inv_nrm[row] = inv;
    }
}

// ---------------- per-edge partial dot over dims 2..511, int8, CSR order ----------------
// wave per src node; 4 edges per iteration, 16 lanes per edge (8 gathers in flight).
__global__ __launch_bounds__(256) void k_edge_dot(const int* __restrict__ rowptr,
                                                  const int* __restrict__ edst_s,
                                                  const char* __restrict__ hq,
                                                  const float* __restrict__ stepr,
                                                  float* __restrict__ rest) {
    int node = blockIdx.x * 4 + (threadIdx.x >> 6);
    if (node >= N_NODES) return;
    int l = threadIdx.x & 63;
    int le = l & 15;        // lane within edge group
    int eg = l >> 4;        // edge slot 0..3
    int p0 = rowptr[node], p1 = rowptr[node + 1];
    if (p0 == p1) return;
    // src row: 32 B per lane (lanes 0..15 cover the 512B row; replicated x4)
    const int4* srow = (const int4*)(hq + (long)node * DIM);
    int4 s0 = srow[le * 2], s1 = srow[le * 2 + 1];
    float ss = stepr[node];
    #pragma unroll 2
    for (int base = p0; base < p1; base += 4) {
        int p = base + eg;
        bool ok = p < p1;
        int d = ok ? edst_s[p] : 0;
        const int4* drow = (const int4*)(hq + (long)d * DIM);
        int4 d0 = drow[le * 2], d1 = drow[le * 2 + 1];
        int acc = 0;
        acc = dot4(s0.x, d0.x, acc); acc = dot4(s0.y, d0.y, acc);
        acc = dot4(s0.z, d0.z, acc); acc = dot4(s0.w, d0.w, acc);
        acc = dot4(s1.x, d1.x, acc); acc = dot4(s1.y, d1.y, acc);
        acc = dot4(s1.z, d1.z, acc); acc = dot4(s1.w, d1.w, acc);
        #pragma unroll
        for (int o = 8; o > 0; o >>= 1) acc += __shfl_xor(acc, o);
        if (ok && le == 0) rest[p] = ss * stepr[d] * (float)acc;
    }
}

// ---------------- fused per-layer: segment-sum + rotate ----------------
template<int WRITE_HB>
__global__ __launch_bounds__(256) void k_layer(const int* __restrict__ rowptr,
                                               const int* __restrict__ edst_s,
                                               const float* __restrict__ rest,
                                               const float* __restrict__ a0i,
                                               const float* __restrict__ a1i,
                                               const float* __restrict__ invn,
                                               const float* __restrict__ dinv,
                                               float* __restrict__ a0o,
                                               float* __restrict__ a1o,
                                               u16* __restrict__ hb) {
    int node = blockIdx.x * 4 + (threadIdx.x >> 6);
    if (node >= N_NODES) return;
    int l = threadIdx.x & 63;
    int p0 = rowptr[node], p1 = rowptr[node + 1];
    float x = a0i[node], y = a1i[node];
    float si = invn[node];
    float sa0 = x * si, sa1 = y * si;
    float accum = 0.f;
    for (int p = p0 + l; p < p1; p += 64) {
        int d = edst_s[p];
        float c = rest[p] + (sa0 * a0i[d] + sa1 * a1i[d]) * invn[d];
        c = fminf(1.f, fmaxf(-1.f, c));
        accum += dinv[d] * c;
    }
    accum = wave_sum(accum);
    if (l == 0) {
        float ang = dinv[node] * accum;
        float sn, cs;
        sincosf(ang, &sn, &cs);
        float r0 = cs * x - sn * y;
        float r1 = sn * x + cs * y;
        a0o[node] = r0;
        a1o[node] = r1;
        if (WRITE_HB) {
            hb[(long)node * DIM + 0] = f2bf(r0);
            hb[(long)node * DIM + 1] = f2bf(r1);
        }
    }
}

// ---------------- final: logits (MFMA skinny GEMM) + log_softmax ----------------
__global__ __launch_bounds__(256) void k_final(const u16* __restrict__ zb,
                                               const u16* __restrict__ W2b,
                                               const float* __restrict__ cb2,
                                               float* __restrict__ out) {
    __shared__ char ldsB[48 * 1024];   // 48 KB, XOR-swizzled rows
    const int tid = threadIdx.x;
    #pragma unroll
    for (int i = 0; i < 12; ++i) {
        int unit = i * 256 + tid;          // 3072 x 16B units
        int byte = unit * 16;
        int row = byte >> 10;
        int colb = byte & 1023;
        uint4 v = *(const uint4*)((const char*)W2b + byte);
        *(uint4*)(ldsB + row * 1024 + (colb ^ ((row & 7) << 4))) = v;
    }
    __syncthreads();

    const int l = tid & 63, wid = tid >> 6;
    const int lm = l & 15, lk = l >> 4;
    const long m0 = (long)blockIdx.x * 128 + wid * 32;

    f32x4 acc[2][3] = {};
    for (int kt = 0; kt < 16; ++kt) {
        const int k0 = kt * 32;
        bf16x8 af[2], bfr[3];
        #pragma unroll
        for (int m = 0; m < 2; ++m)
            af[m] = *(const bf16x8*)(zb + (m0 + m * 16 + lm) * DIM + k0 + lk * 8);
        #pragma unroll
        for (int n = 0; n < 3; ++n) {
            int br = n * 16 + lm;
            bfr[n] = *(const bf16x8*)(ldsB + br * 1024 + ((k0 * 2 + lk * 16) ^ ((br & 7) << 4)));
        }
        #pragma unroll
        for (int m = 0; m < 2; ++m)
            #pragma unroll
            for (int n = 0; n < 3; ++n)
                acc[m][n] = __builtin_amdgcn_mfma_f32_16x16x32_bf16(af[m], bfr[n], acc[m][n], 0, 0, 0);
    }

    float bc[3];
    #pragma unroll
    for (int n = 0; n < 3; ++n) {
        int col = n * 16 + lm;
        bc[n] = (col < DOUT) ? cb2[col] : 0.f;
    }

    #pragma unroll
    for (int m = 0; m < 2; ++m) {
        #pragma unroll
        for (int r = 0; r < 4; ++r) {
            long row = m0 + m * 16 + lk * 4 + r;
            float v[3];
            float mv = -1e30f;
            #pragma unroll
            for (int n = 0; n < 3; ++n) {
                int col = n * 16 + lm;
                float t = (col < DOUT) ? (acc[m][n][r] + bc[n]) : -1e30f;
                v[n] = t;
                mv = fmaxf(mv, t);
            }
            #pragma unroll
            for (int o = 8; o > 0; o >>= 1) mv = fmaxf(mv, __shfl_xor(mv, o));
            float es = 0.f;
            #pragma unroll
            for (int n = 0; n < 3; ++n) {
                int col = n * 16 + lm;
                if (col < DOUT) es += expf(v[n] - mv);
            }
            #pragma unroll
            for (int o = 8; o > 0; o >>= 1) es += __shfl_xor(es, o);
            float lse = logf(es);
            if (row < N_NODES) {
                #pragma unroll
                for (int n = 0; n < 3; ++n) {
                    int col = n * 16 + lm;
                    if (col < DOUT) out[row * DOUT + col] = v[n] - mv - lse;
                }
            }
        }
    }
}

extern "C" void kernel_launch(void* const* d_in, const int* in_sizes, int n_in,
                              void* d_out, int out_size, void* d_ws, size_t ws_size,
                              hipStream_t stream) {
    const float* x       = (const float*)d_in[0];
    const int*   esrc    = (const int*)d_in[1];
    const int*   edst    = (const int*)d_in[2];
    const float* W_in    = (const float*)d_in[3];
    const float* b_in    = (const float*)d_in[4];
    const float* ln_g    = (const float*)d_in[5];
    const float* ln_b    = (const float*)d_in[6];
    const float* cW1     = (const float*)d_in[7];
    const float* cb1     = (const float*)d_in[8];
    const float* bn_g    = (const float*)d_in[9];
    const float* bn_b    = (const float*)d_in[10];
    const float* bn_mean = (const float*)d_in[11];
    const float* bn_var  = (const float*)d_in[12];
    const float* cW2     = (const float*)d_in[13];
    const float* cb2     = (const float*)d_in[14];
    float* out = (float*)d_out;

    char* ws = (char*)d_ws;
    size_t off = 0;
    auto take = [&](size_t bytes) -> char* {
        char* p = ws + off;
        off = (off + bytes + 255) & ~(size_t)255;
        return p;
    };
    u16*   xb     = (u16*)take((size_t)MPAD * DIM * 2);   // later reused as zb
    u16*   hb     = (u16*)take((size_t)MPAD * DIM * 2);
    char*  hq     = (char*)take((size_t)N_NODES * DIM);
    float* stepr  = (float*)take((size_t)N_NODES * 4);
    u16*   WtIn   = (u16*)take((size_t)512 * 512 * 2);
    u16*   W1t    = (u16*)take((size_t)512 * 512 * 2);
    u16*   W2b    = (u16*)take((size_t)48 * 512 * 2);
    int*   deg    = (int*)take((size_t)N_NODES * 4);
    float* dinv   = (float*)take((size_t)N_NODES * 4);
    float* a0A    = (float*)take((size_t)N_NODES * 4);
    float* a1A    = (float*)take((size_t)N_NODES * 4);
    float* a0B    = (float*)take((size_t)N_NODES * 4);
    float* a1B    = (float*)take((size_t)N_NODES * 4);
    float* invn   = (float*)take((size_t)N_NODES * 4);
    float* rest   = (float*)take((size_t)N_EDGES * 4);
    int*   rowptr = (int*)take((size_t)(N_NODES + 1) * 4);
    int*   cnt    = (int*)take((size_t)N_NODES * 4);
    int*   edst_s = (int*)take((size_t)N_EDGES * 4);
    int*   psum   = (int*)take((size_t)NBLK * 4);
    int*   pbase  = (int*)take((size_t)NBLK * 4);
    u16*   zb     = xb;

    hipMemsetAsync(deg, 0, (size_t)N_NODES * 4, stream);

    k_conv_x<<<(MPAD * DIM / 4 + 255) / 256, 256, 0, stream>>>(x, xb);
    k_transpose_bf16<<<dim3(32, 32), dim3(16, 16), 0, stream>>>(W_in, WtIn, 512, 512);
    k_transpose_bf16<<<dim3(32, 32), dim3(16, 16), 0, stream>>>(cW1, W1t, 512, 512);
    k_prep_w2<<<(48 * DIM + 255) / 256, 256, 0, stream>>>(cW2, W2b);

    k_deg<<<N_EDGES / 256, 256, 0, stream>>>(esrc, deg);
    k_dinv<<<(N_NODES + 255) / 256, 256, 0, stream>>>(deg, dinv);
    k_csr_partial<<<NBLK, 256, 0, stream>>>(deg, psum);
    k_csr_base<<<1, 256, 0, stream>>>(psum, pbase, rowptr);
    k_csr_rowptr<<<NBLK, 256, 0, stream>>>(deg, pbase, rowptr, cnt);
    k_scatter<<<N_EDGES / 256, 256, 0, stream>>>(esrc, edst, rowptr, cnt, edst_s);

    k_gemm<0><<<dim3(MPAD / 128, 4), 256, 0, stream>>>(xb, WtIn, hb, b_in,
                                                       nullptr, nullptr, nullptr, nullptr);
    k_ln<<<MPAD / 4, 256, 0, stream>>>(hb, hq, stepr, ln_g, ln_b, a0A, a1A, invn);
    k_edge_dot<<<(N_NODES + 3) / 4, 256, 0, stream>>>(rowptr, edst_s, hq, stepr, rest);

    k_layer<0><<<(N_NODES + 3) / 4, 256, 0, stream>>>(rowptr, edst_s, rest,
                                                      a0A, a1A, invn, dinv, a0B, a1B, nullptr);
    k_layer<0><<<(N_NODES + 3) / 4, 256, 0, stream>>>(rowptr, edst_s, rest,
                                                      a0B, a1B, invn, dinv, a0A, a1A, nullptr);
    k_layer<1><<<(N_NODES + 3) / 4, 256, 0, stream>>>(rowptr, edst_s, rest,
                                                      a0A, a1A, invn, dinv, a0B, a1B, hb);

    k_gemm<1><<<dim3(MPAD / 128, 4), 256, 0, stream>>>(hb, W1t, zb, cb1,
                                                       bn_g, bn_b, bn_mean, bn_var);
    k_final<<<MPAD / 128, 256, 0, stream>>>(zb, W2b, cb2, out);
}

// Round 6
// 526.058 us; speedup vs baseline: 1.3366x; 1.0278x over previous
//
#include <hip/hip_runtime.h>
#include <hip/hip_bf16.h>
#include <math.h>

typedef unsigned short u16;
typedef unsigned int u32;

#define N_NODES 50000
#define N_EDGES 1600000
#define DIM     512
#define DOUT    40
#define MPAD    50048   // 391 * 128
#define NBLK    196     // ceil(N_NODES/256)
#define QROW    256     // int4 row bytes

typedef __bf16 bf16x8 __attribute__((ext_vector_type(8)));
typedef float  f32x4  __attribute__((ext_vector_type(4)));

__device__ inline float bf2f(u16 u) {
    union { u32 i; float f; } v; v.i = ((u32)u) << 16; return v.f;
}
__device__ inline u16 f2bf(float f) {
    union { float f; u32 u; } v; v.f = f;
    u32 u = v.u;
    u32 r = u + 0x7fffu + ((u >> 16) & 1u);   // RNE
    return (u16)(r >> 16);
}
__device__ inline float2 bfpair(u32 u) {
    float2 r;
    union { u32 i; float f; } lo, hi;
    lo.i = u << 16; hi.i = u & 0xffff0000u;
    r.x = lo.f; r.y = hi.f; return r;
}
__device__ inline float wave_sum(float v) {
    #pragma unroll
    for (int o = 32; o > 0; o >>= 1) v += __shfl_xor(v, o);
    return v;
}
__device__ inline float wave_max(float v) {
    #pragma unroll
    for (int o = 32; o > 0; o >>= 1) v = fmaxf(v, __shfl_xor(v, o));
    return v;
}
__device__ inline int wave_sum_i(int v) {
    #pragma unroll
    for (int o = 32; o > 0; o >>= 1) v += __shfl_xor(v, o);
    return v;
}
#if __has_builtin(__builtin_amdgcn_sdot8)
__device__ inline int dot8(int a, int b, int c) {
    return __builtin_amdgcn_sdot8(a, b, c, false);
}
#else
__device__ inline int dot8(int a, int b, int c) {
    #pragma unroll
    for (int j = 0; j < 8; ++j) {
        int av = ((int)((u32)a << (28 - 4 * j))) >> 28;
        int bv = ((int)((u32)b << (28 - 4 * j))) >> 28;
        c += av * bv;
    }
    return c;
}
#endif
// inclusive scan over a 256-thread block
__device__ inline int block_incl_scan(int v, int tid) {
    int lane = tid & 63, w = tid >> 6;
    #pragma unroll
    for (int o = 1; o < 64; o <<= 1) {
        int t = __shfl_up(v, o);
        if (lane >= o) v += t;
    }
    __shared__ int wsum[4];
    if (lane == 63) wsum[w] = v;
    __syncthreads();
    if (w > 0) v += wsum[0];
    if (w > 1) v += wsum[1];
    if (w > 2) v += wsum[2];
    return v;
}

// ---------------- x f32 -> bf16 (padded rows zeroed) ----------------
__global__ __launch_bounds__(256) void k_conv_x(const float* __restrict__ x,
                                                u16* __restrict__ xb) {
    long idx = (long)blockIdx.x * 256 + threadIdx.x;
    long base = idx * 4;
    if (base >= (long)MPAD * DIM) return;
    long row = base >> 9;  // /512
    float4 v;
    if (row < N_NODES) v = *(const float4*)(x + base);
    else { v.x = v.y = v.z = v.w = 0.f; }
    ushort4 o;
    o.x = f2bf(v.x); o.y = f2bf(v.y); o.z = f2bf(v.z); o.w = f2bf(v.w);
    *(ushort4*)(xb + base) = o;
}

// ---------------- weight transposes ----------------
__global__ __launch_bounds__(256) void k_transpose_bf16(const float* __restrict__ W,
                                                        u16* __restrict__ Wt,
                                                        int K, int N) {
    int n = blockIdx.x * 16 + threadIdx.x;
    int k = blockIdx.y * 16 + threadIdx.y;
    if (k < K && n < N) Wt[(long)n * K + k] = f2bf(W[(long)k * N + n]);
}
// cW2 [512][40] f32 -> W2b [48][512] bf16, rows 40..47 zeroed
__global__ __launch_bounds__(256) void k_prep_w2(const float* __restrict__ cW2,
                                                 u16* __restrict__ W2b) {
    int idx = blockIdx.x * 256 + threadIdx.x;   // 0 .. 48*512-1
    if (idx >= 48 * DIM) return;
    int n = idx >> 9;        // out col (0..47)
    int k = idx & 511;       // in dim
    float v = (n < DOUT) ? cW2[(long)k * DOUT + n] : 0.f;
    W2b[idx] = f2bf(v);
}

// ---------------- degree / dinv ----------------
__global__ __launch_bounds__(256) void k_deg(const int* __restrict__ esrc, int* __restrict__ deg) {
    int e = blockIdx.x * 256 + threadIdx.x;
    if (e < N_EDGES) atomicAdd(&deg[esrc[e]], 1);
}
__global__ __launch_bounds__(256) void k_dinv(const int* __restrict__ deg, float* __restrict__ dinv) {
    int i = blockIdx.x * 256 + threadIdx.x;
    if (i < N_NODES) {
        int d = deg[i];
        dinv[i] = (d > 0) ? (1.0f / sqrtf((float)d)) : 0.0f;
    }
}

// ---------------- CSR build: psum -> pbase -> rowptr -> scatter ----------------
__global__ __launch_bounds__(256) void k_csr_partial(const int* __restrict__ deg,
                                                     int* __restrict__ psum) {
    int idx = blockIdx.x * 256 + threadIdx.x;
    int v = (idx < N_NODES) ? deg[idx] : 0;
    int t = wave_sum_i(v);
    __shared__ int ws[4];
    int lane = threadIdx.x & 63, w = threadIdx.x >> 6;
    if (lane == 0) ws[w] = t;
    __syncthreads();
    if (threadIdx.x == 0) psum[blockIdx.x] = ws[0] + ws[1] + ws[2] + ws[3];
}
__global__ __launch_bounds__(256) void k_csr_base(const int* __restrict__ psum,
                                                  int* __restrict__ pbase,
                                                  int* __restrict__ rowptr) {
    int tid = threadIdx.x;
    int v = (tid < NBLK) ? psum[tid] : 0;
    int incl = block_incl_scan(v, tid);
    if (tid < NBLK) pbase[tid] = incl - v;   // exclusive
    if (tid == 0) rowptr[N_NODES] = N_EDGES;
}
__global__ __launch_bounds__(256) void k_csr_rowptr(const int* __restrict__ deg,
                                                    const int* __restrict__ pbase,
                                                    int* __restrict__ rowptr,
                                                    int* __restrict__ cnt) {
    int idx = blockIdx.x * 256 + threadIdx.x;
    int v = (idx < N_NODES) ? deg[idx] : 0;
    int incl = block_incl_scan(v, threadIdx.x);
    if (idx < N_NODES) {
        rowptr[idx] = pbase[blockIdx.x] + incl - v;
        cnt[idx] = 0;
    }
}
__global__ __launch_bounds__(256) void k_scatter(const int* __restrict__ esrc,
                                                 const int* __restrict__ edst,
                                                 const int* __restrict__ rowptr,
                                                 int* __restrict__ cnt,
                                                 int* __restrict__ edst_s) {
    int e = blockIdx.x * 256 + threadIdx.x;
    if (e >= N_EDGES) return;
    int s = esrc[e];
    int pos = rowptr[s] + atomicAdd(&cnt[s], 1);
    edst_s[pos] = edst[e];
}

// ---------------- bf16 MFMA GEMM: out = epilogue(A @ Bt^T) ----------------
template<int EPI>
__global__ __launch_bounds__(256) void k_gemm(const u16* __restrict__ A,
                                              const u16* __restrict__ Bt,
                                              u16* __restrict__ outB,
                                              const float* __restrict__ bias,
                                              const float* __restrict__ bn_g,
                                              const float* __restrict__ bn_b,
                                              const float* __restrict__ bn_mean,
                                              const float* __restrict__ bn_var) {
    __shared__ u16 lds[2 * 128 * 64];  // 32 KB: A tile then B tile
    char* ldsA = (char*)lds;
    char* ldsB = (char*)lds + 16384;

    const int tid = threadIdx.x;
    const int tm = blockIdx.x, tn = blockIdx.y;
    const int l = tid & 63, wid = tid >> 6;
    const int wr = wid >> 1, wc = wid & 1;
    const int lm = l & 15, lk = l >> 4;

    const int srow0 = tid >> 3;            // staging row base (0..31)
    const int scole = (tid & 7) * 8;       // staging elem col (0..56)
    const int scolb = scole * 2;           // byte col

    f32x4 acc[4][4] = {};

    for (int kt = 0; kt < 8; ++kt) {
        const int k0 = kt * 64;
        #pragma unroll
        for (int r = 0; r < 4; ++r) {
            int row = r * 32 + srow0;
            uint4 va = *(const uint4*)(A + ((long)tm * 128 + row) * DIM + k0 + scole);
            *(uint4*)(ldsA + row * 128 + (scolb ^ ((row & 7) << 4))) = va;
            uint4 vb = *(const uint4*)(Bt + ((long)tn * 128 + row) * DIM + k0 + scole);
            *(uint4*)(ldsB + row * 128 + (scolb ^ ((row & 7) << 4))) = vb;
        }
        __syncthreads();
        #pragma unroll
        for (int kk = 0; kk < 2; ++kk) {
            bf16x8 af[4], bfr[4];
            #pragma unroll
            for (int m = 0; m < 4; ++m) {
                int ar = wr * 64 + m * 16 + lm;
                af[m] = *(const bf16x8*)(ldsA + ar * 128 + ((kk * 64 + lk * 16) ^ ((ar & 7) << 4)));
            }
            #pragma unroll
            for (int n = 0; n < 4; ++n) {
                int br = wc * 64 + n * 16 + lm;
                bfr[n] = *(const bf16x8*)(ldsB + br * 128 + ((kk * 64 + lk * 16) ^ ((br & 7) << 4)));
            }
            #pragma unroll
            for (int m = 0; m < 4; ++m)
                #pragma unroll
                for (int n = 0; n < 4; ++n)
                    acc[m][n] = __builtin_amdgcn_mfma_f32_16x16x32_bf16(af[m], bfr[n], acc[m][n], 0, 0, 0);
        }
        __syncthreads();
    }

    #pragma unroll
    for (int n = 0; n < 4; ++n) {
        int col = tn * 128 + wc * 64 + n * 16 + lm;
        float bc = bias[col];
        float scale = 0.f, shift = 0.f;
        if (EPI == 1) {
            scale = bn_g[col] / sqrtf(bn_var[col] + 1e-5f);
            shift = bn_b[col] - bn_mean[col] * scale;
        }
        #pragma unroll
        for (int m = 0; m < 4; ++m) {
            f32x4 v = acc[m][n];
            #pragma unroll
            for (int r = 0; r < 4; ++r) {
                long row = (long)tm * 128 + wr * 64 + m * 16 + lk * 4 + r;
                float val = fmaxf(v[r] + bc, 0.f);
                if (EPI == 1) val = val * scale + shift;
                outB[row * DIM + col] = f2bf(val);
            }
        }
    }
}

// ---------------- LayerNorm (in-place on hb) + int4-quantized normalized row ----------------
// hq[row][256B] int4 (dims 0,1 zeroed), stepr[row] = dequant step, a0/a1/invn f32.
__global__ __launch_bounds__(256) void k_ln(u16* __restrict__ hb,
                                            char* __restrict__ hq,
                                            float* __restrict__ stepr,
                                            const float* __restrict__ g,
                                            const float* __restrict__ b,
                                            float* __restrict__ a0,
                                            float* __restrict__ a1,
                                            float* __restrict__ inv_nrm) {
    int row = blockIdx.x * 4 + (threadIdx.x >> 6);
    int l = threadIdx.x & 63;
    u16* prow = hb + (long)row * DIM + l * 8;
    if (row >= N_NODES) {
        if (row < MPAD) { uint4 z; z.x = z.y = z.z = z.w = 0u; *(uint4*)prow = z; }
        return;
    }
    uint4 v = *(const uint4*)prow;
    float x[8];
    { float2 p;
      p = bfpair(v.x); x[0] = p.x; x[1] = p.y;
      p = bfpair(v.y); x[2] = p.x; x[3] = p.y;
      p = bfpair(v.z); x[4] = p.x; x[5] = p.y;
      p = bfpair(v.w); x[6] = p.x; x[7] = p.y; }
    float s = 0.f, sq = 0.f;
    #pragma unroll
    for (int j = 0; j < 8; ++j) { s += x[j]; sq += x[j] * x[j]; }
    #pragma unroll
    for (int o = 32; o > 0; o >>= 1) { s += __shfl_xor(s, o); sq += __shfl_xor(sq, o); }
    float mean = s * (1.f / DIM);
    float var = sq * (1.f / DIM) - mean * mean;
    float rstd = 1.f / sqrtf(var + 1e-5f);
    float y[8];
    #pragma unroll
    for (int j = 0; j < 8; ++j) {
        int c = l * 8 + j;
        y[j] = (x[j] - mean) * rstd * g[c] + b[c];
    }
    float s2 = 0.f;
    #pragma unroll
    for (int j = 0; j < 8; ++j) s2 += y[j] * y[j];
    s2 = wave_sum(s2);
    float nrm = sqrtf(s2);
    float inv = 1.f / (nrm + 1e-4f);
    // write LN output (bf16) for GEMM2
    ushort4 oh;
    oh.x = f2bf(y[0]); oh.y = f2bf(y[1]); oh.z = f2bf(y[2]); oh.w = f2bf(y[3]);
    *(ushort4*)prow = oh;
    oh.x = f2bf(y[4]); oh.y = f2bf(y[5]); oh.z = f2bf(y[6]); oh.w = f2bf(y[7]);
    *(ushort4*)(prow + 4) = oh;
    // quantize normalized row to int4 with per-row scale
    float nv[8];
    float mx = 0.f;
    #pragma unroll
    for (int j = 0; j < 8; ++j) { nv[j] = y[j] * inv; mx = fmaxf(mx, fabsf(nv[j])); }
    mx = wave_max(mx);
    float qs = (mx > 0.f) ? (7.f / mx) : 0.f;
    if (l == 0) { nv[0] = 0.f; nv[1] = 0.f; }   // exclude dims 0,1 from rest
    u32 w = 0;
    #pragma unroll
    for (int j = 0; j < 8; ++j) {
        int q = (int)rintf(nv[j] * qs);
        w |= ((u32)(q & 0xF)) << (4 * j);
    }
    *(u32*)(hq + (long)row * QROW + l * 4) = w;
    if (l == 0) {
        stepr[row] = (mx > 0.f) ? (mx * (1.f / 7.f)) : 0.f;
        a0[row] = y[0]; a1[row] = y[1]; inv_nrm[row] = inv;
    }
}

// ---------------- per-edge partial dot over dims 2..511, int4, CSR order ----------------
// wave per src node; 4 edges per iteration, 16 lanes per edge.
__global__ __launch_bounds__(256) void k_edge_dot(const int* __restrict__ rowptr,
                                                  const int* __restrict__ edst_s,
                                                  const char* __restrict__ hq,
                                                  const float* __restrict__ stepr,
                                                  float* __restrict__ rest) {
    int node = blockIdx.x * 4 + (threadIdx.x >> 6);
    if (node >= N_NODES) return;
    int l = threadIdx.x & 63;
    int le = l & 15;        // lane within edge group
    int eg = l >> 4;        // edge slot 0..3
    int p0 = rowptr[node], p1 = rowptr[node + 1];
    if (p0 == p1) return;
    // src row: 16 B per lane (lanes 0..15 cover the 256B row; replicated x4)
    const int4* srow = (const int4*)(hq + (long)node * QROW);
    int4 s0 = srow[le];
    float ss = stepr[node];
    #pragma unroll 2
    for (int base = p0; base < p1; base += 4) {
        int p = base + eg;
        bool ok = p < p1;
        int d = ok ? edst_s[p] : 0;
        const int4* drow = (const int4*)(hq + (long)d * QROW);
        int4 d0 = drow[le];
        int acc = 0;
        acc = dot8(s0.x, d0.x, acc); acc = dot8(s0.y, d0.y, acc);
        acc = dot8(s0.z, d0.z, acc); acc = dot8(s0.w, d0.w, acc);
        #pragma unroll
        for (int o = 8; o > 0; o >>= 1) acc += __shfl_xor(acc, o);
        if (ok && le == 0) rest[p] = ss * stepr[d] * (float)acc;
    }
}

// ---------------- fused per-layer: segment-sum + rotate ----------------
template<int WRITE_HB>
__global__ __launch_bounds__(256) void k_layer(const int* __restrict__ rowptr,
                                               const int* __restrict__ edst_s,
                                               const float* __restrict__ rest,
                                               const float* __restrict__ a0i,
                                               const float* __restrict__ a1i,
                                               const float* __restrict__ invn,
                                               const float* __restrict__ dinv,
                                               float* __restrict__ a0o,
                                               float* __restrict__ a1o,
                                               u16* __restrict__ hb) {
    int node = blockIdx.x * 4 + (threadIdx.x >> 6);
    if (node >= N_NODES) return;
    int l = threadIdx.x & 63;
    int p0 = rowptr[node], p1 = rowptr[node + 1];
    float x = a0i[node], y = a1i[node];
    float si = invn[node];
    float sa0 = x * si, sa1 = y * si;
    float accum = 0.f;
    for (int p = p0 + l; p < p1; p += 64) {
        int d = edst_s[p];
        float c = rest[p] + (sa0 * a0i[d] + sa1 * a1i[d]) * invn[d];
        c = fminf(1.f, fmaxf(-1.f, c));
        accum += dinv[d] * c;
    }
    accum = wave_sum(accum);
    if (l == 0) {
        float ang = dinv[node] * accum;
        float sn, cs;
        sincosf(ang, &sn, &cs);
        float r0 = cs * x - sn * y;
        float r1 = sn * x + cs * y;
        a0o[node] = r0;
        a1o[node] = r1;
        if (WRITE_HB) {
            hb[(long)node * DIM + 0] = f2bf(r0);
            hb[(long)node * DIM + 1] = f2bf(r1);
        }
    }
}

// ---------------- final: logits (MFMA skinny GEMM) + log_softmax ----------------
__global__ __launch_bounds__(256) void k_final(const u16* __restrict__ zb,
                                               const u16* __restrict__ W2b,
                                               const float* __restrict__ cb2,
                                               float* __restrict__ out) {
    __shared__ char ldsB[48 * 1024];   // 48 KB, XOR-swizzled rows
    const int tid = threadIdx.x;
    #pragma unroll
    for (int i = 0; i < 12; ++i) {
        int unit = i * 256 + tid;          // 3072 x 16B units
        int byte = unit * 16;
        int row = byte >> 10;
        int colb = byte & 1023;
        uint4 v = *(const uint4*)((const char*)W2b + byte);
        *(uint4*)(ldsB + row * 1024 + (colb ^ ((row & 7) << 4))) = v;
    }
    __syncthreads();

    const int l = tid & 63, wid = tid >> 6;
    const int lm = l & 15, lk = l >> 4;
    const long m0 = (long)blockIdx.x * 128 + wid * 32;

    f32x4 acc[2][3] = {};
    for (int kt = 0; kt < 16; ++kt) {
        const int k0 = kt * 32;
        bf16x8 af[2], bfr[3];
        #pragma unroll
        for (int m = 0; m < 2; ++m)
            af[m] = *(const bf16x8*)(zb + (m0 + m * 16 + lm) * DIM + k0 + lk * 8);
        #pragma unroll
        for (int n = 0; n < 3; ++n) {
            int br = n * 16 + lm;
            bfr[n] = *(const bf16x8*)(ldsB + br * 1024 + ((k0 * 2 + lk * 16) ^ ((br & 7) << 4)));
        }
        #pragma unroll
        for (int m = 0; m < 2; ++m)
            #pragma unroll
            for (int n = 0; n < 3; ++n)
                acc[m][n] = __builtin_amdgcn_mfma_f32_16x16x32_bf16(af[m], bfr[n], acc[m][n], 0, 0, 0);
    }

    float bc[3];
    #pragma unroll
    for (int n = 0; n < 3; ++n) {
        int col = n * 16 + lm;
        bc[n] = (col < DOUT) ? cb2[col] : 0.f;
    }

    #pragma unroll
    for (int m = 0; m < 2; ++m) {
        #pragma unroll
        for (int r = 0; r < 4; ++r) {
            long row = m0 + m * 16 + lk * 4 + r;
            float v[3];
            float mv = -1e30f;
            #pragma unroll
            for (int n = 0; n < 3; ++n) {
                int col = n * 16 + lm;
                float t = (col < DOUT) ? (acc[m][n][r] + bc[n]) : -1e30f;
                v[n] = t;
                mv = fmaxf(mv, t);
            }
            #pragma unroll
            for (int o = 8; o > 0; o >>= 1) mv = fmaxf(mv, __shfl_xor(mv, o));
            float es = 0.f;
            #pragma unroll
            for (int n = 0; n < 3; ++n) {
                int col = n * 16 + lm;
                if (col < DOUT) es += expf(v[n] - mv);
            }
            #pragma unroll
            for (int o = 8; o > 0; o >>= 1) es += __shfl_xor(es, o);
            float lse = logf(es);
            if (row < N_NODES) {
                #pragma unroll
                for (int n = 0; n < 3; ++n) {
                    int col = n * 16 + lm;
                    if (col < DOUT) out[row * DOUT + col] = v[n] - mv - lse;
                }
            }
        }
    }
}

extern "C" void kernel_launch(void* const* d_in, const int* in_sizes, int n_in,
                              void* d_out, int out_size, void* d_ws, size_t ws_size,
                              hipStream_t stream) {
    const float* x       = (const float*)d_in[0];
    const int*   esrc    = (const int*)d_in[1];
    const int*   edst    = (const int*)d_in[2];
    const float* W_in    = (const float*)d_in[3];
    const float* b_in    = (const float*)d_in[4];
    const float* ln_g    = (const float*)d_in[5];
    const float* ln_b    = (const float*)d_in[6];
    const float* cW1     = (const float*)d_in[7];
    const float* cb1     = (const float*)d_in[8];
    const float* bn_g    = (const float*)d_in[9];
    const float* bn_b    = (const float*)d_in[10];
    const float* bn_mean = (const float*)d_in[11];
    const float* bn_var  = (const float*)d_in[12];
    const float* cW2     = (const float*)d_in[13];
    const float* cb2     = (const float*)d_in[14];
    float* out = (float*)d_out;

    char* ws = (char*)d_ws;
    size_t off = 0;
    auto take = [&](size_t bytes) -> char* {
        char* p = ws + off;
        off = (off + bytes + 255) & ~(size_t)255;
        return p;
    };
    u16*   xb     = (u16*)take((size_t)MPAD * DIM * 2);   // later reused as zb
    u16*   hb     = (u16*)take((size_t)MPAD * DIM * 2);
    char*  hq     = (char*)take((size_t)N_NODES * QROW);
    float* stepr  = (float*)take((size_t)N_NODES * 4);
    u16*   WtIn   = (u16*)take((size_t)512 * 512 * 2);
    u16*   W1t    = (u16*)take((size_t)512 * 512 * 2);
    u16*   W2b    = (u16*)take((size_t)48 * 512 * 2);
    int*   deg    = (int*)take((size_t)N_NODES * 4);
    float* dinv   = (float*)take((size_t)N_NODES * 4);
    float* a0A    = (float*)take((size_t)N_NODES * 4);
    float* a1A    = (float*)take((size_t)N_NODES * 4);
    float* a0B    = (float*)take((size_t)N_NODES * 4);
    float* a1B    = (float*)take((size_t)N_NODES * 4);
    float* invn   = (float*)take((size_t)N_NODES * 4);
    float* rest   = (float*)take((size_t)N_EDGES * 4);
    int*   rowptr = (int*)take((size_t)(N_NODES + 1) * 4);
    int*   cnt    = (int*)take((size_t)N_NODES * 4);
    int*   edst_s = (int*)take((size_t)N_EDGES * 4);
    int*   psum   = (int*)take((size_t)NBLK * 4);
    int*   pbase  = (int*)take((size_t)NBLK * 4);
    u16*   zb     = xb;

    hipMemsetAsync(deg, 0, (size_t)N_NODES * 4, stream);

    k_conv_x<<<(MPAD * DIM / 4 + 255) / 256, 256, 0, stream>>>(x, xb);
    k_transpose_bf16<<<dim3(32, 32), dim3(16, 16), 0, stream>>>(W_in, WtIn, 512, 512);
    k_transpose_bf16<<<dim3(32, 32), dim3(16, 16), 0, stream>>>(cW1, W1t, 512, 512);
    k_prep_w2<<<(48 * DIM + 255) / 256, 256, 0, stream>>>(cW2, W2b);

    k_deg<<<N_EDGES / 256, 256, 0, stream>>>(esrc, deg);
    k_dinv<<<(N_NODES + 255) / 256, 256, 0, stream>>>(deg, dinv);
    k_csr_partial<<<NBLK, 256, 0, stream>>>(deg, psum);
    k_csr_base<<<1, 256, 0, stream>>>(psum, pbase, rowptr);
    k_csr_rowptr<<<NBLK, 256, 0, stream>>>(deg, pbase, rowptr, cnt);
    k_scatter<<<N_EDGES / 256, 256, 0, stream>>>(esrc, edst, rowptr, cnt, edst_s);

    k_gemm<0><<<dim3(MPAD / 128, 4), 256, 0, stream>>>(xb, WtIn, hb, b_in,
                                                       nullptr, nullptr, nullptr, nullptr);
    k_ln<<<MPAD / 4, 256, 0, stream>>>(hb, hq, stepr, ln_g, ln_b, a0A, a1A, invn);
    k_edge_dot<<<(N_NODES + 3) / 4, 256, 0, stream>>>(rowptr, edst_s, hq, stepr, rest);

    k_layer<0><<<(N_NODES + 3) / 4, 256, 0, stream>>>(rowptr, edst_s, rest,
                                                      a0A, a1A, invn, dinv, a0B, a1B, nullptr);
    k_layer<0><<<(N_NODES + 3) / 4, 256, 0, stream>>>(rowptr, edst_s, rest,
                                                      a0B, a1B, invn, dinv, a0A, a1A, nullptr);
    k_layer<1><<<(N_NODES + 3) / 4, 256, 0, stream>>>(rowptr, edst_s, rest,
                                                      a0A, a1A, invn, dinv, a0B, a1B, hb);

    k_gemm<1><<<dim3(MPAD / 128, 4), 256, 0, stream>>>(hb, W1t, zb, cb1,
                                                       bn_g, bn_b, bn_mean, bn_var);
    k_final<<<MPAD / 128, 256, 0, stream>>>(zb, W2b, cb2, out);
}

// Round 7
// 477.633 us; speedup vs baseline: 1.4721x; 1.1014x over previous
//
#include <hip/hip_runtime.h>
#include <hip/hip_bf16.h>
#include <math.h>

typedef unsigned short u16;
typedef unsigned int u32;

#define N_NODES 50000
#define N_EDGES 1600000
#define DIM     512
#define DOUT    40
#define MPAD    50048   // 391 * 128
#define NBLK    196     // ceil(N_NODES/256)
#define QROW    256     // int4 row bytes
#define NBKT    196     // buckets = src>>8
#define NB1     256     // multisplit pass-1 blocks
#define CHUNK   6250    // edges per pass-1 block (256*6250 = 1.6M exactly)

typedef __bf16 bf16x8 __attribute__((ext_vector_type(8)));
typedef float  f32x4  __attribute__((ext_vector_type(4)));

__device__ inline float bf2f(u16 u) {
    union { u32 i; float f; } v; v.i = ((u32)u) << 16; return v.f;
}
__device__ inline u16 f2bf(float f) {
    union { float f; u32 u; } v; v.f = f;
    u32 u = v.u;
    u32 r = u + 0x7fffu + ((u >> 16) & 1u);   // RNE
    return (u16)(r >> 16);
}
__device__ inline float2 bfpair(u32 u) {
    float2 r;
    union { u32 i; float f; } lo, hi;
    lo.i = u << 16; hi.i = u & 0xffff0000u;
    r.x = lo.f; r.y = hi.f; return r;
}
__device__ inline float wave_sum(float v) {
    #pragma unroll
    for (int o = 32; o > 0; o >>= 1) v += __shfl_xor(v, o);
    return v;
}
__device__ inline float wave_max(float v) {
    #pragma unroll
    for (int o = 32; o > 0; o >>= 1) v = fmaxf(v, __shfl_xor(v, o));
    return v;
}
__device__ inline int wave_sum_i(int v) {
    #pragma unroll
    for (int o = 32; o > 0; o >>= 1) v += __shfl_xor(v, o);
    return v;
}
#if __has_builtin(__builtin_amdgcn_sdot8)
__device__ inline int dot8(int a, int b, int c) {
    return __builtin_amdgcn_sdot8(a, b, c, false);
}
#else
__device__ inline int dot8(int a, int b, int c) {
    #pragma unroll
    for (int j = 0; j < 8; ++j) {
        int av = ((int)((u32)a << (28 - 4 * j))) >> 28;
        int bv = ((int)((u32)b << (28 - 4 * j))) >> 28;
        c += av * bv;
    }
    return c;
}
#endif
// inclusive scan over a 256-thread block
__device__ inline int block_incl_scan(int v, int tid) {
    int lane = tid & 63, w = tid >> 6;
    #pragma unroll
    for (int o = 1; o < 64; o <<= 1) {
        int t = __shfl_up(v, o);
        if (lane >= o) v += t;
    }
    __shared__ int wsum[4];
    if (lane == 63) wsum[w] = v;
    __syncthreads();
    if (w > 0) v += wsum[0];
    if (w > 1) v += wsum[1];
    if (w > 2) v += wsum[2];
    return v;
}

// ---------------- x f32 -> bf16 (padded rows zeroed) ----------------
__global__ __launch_bounds__(256) void k_conv_x(const float* __restrict__ x,
                                                u16* __restrict__ xb) {
    long idx = (long)blockIdx.x * 256 + threadIdx.x;
    long base = idx * 4;
    if (base >= (long)MPAD * DIM) return;
    long row = base >> 9;  // /512
    float4 v;
    if (row < N_NODES) v = *(const float4*)(x + base);
    else { v.x = v.y = v.z = v.w = 0.f; }
    ushort4 o;
    o.x = f2bf(v.x); o.y = f2bf(v.y); o.z = f2bf(v.z); o.w = f2bf(v.w);
    *(ushort4*)(xb + base) = o;
}

// ---------------- weight transposes ----------------
__global__ __launch_bounds__(256) void k_transpose_bf16(const float* __restrict__ W,
                                                        u16* __restrict__ Wt,
                                                        int K, int N) {
    int n = blockIdx.x * 16 + threadIdx.x;
    int k = blockIdx.y * 16 + threadIdx.y;
    if (k < K && n < N) Wt[(long)n * K + k] = f2bf(W[(long)k * N + n]);
}
// cW2 [512][40] f32 -> W2b [48][512] bf16, rows 40..47 zeroed
__global__ __launch_bounds__(256) void k_prep_w2(const float* __restrict__ cW2,
                                                 u16* __restrict__ W2b) {
    int idx = blockIdx.x * 256 + threadIdx.x;   // 0 .. 48*512-1
    if (idx >= 48 * DIM) return;
    int n = idx >> 9;        // out col (0..47)
    int k = idx & 511;       // in dim
    float v = (n < DOUT) ? cW2[(long)k * DOUT + n] : 0.f;
    W2b[idx] = f2bf(v);
}

// ---------------- degree / dinv ----------------
__global__ __launch_bounds__(256) void k_deg(const int* __restrict__ esrc, int* __restrict__ deg) {
    int e = blockIdx.x * 256 + threadIdx.x;
    if (e < N_EDGES) atomicAdd(&deg[esrc[e]], 1);
}
__global__ __launch_bounds__(256) void k_dinv(const int* __restrict__ deg, float* __restrict__ dinv) {
    int i = blockIdx.x * 256 + threadIdx.x;
    if (i < N_NODES) {
        int d = deg[i];
        dinv[i] = (d > 0) ? (1.0f / sqrtf((float)d)) : 0.0f;
    }
}

// ---------------- CSR rowptr build: psum -> pbase -> rowptr ----------------
__global__ __launch_bounds__(256) void k_csr_partial(const int* __restrict__ deg,
                                                     int* __restrict__ psum) {
    int idx = blockIdx.x * 256 + threadIdx.x;
    int v = (idx < N_NODES) ? deg[idx] : 0;
    int t = wave_sum_i(v);
    __shared__ int ws[4];
    int lane = threadIdx.x & 63, w = threadIdx.x >> 6;
    if (lane == 0) ws[w] = t;
    __syncthreads();
    if (threadIdx.x == 0) psum[blockIdx.x] = ws[0] + ws[1] + ws[2] + ws[3];
}
__global__ __launch_bounds__(256) void k_csr_base(const int* __restrict__ psum,
                                                  int* __restrict__ pbase,
                                                  int* __restrict__ rowptr) {
    int tid = threadIdx.x;
    int v = (tid < NBLK) ? psum[tid] : 0;
    int incl = block_incl_scan(v, tid);
    if (tid < NBLK) pbase[tid] = incl - v;   // exclusive
    if (tid == 0) rowptr[N_NODES] = N_EDGES;
}
__global__ __launch_bounds__(256) void k_csr_rowptr(const int* __restrict__ deg,
                                                    const int* __restrict__ pbase,
                                                    int* __restrict__ rowptr) {
    int idx = blockIdx.x * 256 + threadIdx.x;
    int v = (idx < N_NODES) ? deg[idx] : 0;
    int incl = block_incl_scan(v, threadIdx.x);
    if (idx < N_NODES) rowptr[idx] = pbase[blockIdx.x] + incl - v;
}

// ---------------- multisplit CSR build (no global atomics) ----------------
// C[bucket][block] layout, flat idx = bucket*NB1 + block.
__global__ __launch_bounds__(256) void k_ms_count(const int* __restrict__ esrc,
                                                  int* __restrict__ C) {
    __shared__ int bcnt[NBKT];
    int tid = threadIdx.x, blk = blockIdx.x;
    if (tid < NBKT) bcnt[tid] = 0;
    __syncthreads();
    int e0 = blk * CHUNK, e1 = e0 + CHUNK;
    for (int e = e0 + tid; e < e1; e += 256)
        atomicAdd(&bcnt[esrc[e] >> 8], 1);
    __syncthreads();
    if (tid < NBKT) C[tid * NB1 + blk] = bcnt[tid];
}
// scan of flat C (length NBKT*NB1 = 50176 = 196 blocks x 256)
__global__ __launch_bounds__(256) void k_ms_scan_partial(const int* __restrict__ C,
                                                         int* __restrict__ psum2) {
    int v = C[blockIdx.x * 256 + threadIdx.x];
    int t = wave_sum_i(v);
    __shared__ int ws[4];
    int lane = threadIdx.x & 63, w = threadIdx.x >> 6;
    if (lane == 0) ws[w] = t;
    __syncthreads();
    if (threadIdx.x == 0) psum2[blockIdx.x] = ws[0] + ws[1] + ws[2] + ws[3];
}
__global__ __launch_bounds__(256) void k_ms_scan_base(const int* __restrict__ psum2,
                                                      int* __restrict__ pb2) {
    int tid = threadIdx.x;
    int v = (tid < NBKT) ? psum2[tid] : 0;
    int incl = block_incl_scan(v, tid);
    if (tid < NBKT) pb2[tid] = incl - v;
}
__global__ __launch_bounds__(256) void k_ms_scan_add(const int* __restrict__ C,
                                                     const int* __restrict__ pb2,
                                                     int* __restrict__ O) {
    int idx = blockIdx.x * 256 + threadIdx.x;
    int v = C[idx];
    int incl = block_incl_scan(v, threadIdx.x);
    O[idx] = pb2[blockIdx.x] + incl - v;
}
// pass 1c: write (src,dst) pairs to bucket-major tmp; per-(bucket,block) runs are
// contiguous, so each 64B line is completed by one block (one XCD).
__global__ __launch_bounds__(256) void k_ms_scatter(const int* __restrict__ esrc,
                                                    const int* __restrict__ edst,
                                                    const int* __restrict__ O,
                                                    uint2* __restrict__ tmp) {
    __shared__ int cur[NBKT];
    int tid = threadIdx.x, blk = blockIdx.x;
    if (tid < NBKT) cur[tid] = O[tid * NB1 + blk];
    __syncthreads();
    int e0 = blk * CHUNK, e1 = e0 + CHUNK;
    for (int e = e0 + tid; e < e1; e += 256) {
        int s = esrc[e], d = edst[e];
        int pos = atomicAdd(&cur[s >> 8], 1);
        uint2 pr; pr.x = (u32)s; pr.y = (u32)d;
        tmp[pos] = pr;
    }
}
// pass 2: one block per bucket; node cursors straight from rowptr; writes stay
// inside the bucket's ~32KB window (single block -> single XCD L2 coalesces).
__global__ __launch_bounds__(256) void k_ms_sort(const int* __restrict__ rowptr,
                                                 const uint2* __restrict__ tmp,
                                                 int* __restrict__ edst_s) {
    __shared__ int cur[256];
    int tid = threadIdx.x, b = blockIdx.x;
    int base = b * 256;
    cur[tid] = (base + tid < N_NODES) ? rowptr[base + tid] : 0;
    __syncthreads();
    int top = base + 256; if (top > N_NODES) top = N_NODES;
    int rs = rowptr[base], re = rowptr[top];
    for (int p = rs + tid; p < re; p += 256) {
        uint2 pr = tmp[p];
        int pos = atomicAdd(&cur[pr.x - base], 1);
        edst_s[pos] = (int)pr.y;
    }
}

// ---------------- bf16 MFMA GEMM: out = epilogue(A @ Bt^T) ----------------
template<int EPI>
__global__ __launch_bounds__(256) void k_gemm(const u16* __restrict__ A,
                                              const u16* __restrict__ Bt,
                                              u16* __restrict__ outB,
                                              const float* __restrict__ bias,
                                              const float* __restrict__ bn_g,
                                              const float* __restrict__ bn_b,
                                              const float* __restrict__ bn_mean,
                                              const float* __restrict__ bn_var) {
    __shared__ u16 lds[2 * 128 * 64];  // 32 KB: A tile then B tile
    char* ldsA = (char*)lds;
    char* ldsB = (char*)lds + 16384;

    const int tid = threadIdx.x;
    const int tm = blockIdx.x, tn = blockIdx.y;
    const int l = tid & 63, wid = tid >> 6;
    const int wr = wid >> 1, wc = wid & 1;
    const int lm = l & 15, lk = l >> 4;

    const int srow0 = tid >> 3;            // staging row base (0..31)
    const int scole = (tid & 7) * 8;       // staging elem col (0..56)
    const int scolb = scole * 2;           // byte col

    f32x4 acc[4][4] = {};

    for (int kt = 0; kt < 8; ++kt) {
        const int k0 = kt * 64;
        #pragma unroll
        for (int r = 0; r < 4; ++r) {
            int row = r * 32 + srow0;
            uint4 va = *(const uint4*)(A + ((long)tm * 128 + row) * DIM + k0 + scole);
            *(uint4*)(ldsA + row * 128 + (scolb ^ ((row & 7) << 4))) = va;
            uint4 vb = *(const uint4*)(Bt + ((long)tn * 128 + row) * DIM + k0 + scole);
            *(uint4*)(ldsB + row * 128 + (scolb ^ ((row & 7) << 4))) = vb;
        }
        __syncthreads();
        #pragma unroll
        for (int kk = 0; kk < 2; ++kk) {
            bf16x8 af[4], bfr[4];
            #pragma unroll
            for (int m = 0; m < 4; ++m) {
                int ar = wr * 64 + m * 16 + lm;
                af[m] = *(const bf16x8*)(ldsA + ar * 128 + ((kk * 64 + lk * 16) ^ ((ar & 7) << 4)));
            }
            #pragma unroll
            for (int n = 0; n < 4; ++n) {
                int br = wc * 64 + n * 16 + lm;
                bfr[n] = *(const bf16x8*)(ldsB + br * 128 + ((kk * 64 + lk * 16) ^ ((br & 7) << 4)));
            }
            #pragma unroll
            for (int m = 0; m < 4; ++m)
                #pragma unroll
                for (int n = 0; n < 4; ++n)
                    acc[m][n] = __builtin_amdgcn_mfma_f32_16x16x32_bf16(af[m], bfr[n], acc[m][n], 0, 0, 0);
        }
        __syncthreads();
    }

    #pragma unroll
    for (int n = 0; n < 4; ++n) {
        int col = tn * 128 + wc * 64 + n * 16 + lm;
        float bc = bias[col];
        float scale = 0.f, shift = 0.f;
        if (EPI == 1) {
            scale = bn_g[col] / sqrtf(bn_var[col] + 1e-5f);
            shift = bn_b[col] - bn_mean[col] * scale;
        }
        #pragma unroll
        for (int m = 0; m < 4; ++m) {
            f32x4 v = acc[m][n];
            #pragma unroll
            for (int r = 0; r < 4; ++r) {
                long row = (long)tm * 128 + wr * 64 + m * 16 + lk * 4 + r;
                float val = fmaxf(v[r] + bc, 0.f);
                if (EPI == 1) val = val * scale + shift;
                outB[row * DIM + col] = f2bf(val);
            }
        }
    }
}

// ---------------- LayerNorm (in-place on hb) + int4-quantized normalized row ----------------
__global__ __launch_bounds__(256) void k_ln(u16* __restrict__ hb,
                                            char* __restrict__ hq,
                                            float* __restrict__ stepr,
                                            const float* __restrict__ g,
                                            const float* __restrict__ b,
                                            float* __restrict__ a0,
                                            float* __restrict__ a1,
                                            float* __restrict__ inv_nrm) {
    int row = blockIdx.x * 4 + (threadIdx.x >> 6);
    int l = threadIdx.x & 63;
    u16* prow = hb + (long)row * DIM + l * 8;
    if (row >= N_NODES) {
        if (row < MPAD) { uint4 z; z.x = z.y = z.z = z.w = 0u; *(uint4*)prow = z; }
        return;
    }
    uint4 v = *(const uint4*)prow;
    float x[8];
    { float2 p;
      p = bfpair(v.x); x[0] = p.x; x[1] = p.y;
      p = bfpair(v.y); x[2] = p.x; x[3] = p.y;
      p = bfpair(v.z); x[4] = p.x; x[5] = p.y;
      p = bfpair(v.w); x[6] = p.x; x[7] = p.y; }
    float s = 0.f, sq = 0.f;
    #pragma unroll
    for (int j = 0; j < 8; ++j) { s += x[j]; sq += x[j] * x[j]; }
    #pragma unroll
    for (int o = 32; o > 0; o >>= 1) { s += __shfl_xor(s, o); sq += __shfl_xor(sq, o); }
    float mean = s * (1.f / DIM);
    float var = sq * (1.f / DIM) - mean * mean;
    float rstd = 1.f / sqrtf(var + 1e-5f);
    float y[8];
    #pragma unroll
    for (int j = 0; j < 8; ++j) {
        int c = l * 8 + j;
        y[j] = (x[j] - mean) * rstd * g[c] + b[c];
    }
    float s2 = 0.f;
    #pragma unroll
    for (int j = 0; j < 8; ++j) s2 += y[j] * y[j];
    s2 = wave_sum(s2);
    float nrm = sqrtf(s2);
    float inv = 1.f / (nrm + 1e-4f);
    // write LN output (bf16) for GEMM2
    ushort4 oh;
    oh.x = f2bf(y[0]); oh.y = f2bf(y[1]); oh.z = f2bf(y[2]); oh.w = f2bf(y[3]);
    *(ushort4*)prow = oh;
    oh.x = f2bf(y[4]); oh.y = f2bf(y[5]); oh.z = f2bf(y[6]); oh.w = f2bf(y[7]);
    *(ushort4*)(prow + 4) = oh;
    // quantize normalized row to int4 with per-row scale
    float nv[8];
    float mx = 0.f;
    #pragma unroll
    for (int j = 0; j < 8; ++j) { nv[j] = y[j] * inv; mx = fmaxf(mx, fabsf(nv[j])); }
    mx = wave_max(mx);
    float qs = (mx > 0.f) ? (7.f / mx) : 0.f;
    if (l == 0) { nv[0] = 0.f; nv[1] = 0.f; }   // exclude dims 0,1 from rest
    u32 w = 0;
    #pragma unroll
    for (int j = 0; j < 8; ++j) {
        int q = (int)rintf(nv[j] * qs);
        w |= ((u32)(q & 0xF)) << (4 * j);
    }
    *(u32*)(hq + (long)row * QROW + l * 4) = w;
    if (l == 0) {
        stepr[row] = (mx > 0.f) ? (mx * (1.f / 7.f)) : 0.f;
        a0[row] = y[0]; a1[row] = y[1]; inv_nrm[row] = inv;
    }
}

// ---------------- per-edge partial dot over dims 2..511, int4, CSR order ----------------
__global__ __launch_bounds__(256) void k_edge_dot(const int* __restrict__ rowptr,
                                                  const int* __restrict__ edst_s,
                                                  const char* __restrict__ hq,
                                                  const float* __restrict__ stepr,
                                                  float* __restrict__ rest) {
    int node = blockIdx.x * 4 + (threadIdx.x >> 6);
    if (node >= N_NODES) return;
    int l = threadIdx.x & 63;
    int le = l & 15;        // lane within edge group
    int eg = l >> 4;        // edge slot 0..3
    int p0 = rowptr[node], p1 = rowptr[node + 1];
    if (p0 == p1) return;
    const int4* srow = (const int4*)(hq + (long)node * QROW);
    int4 s0 = srow[le];
    float ss = stepr[node];
    #pragma unroll 2
    for (int base = p0; base < p1; base += 4) {
        int p = base + eg;
        bool ok = p < p1;
        int d = ok ? edst_s[p] : 0;
        const int4* drow = (const int4*)(hq + (long)d * QROW);
        int4 d0 = drow[le];
        int acc = 0;
        acc = dot8(s0.x, d0.x, acc); acc = dot8(s0.y, d0.y, acc);
        acc = dot8(s0.z, d0.z, acc); acc = dot8(s0.w, d0.w, acc);
        #pragma unroll
        for (int o = 8; o > 0; o >>= 1) acc += __shfl_xor(acc, o);
        if (ok && le == 0) rest[p] = ss * stepr[d] * (float)acc;
    }
}

// ---------------- fused per-layer: segment-sum + rotate ----------------
template<int WRITE_HB>
__global__ __launch_bounds__(256) void k_layer(const int* __restrict__ rowptr,
                                               const int* __restrict__ edst_s,
                                               const float* __restrict__ rest,
                                               const float* __restrict__ a0i,
                                               const float* __restrict__ a1i,
                                               const float* __restrict__ invn,
                                               const float* __restrict__ dinv,
                                               float* __restrict__ a0o,
                                               float* __restrict__ a1o,
                                               u16* __restrict__ hb) {
    int node = blockIdx.x * 4 + (threadIdx.x >> 6);
    if (node >= N_NODES) return;
    int l = threadIdx.x & 63;
    int p0 = rowptr[node], p1 = rowptr[node + 1];
    float x = a0i[node], y = a1i[node];
    float si = invn[node];
    float sa0 = x * si, sa1 = y * si;
    float accum = 0.f;
    for (int p = p0 + l; p < p1; p += 64) {
        int d = edst_s[p];
        float c = rest[p] + (sa0 * a0i[d] + sa1 * a1i[d]) * invn[d];
        c = fminf(1.f, fmaxf(-1.f, c));
        accum += dinv[d] * c;
    }
    accum = wave_sum(accum);
    if (l == 0) {
        float ang = dinv[node] * accum;
        float sn, cs;
        sincosf(ang, &sn, &cs);
        float r0 = cs * x - sn * y;
        float r1 = sn * x + cs * y;
        a0o[node] = r0;
        a1o[node] = r1;
        if (WRITE_HB) {
            hb[(long)node * DIM + 0] = f2bf(r0);
            hb[(long)node * DIM + 1] = f2bf(r1);
        }
    }
}

// ---------------- final: logits (MFMA skinny GEMM) + log_softmax ----------------
__global__ __launch_bounds__(256) void k_final(const u16* __restrict__ zb,
                                               const u16* __restrict__ W2b,
                                               const float* __restrict__ cb2,
                                               float* __restrict__ out) {
    __shared__ char ldsB[48 * 1024];   // 48 KB, XOR-swizzled rows
    const int tid = threadIdx.x;
    #pragma unroll
    for (int i = 0; i < 12; ++i) {
        int unit = i * 256 + tid;          // 3072 x 16B units
        int byte = unit * 16;
        int row = byte >> 10;
        int colb = byte & 1023;
        uint4 v = *(const uint4*)((const char*)W2b + byte);
        *(uint4*)(ldsB + row * 1024 + (colb ^ ((row & 7) << 4))) = v;
    }
    __syncthreads();

    const int l = tid & 63, wid = tid >> 6;
    const int lm = l & 15, lk = l >> 4;
    const long m0 = (long)blockIdx.x * 128 + wid * 32;

    f32x4 acc[2][3] = {};
    for (int kt = 0; kt < 16; ++kt) {
        const int k0 = kt * 32;
        bf16x8 af[2], bfr[3];
        #pragma unroll
        for (int m = 0; m < 2; ++m)
            af[m] = *(const bf16x8*)(zb + (m0 + m * 16 + lm) * DIM + k0 + lk * 8);
        #pragma unroll
        for (int n = 0; n < 3; ++n) {
            int br = n * 16 + lm;
            bfr[n] = *(const bf16x8*)(ldsB + br * 1024 + ((k0 * 2 + lk * 16) ^ ((br & 7) << 4)));
        }
        #pragma unroll
        for (int m = 0; m < 2; ++m)
            #pragma unroll
            for (int n = 0; n < 3; ++n)
                acc[m][n] = __builtin_amdgcn_mfma_f32_16x16x32_bf16(af[m], bfr[n], acc[m][n], 0, 0, 0);
    }

    float bc[3];
    #pragma unroll
    for (int n = 0; n < 3; ++n) {
        int col = n * 16 + lm;
        bc[n] = (col < DOUT) ? cb2[col] : 0.f;
    }

    #pragma unroll
    for (int m = 0; m < 2; ++m) {
        #pragma unroll
        for (int r = 0; r < 4; ++r) {
            long row = m0 + m * 16 + lk * 4 + r;
            float v[3];
            float mv = -1e30f;
            #pragma unroll
            for (int n = 0; n < 3; ++n) {
                int col = n * 16 + lm;
                float t = (col < DOUT) ? (acc[m][n][r] + bc[n]) : -1e30f;
                v[n] = t;
                mv = fmaxf(mv, t);
            }
            #pragma unroll
            for (int o = 8; o > 0; o >>= 1) mv = fmaxf(mv, __shfl_xor(mv, o));
            float es = 0.f;
            #pragma unroll
            for (int n = 0; n < 3; ++n) {
                int col = n * 16 + lm;
                if (col < DOUT) es += expf(v[n] - mv);
            }
            #pragma unroll
            for (int o = 8; o > 0; o >>= 1) es += __shfl_xor(es, o);
            float lse = logf(es);
            if (row < N_NODES) {
                #pragma unroll
                for (int n = 0; n < 3; ++n) {
                    int col = n * 16 + lm;
                    if (col < DOUT) out[row * DOUT + col] = v[n] - mv - lse;
                }
            }
        }
    }
}

extern "C" void kernel_launch(void* const* d_in, const int* in_sizes, int n_in,
                              void* d_out, int out_size, void* d_ws, size_t ws_size,
                              hipStream_t stream) {
    const float* x       = (const float*)d_in[0];
    const int*   esrc    = (const int*)d_in[1];
    const int*   edst    = (const int*)d_in[2];
    const float* W_in    = (const float*)d_in[3];
    const float* b_in    = (const float*)d_in[4];
    const float* ln_g    = (const float*)d_in[5];
    const float* ln_b    = (const float*)d_in[6];
    const float* cW1     = (const float*)d_in[7];
    const float* cb1     = (const float*)d_in[8];
    const float* bn_g    = (const float*)d_in[9];
    const float* bn_b    = (const float*)d_in[10];
    const float* bn_mean = (const float*)d_in[11];
    const float* bn_var  = (const float*)d_in[12];
    const float* cW2     = (const float*)d_in[13];
    const float* cb2     = (const float*)d_in[14];
    float* out = (float*)d_out;

    char* ws = (char*)d_ws;
    size_t off = 0;
    auto take = [&](size_t bytes) -> char* {
        char* p = ws + off;
        off = (off + bytes + 255) & ~(size_t)255;
        return p;
    };
    u16*   xb     = (u16*)take((size_t)MPAD * DIM * 2);   // later reused as zb
    u16*   hb     = (u16*)take((size_t)MPAD * DIM * 2);
    char*  hq     = (char*)take((size_t)N_NODES * QROW);
    float* stepr  = (float*)take((size_t)N_NODES * 4);
    u16*   WtIn   = (u16*)take((size_t)512 * 512 * 2);
    u16*   W1t    = (u16*)take((size_t)512 * 512 * 2);
    u16*   W2b    = (u16*)take((size_t)48 * 512 * 2);
    int*   deg    = (int*)take((size_t)N_NODES * 4);
    float* dinv   = (float*)take((size_t)N_NODES * 4);
    float* a0A    = (float*)take((size_t)N_NODES * 4);
    float* a1A    = (float*)take((size_t)N_NODES * 4);
    float* a0B    = (float*)take((size_t)N_NODES * 4);
    float* a1B    = (float*)take((size_t)N_NODES * 4);
    float* invn   = (float*)take((size_t)N_NODES * 4);
    float* rest   = (float*)take((size_t)N_EDGES * 4);
    int*   rowptr = (int*)take((size_t)(N_NODES + 1) * 4);
    int*   edst_s = (int*)take((size_t)N_EDGES * 4);
    int*   psum   = (int*)take((size_t)NBLK * 4);
    int*   pbase  = (int*)take((size_t)NBLK * 4);
    uint2* tmp    = (uint2*)take((size_t)N_EDGES * 8);
    int*   Cm     = (int*)take((size_t)NBKT * NB1 * 4);
    int*   Om     = (int*)take((size_t)NBKT * NB1 * 4);
    int*   psum2  = (int*)take((size_t)NBKT * 4);
    int*   pb2    = (int*)take((size_t)NBKT * 4);
    u16*   zb     = xb;

    hipMemsetAsync(deg, 0, (size_t)N_NODES * 4, stream);

    k_conv_x<<<(MPAD * DIM / 4 + 255) / 256, 256, 0, stream>>>(x, xb);
    k_transpose_bf16<<<dim3(32, 32), dim3(16, 16), 0, stream>>>(W_in, WtIn, 512, 512);
    k_transpose_bf16<<<dim3(32, 32), dim3(16, 16), 0, stream>>>(cW1, W1t, 512, 512);
    k_prep_w2<<<(48 * DIM + 255) / 256, 256, 0, stream>>>(cW2, W2b);

    k_deg<<<N_EDGES / 256, 256, 0, stream>>>(esrc, deg);
    k_dinv<<<(N_NODES + 255) / 256, 256, 0, stream>>>(deg, dinv);
    k_csr_partial<<<NBLK, 256, 0, stream>>>(deg, psum);
    k_csr_base<<<1, 256, 0, stream>>>(psum, pbase, rowptr);
    k_csr_rowptr<<<NBLK, 256, 0, stream>>>(deg, pbase, rowptr);

    // multisplit CSR edge ordering (replaces atomic scatter)
    k_ms_count<<<NB1, 256, 0, stream>>>(esrc, Cm);
    k_ms_scan_partial<<<NBKT, 256, 0, stream>>>(Cm, psum2);
    k_ms_scan_base<<<1, 256, 0, stream>>>(psum2, pb2);
    k_ms_scan_add<<<NBKT, 256, 0, stream>>>(Cm, pb2, Om);
    k_ms_scatter<<<NB1, 256, 0, stream>>>(esrc, edst, Om, tmp);
    k_ms_sort<<<NBKT, 256, 0, stream>>>(rowptr, tmp, edst_s);

    k_gemm<0><<<dim3(MPAD / 128, 4), 256, 0, stream>>>(xb, WtIn, hb, b_in,
                                                       nullptr, nullptr, nullptr, nullptr);
    k_ln<<<MPAD / 4, 256, 0, stream>>>(hb, hq, stepr, ln_g, ln_b, a0A, a1A, invn);
    k_edge_dot<<<(N_NODES + 3) / 4, 256, 0, stream>>>(rowptr, edst_s, hq, stepr, rest);

    k_layer<0><<<(N_NODES + 3) / 4, 256, 0, stream>>>(rowptr, edst_s, rest,
                                                      a0A, a1A, invn, dinv, a0B, a1B, nullptr);
    k_layer<0><<<(N_NODES + 3) / 4, 256, 0, stream>>>(rowptr, edst_s, rest,
                                                      a0B, a1B, invn, dinv, a0A, a1A, nullptr);
    k_layer<1><<<(N_NODES + 3) / 4, 256, 0, stream>>>(rowptr, edst_s, rest,
                                                      a0A, a1A, invn, dinv, a0B, a1B, hb);

    k_gemm<1><<<dim3(MPAD / 128, 4), 256, 0, stream>>>(hb, W1t, zb, cb1,
                                                       bn_g, bn_b, bn_mean, bn_var);
    k_final<<<MPAD / 128, 256, 0, stream>>>(zb, W2b, cb2, out);
}

// Round 8
// 420.301 us; speedup vs baseline: 1.6729x; 1.1364x over previous
//
#include <hip/hip_runtime.h>
#include <hip/hip_bf16.h>
#include <math.h>

typedef unsigned short u16;
typedef unsigned int u32;

#define N_NODES 50000
#define N_EDGES 1600000
#define DIM     512
#define DOUT    40
#define MPAD    50048   // 391 * 128
#define QROW    256     // int4 row bytes
#define NBKT    196     // buckets = src>>8
#define NB1     256     // multisplit pass-1 blocks
#define CHUNK   6250    // edges per pass-1 block (256*6250 = 1.6M exactly)

typedef __bf16 bf16x8 __attribute__((ext_vector_type(8)));
typedef float  f32x4  __attribute__((ext_vector_type(4)));

__device__ inline u16 f2bf(float f) {
    union { float f; u32 u; } v; v.f = f;
    u32 u = v.u;
    u32 r = u + 0x7fffu + ((u >> 16) & 1u);   // RNE
    return (u16)(r >> 16);
}
__device__ inline float2 bfpair(u32 u) {
    float2 r;
    union { u32 i; float f; } lo, hi;
    lo.i = u << 16; hi.i = u & 0xffff0000u;
    r.x = lo.f; r.y = hi.f; return r;
}
__device__ inline float wave_sum(float v) {
    #pragma unroll
    for (int o = 32; o > 0; o >>= 1) v += __shfl_xor(v, o);
    return v;
}
__device__ inline float wave_max(float v) {
    #pragma unroll
    for (int o = 32; o > 0; o >>= 1) v = fmaxf(v, __shfl_xor(v, o));
    return v;
}
__device__ inline int wave_sum_i(int v) {
    #pragma unroll
    for (int o = 32; o > 0; o >>= 1) v += __shfl_xor(v, o);
    return v;
}
#if __has_builtin(__builtin_amdgcn_sdot8)
__device__ inline int dot8(int a, int b, int c) {
    return __builtin_amdgcn_sdot8(a, b, c, false);
}
#else
__device__ inline int dot8(int a, int b, int c) {
    #pragma unroll
    for (int j = 0; j < 8; ++j) {
        int av = ((int)((u32)a << (28 - 4 * j))) >> 28;
        int bv = ((int)((u32)b << (28 - 4 * j))) >> 28;
        c += av * bv;
    }
    return c;
}
#endif
// inclusive scan over a 256-thread block
__device__ inline int block_incl_scan(int v, int tid) {
    int lane = tid & 63, w = tid >> 6;
    #pragma unroll
    for (int o = 1; o < 64; o <<= 1) {
        int t = __shfl_up(v, o);
        if (lane >= o) v += t;
    }
    __shared__ int wsum[4];
    if (lane == 63) wsum[w] = v;
    __syncthreads();
    if (w > 0) v += wsum[0];
    if (w > 1) v += wsum[1];
    if (w > 2) v += wsum[2];
    return v;
}

// ---------------- weight transposes (both 512x512 in one launch) ----------------
__global__ __launch_bounds__(256) void k_transpose2(const float* __restrict__ W0,
                                                    const float* __restrict__ W1,
                                                    u16* __restrict__ T0,
                                                    u16* __restrict__ T1) {
    const float* W = blockIdx.z ? W1 : W0;
    u16* T = blockIdx.z ? T1 : T0;
    int n = blockIdx.x * 16 + threadIdx.x;
    int k = blockIdx.y * 16 + threadIdx.y;
    T[(long)n * 512 + k] = f2bf(W[(long)k * 512 + n]);
}
// cW2 [512][40] f32 -> W2b [48][512] bf16, rows 40..47 zeroed
__global__ __launch_bounds__(256) void k_prep_w2(const float* __restrict__ cW2,
                                                 u16* __restrict__ W2b) {
    int idx = blockIdx.x * 256 + threadIdx.x;   // 0 .. 48*512-1
    if (idx >= 48 * DIM) return;
    int n = idx >> 9;        // out col (0..47)
    int k = idx & 511;       // in dim
    float v = (n < DOUT) ? cW2[(long)k * DOUT + n] : 0.f;
    W2b[idx] = f2bf(v);
}

// ---------------- multisplit (no global atomics) ----------------
// C[bucket][block] layout, flat idx = bucket*NB1 + block.
__global__ __launch_bounds__(256) void k_ms_count(const int* __restrict__ esrc,
                                                  int* __restrict__ C) {
    __shared__ int bcnt[NBKT];
    int tid = threadIdx.x, blk = blockIdx.x;
    if (tid < NBKT) bcnt[tid] = 0;
    __syncthreads();
    int e0 = blk * CHUNK, e1 = e0 + CHUNK;
    for (int e = e0 + tid; e < e1; e += 256)
        atomicAdd(&bcnt[esrc[e] >> 8], 1);
    __syncthreads();
    if (tid < NBKT) C[tid * NB1 + blk] = bcnt[tid];
}
__global__ __launch_bounds__(256) void k_ms_scan_partial(const int* __restrict__ C,
                                                         int* __restrict__ psum2) {
    int v = C[blockIdx.x * 256 + threadIdx.x];
    int t = wave_sum_i(v);
    __shared__ int ws[4];
    int lane = threadIdx.x & 63, w = threadIdx.x >> 6;
    if (lane == 0) ws[w] = t;
    __syncthreads();
    if (threadIdx.x == 0) psum2[blockIdx.x] = ws[0] + ws[1] + ws[2] + ws[3];
}
__global__ __launch_bounds__(256) void k_ms_scan_base(const int* __restrict__ psum2,
                                                      int* __restrict__ pb2) {
    int tid = threadIdx.x;
    int v = (tid < NBKT) ? psum2[tid] : 0;
    int incl = block_incl_scan(v, tid);
    if (tid < NBKT) pb2[tid] = incl - v;
}
__global__ __launch_bounds__(256) void k_ms_scan_add(const int* __restrict__ C,
                                                     const int* __restrict__ pb2,
                                                     int* __restrict__ O) {
    int idx = blockIdx.x * 256 + threadIdx.x;
    int v = C[idx];
    int incl = block_incl_scan(v, threadIdx.x);
    O[idx] = pb2[blockIdx.x] + incl - v;
}
// pass 1c: write (src,dst) pairs bucket-major; per-(bucket,block) runs contiguous.
__global__ __launch_bounds__(256) void k_ms_scatter(const int* __restrict__ esrc,
                                                    const int* __restrict__ edst,
                                                    const int* __restrict__ O,
                                                    uint2* __restrict__ tmp) {
    __shared__ int cur[NBKT];
    int tid = threadIdx.x, blk = blockIdx.x;
    if (tid < NBKT) cur[tid] = O[tid * NB1 + blk];
    __syncthreads();
    int e0 = blk * CHUNK, e1 = e0 + CHUNK;
    for (int e = e0 + tid; e < e1; e += 256) {
        int s = esrc[e], d = edst[e];
        int pos = atomicAdd(&cur[s >> 8], 1);
        uint2 pr; pr.x = (u32)s; pr.y = (u32)d;
        tmp[pos] = pr;
    }
}
// fused pass 2: per-bucket LDS histogram -> rowptr + dinv + CSR scatter.
// Replaces k_deg / k_dinv / csr_partial / csr_base / csr_rowptr / ms_sort.
__global__ __launch_bounds__(256) void k_bucket(const int* __restrict__ Om,
                                                const uint2* __restrict__ tmp,
                                                int* __restrict__ rowptr,
                                                float* __restrict__ dinv,
                                                int* __restrict__ edst_s) {
    __shared__ int cnt[256];
    __shared__ int curs[256];
    int tid = threadIdx.x, b = blockIdx.x;
    int base = b * 256;
    int start = Om[b * NB1];
    int end = (b == NBKT - 1) ? N_EDGES : Om[(b + 1) * NB1];
    cnt[tid] = 0;
    __syncthreads();
    for (int p = start + tid; p < end; p += 256)
        atomicAdd(&cnt[(int)tmp[p].x - base], 1);
    __syncthreads();
    int c = cnt[tid];
    int incl = block_incl_scan(c, tid);
    int excl = incl - c;
    int node = base + tid;
    if (node < N_NODES) {
        rowptr[node] = start + excl;
        dinv[node] = (c > 0) ? (1.f / sqrtf((float)c)) : 0.f;
    }
    if (b == NBKT - 1 && tid == 0) rowptr[N_NODES] = N_EDGES;
    curs[tid] = start + excl;
    __syncthreads();
    for (int p = start + tid; p < end; p += 256) {
        uint2 pr = tmp[p];
        int pos = atomicAdd(&curs[(int)pr.x - base], 1);
        edst_s[pos] = (int)pr.y;
    }
}

// ---------------- bf16 MFMA GEMM: out = epilogue(A @ Bt^T) ----------------
// AF32=1: A is f32 [MPAD? no, N_NODES][512]; converts to bf16 in staging, pad rows -> 0.
template<int EPI, int AF32>
__global__ __launch_bounds__(256) void k_gemm(const void* __restrict__ Ap,
                                              const u16* __restrict__ Bt,
                                              u16* __restrict__ outB,
                                              const float* __restrict__ bias,
                                              const float* __restrict__ bn_g,
                                              const float* __restrict__ bn_b,
                                              const float* __restrict__ bn_mean,
                                              const float* __restrict__ bn_var) {
    __shared__ u16 lds[2 * 128 * 64];  // 32 KB: A tile then B tile
    char* ldsA = (char*)lds;
    char* ldsB = (char*)lds + 16384;
    const u16* Ab = (const u16*)Ap;
    const float* Af = (const float*)Ap;

    const int tid = threadIdx.x;
    const int tm = blockIdx.x, tn = blockIdx.y;
    const int l = tid & 63, wid = tid >> 6;
    const int wr = wid >> 1, wc = wid & 1;
    const int lm = l & 15, lk = l >> 4;

    const int srow0 = tid >> 3;            // staging row base (0..31)
    const int scole = (tid & 7) * 8;       // staging elem col (0..56)
    const int scolb = scole * 2;           // byte col

    f32x4 acc[4][4] = {};

    for (int kt = 0; kt < 8; ++kt) {
        const int k0 = kt * 64;
        #pragma unroll
        for (int r = 0; r < 4; ++r) {
            int row = r * 32 + srow0;
            uint4 va;
            if (AF32) {
                long gr = (long)tm * 128 + row;
                if (gr < N_NODES) {
                    const float4* src = (const float4*)(Af + gr * DIM + k0 + scole);
                    float4 f0 = src[0], f1 = src[1];
                    va.x = (u32)f2bf(f0.x) | ((u32)f2bf(f0.y) << 16);
                    va.y = (u32)f2bf(f0.z) | ((u32)f2bf(f0.w) << 16);
                    va.z = (u32)f2bf(f1.x) | ((u32)f2bf(f1.y) << 16);
                    va.w = (u32)f2bf(f1.z) | ((u32)f2bf(f1.w) << 16);
                } else {
                    va.x = va.y = va.z = va.w = 0u;
                }
            } else {
                va = *(const uint4*)(Ab + ((long)tm * 128 + row) * DIM + k0 + scole);
            }
            *(uint4*)(ldsA + row * 128 + (scolb ^ ((row & 7) << 4))) = va;
            uint4 vb = *(const uint4*)(Bt + ((long)tn * 128 + row) * DIM + k0 + scole);
            *(uint4*)(ldsB + row * 128 + (scolb ^ ((row & 7) << 4))) = vb;
        }
        __syncthreads();
        #pragma unroll
        for (int kk = 0; kk < 2; ++kk) {
            bf16x8 af[4], bfr[4];
            #pragma unroll
            for (int m = 0; m < 4; ++m) {
                int ar = wr * 64 + m * 16 + lm;
                af[m] = *(const bf16x8*)(ldsA + ar * 128 + ((kk * 64 + lk * 16) ^ ((ar & 7) << 4)));
            }
            #pragma unroll
            for (int n = 0; n < 4; ++n) {
                int br = wc * 64 + n * 16 + lm;
                bfr[n] = *(const bf16x8*)(ldsB + br * 128 + ((kk * 64 + lk * 16) ^ ((br & 7) << 4)));
            }
            #pragma unroll
            for (int m = 0; m < 4; ++m)
                #pragma unroll
                for (int n = 0; n < 4; ++n)
                    acc[m][n] = __builtin_amdgcn_mfma_f32_16x16x32_bf16(af[m], bfr[n], acc[m][n], 0, 0, 0);
        }
        __syncthreads();
    }

    #pragma unroll
    for (int n = 0; n < 4; ++n) {
        int col = tn * 128 + wc * 64 + n * 16 + lm;
        float bc = bias[col];
        float scale = 0.f, shift = 0.f;
        if (EPI == 1) {
            scale = bn_g[col] / sqrtf(bn_var[col] + 1e-5f);
            shift = bn_b[col] - bn_mean[col] * scale;
        }
        #pragma unroll
        for (int m = 0; m < 4; ++m) {
            f32x4 v = acc[m][n];
            #pragma unroll
            for (int r = 0; r < 4; ++r) {
                long row = (long)tm * 128 + wr * 64 + m * 16 + lk * 4 + r;
                float val = fmaxf(v[r] + bc, 0.f);
                if (EPI == 1) val = val * scale + shift;
                outB[row * DIM + col] = f2bf(val);
            }
        }
    }
}

// ---------------- LayerNorm (in-place on hb) + int4-quantized normalized row ----------------
__global__ __launch_bounds__(256) void k_ln(u16* __restrict__ hb,
                                            char* __restrict__ hq,
                                            float* __restrict__ stepr,
                                            const float* __restrict__ g,
                                            const float* __restrict__ b,
                                            float* __restrict__ a0,
                                            float* __restrict__ a1,
                                            float* __restrict__ inv_nrm) {
    int row = blockIdx.x * 4 + (threadIdx.x >> 6);
    int l = threadIdx.x & 63;
    u16* prow = hb + (long)row * DIM + l * 8;
    if (row >= N_NODES) {
        if (row < MPAD) { uint4 z; z.x = z.y = z.z = z.w = 0u; *(uint4*)prow = z; }
        return;
    }
    uint4 v = *(const uint4*)prow;
    float x[8];
    { float2 p;
      p = bfpair(v.x); x[0] = p.x; x[1] = p.y;
      p = bfpair(v.y); x[2] = p.x; x[3] = p.y;
      p = bfpair(v.z); x[4] = p.x; x[5] = p.y;
      p = bfpair(v.w); x[6] = p.x; x[7] = p.y; }
    float s = 0.f, sq = 0.f;
    #pragma unroll
    for (int j = 0; j < 8; ++j) { s += x[j]; sq += x[j] * x[j]; }
    #pragma unroll
    for (int o = 32; o > 0; o >>= 1) { s += __shfl_xor(s, o); sq += __shfl_xor(sq, o); }
    float mean = s * (1.f / DIM);
    float var = sq * (1.f / DIM) - mean * mean;
    float rstd = 1.f / sqrtf(var + 1e-5f);
    float y[8];
    #pragma unroll
    for (int j = 0; j < 8; ++j) {
        int c = l * 8 + j;
        y[j] = (x[j] - mean) * rstd * g[c] + b[c];
    }
    float s2 = 0.f;
    #pragma unroll
    for (int j = 0; j < 8; ++j) s2 += y[j] * y[j];
    s2 = wave_sum(s2);
    float nrm = sqrtf(s2);
    float inv = 1.f / (nrm + 1e-4f);
    // write LN output (bf16) for GEMM2
    ushort4 oh;
    oh.x = f2bf(y[0]); oh.y = f2bf(y[1]); oh.z = f2bf(y[2]); oh.w = f2bf(y[3]);
    *(ushort4*)prow = oh;
    oh.x = f2bf(y[4]); oh.y = f2bf(y[5]); oh.z = f2bf(y[6]); oh.w = f2bf(y[7]);
    *(ushort4*)(prow + 4) = oh;
    // quantize normalized row to int4 with per-row scale
    float nv[8];
    float mx = 0.f;
    #pragma unroll
    for (int j = 0; j < 8; ++j) { nv[j] = y[j] * inv; mx = fmaxf(mx, fabsf(nv[j])); }
    mx = wave_max(mx);
    float qs = (mx > 0.f) ? (7.f / mx) : 0.f;
    if (l == 0) { nv[0] = 0.f; nv[1] = 0.f; }   // exclude dims 0,1 from rest
    u32 w = 0;
    #pragma unroll
    for (int j = 0; j < 8; ++j) {
        int q = (int)rintf(nv[j] * qs);
        w |= ((u32)(q & 0xF)) << (4 * j);
    }
    *(u32*)(hq + (long)row * QROW + l * 4) = w;
    if (l == 0) {
        stepr[row] = (mx > 0.f) ? (mx * (1.f / 7.f)) : 0.f;
        a0[row] = y[0]; a1[row] = y[1]; inv_nrm[row] = inv;
    }
}

// ---------------- per-edge partial dot over dims 2..511, int4, CSR order ----------------
// wave per src node; 8 edges per iteration, 8 lanes per edge (16 gathers in flight).
__global__ __launch_bounds__(256) void k_edge_dot(const int* __restrict__ rowptr,
                                                  const int* __restrict__ edst_s,
                                                  const char* __restrict__ hq,
                                                  const float* __restrict__ stepr,
                                                  float* __restrict__ rest) {
    int node = blockIdx.x * 4 + (threadIdx.x >> 6);
    if (node >= N_NODES) return;
    int l = threadIdx.x & 63;
    int le = l & 7;         // lane within edge group
    int eg = l >> 3;        // edge slot 0..7
    int p0 = rowptr[node], p1 = rowptr[node + 1];
    if (p0 == p1) return;
    // src row: 32 B per lane (lanes 0..7 cover the 256B row; replicated x8)
    const int4* srow = (const int4*)(hq + (long)node * QROW);
    int4 s0 = srow[le * 2], s1 = srow[le * 2 + 1];
    float ss = stepr[node];
    #pragma unroll 2
    for (int base = p0; base < p1; base += 8) {
        int p = base + eg;
        bool ok = p < p1;
        int d = ok ? edst_s[p] : 0;
        const int4* drow = (const int4*)(hq + (long)d * QROW);
        int4 d0 = drow[le * 2], d1 = drow[le * 2 + 1];
        int acc = 0;
        acc = dot8(s0.x, d0.x, acc); acc = dot8(s0.y, d0.y, acc);
        acc = dot8(s0.z, d0.z, acc); acc = dot8(s0.w, d0.w, acc);
        acc = dot8(s1.x, d1.x, acc); acc = dot8(s1.y, d1.y, acc);
        acc = dot8(s1.z, d1.z, acc); acc = dot8(s1.w, d1.w, acc);
        acc += __shfl_xor(acc, 4);
        acc += __shfl_xor(acc, 2);
        acc += __shfl_xor(acc, 1);
        if (ok && le == 0) rest[p] = ss * stepr[d] * (float)acc;
    }
}

// ---------------- fused per-layer: segment-sum + rotate ----------------
template<int WRITE_HB>
__global__ __launch_bounds__(256) void k_layer(const int* __restrict__ rowptr,
                                               const int* __restrict__ edst_s,
                                               const float* __restrict__ rest,
                                               const float* __restrict__ a0i,
                                               const float* __restrict__ a1i,
                                               const float* __restrict__ invn,
                                               const float* __restrict__ dinv,
                                               float* __restrict__ a0o,
                                               float* __restrict__ a1o,
                                               u16* __restrict__ hb) {
    int node = blockIdx.x * 4 + (threadIdx.x >> 6);
    if (node >= N_NODES) return;
    int l = threadIdx.x & 63;
    int p0 = rowptr[node], p1 = rowptr[node + 1];
    float x = a0i[node], y = a1i[node];
    float si = invn[node];
    float sa0 = x * si, sa1 = y * si;
    float accum = 0.f;
    for (int p = p0 + l; p < p1; p += 64) {
        int d = edst_s[p];
        float c = rest[p] + (sa0 * a0i[d] + sa1 * a1i[d]) * invn[d];
        c = fminf(1.f, fmaxf(-1.f, c));
        accum += dinv[d] * c;
    }
    accum = wave_sum(accum);
    if (l == 0) {
        float ang = dinv[node] * accum;
        float sn, cs;
        sincosf(ang, &sn, &cs);
        float r0 = cs * x - sn * y;
        float r1 = sn * x + cs * y;
        a0o[node] = r0;
        a1o[node] = r1;
        if (WRITE_HB) {
            hb[(long)node * DIM + 0] = f2bf(r0);
            hb[(long)node * DIM + 1] = f2bf(r1);
        }
    }
}

// ---------------- final: logits (MFMA skinny GEMM) + log_softmax ----------------
__global__ __launch_bounds__(256) void k_final(const u16* __restrict__ zb,
                                               const u16* __restrict__ W2b,
                                               const float* __restrict__ cb2,
                                               float* __restrict__ out) {
    __shared__ char ldsB[48 * 1024];   // 48 KB, XOR-swizzled rows
    const int tid = threadIdx.x;
    #pragma unroll
    for (int i = 0; i < 12; ++i) {
        int unit = i * 256 + tid;          // 3072 x 16B units
        int byte = unit * 16;
        int row = byte >> 10;
        int colb = byte & 1023;
        uint4 v = *(const uint4*)((const char*)W2b + byte);
        *(uint4*)(ldsB + row * 1024 + (colb ^ ((row & 7) << 4))) = v;
    }
    __syncthreads();

    const int l = tid & 63, wid = tid >> 6;
    const int lm = l & 15, lk = l >> 4;
    const long m0 = (long)blockIdx.x * 128 + wid * 32;

    f32x4 acc[2][3] = {};
    for (int kt = 0; kt < 16; ++kt) {
        const int k0 = kt * 32;
        bf16x8 af[2], bfr[3];
        #pragma unroll
        for (int m = 0; m < 2; ++m)
            af[m] = *(const bf16x8*)(zb + (m0 + m * 16 + lm) * DIM + k0 + lk * 8);
        #pragma unroll
        for (int n = 0; n < 3; ++n) {
            int br = n * 16 + lm;
            bfr[n] = *(const bf16x8*)(ldsB + br * 1024 + ((k0 * 2 + lk * 16) ^ ((br & 7) << 4)));
        }
        #pragma unroll
        for (int m = 0; m < 2; ++m)
            #pragma unroll
            for (int n = 0; n < 3; ++n)
                acc[m][n] = __builtin_amdgcn_mfma_f32_16x16x32_bf16(af[m], bfr[n], acc[m][n], 0, 0, 0);
    }

    float bc[3];
    #pragma unroll
    for (int n = 0; n < 3; ++n) {
        int col = n * 16 + lm;
        bc[n] = (col < DOUT) ? cb2[col] : 0.f;
    }

    #pragma unroll
    for (int m = 0; m < 2; ++m) {
        #pragma unroll
        for (int r = 0; r < 4; ++r) {
            long row = m0 + m * 16 + lk * 4 + r;
            float v[3];
            float mv = -1e30f;
            #pragma unroll
            for (int n = 0; n < 3; ++n) {
                int col = n * 16 + lm;
                float t = (col < DOUT) ? (acc[m][n][r] + bc[n]) : -1e30f;
                v[n] = t;
                mv = fmaxf(mv, t);
            }
            #pragma unroll
            for (int o = 8; o > 0; o >>= 1) mv = fmaxf(mv, __shfl_xor(mv, o));
            float es = 0.f;
            #pragma unroll
            for (int n = 0; n < 3; ++n) {
                int col = n * 16 + lm;
                if (col < DOUT) es += expf(v[n] - mv);
            }
            #pragma unroll
            for (int o = 8; o > 0; o >>= 1) es += __shfl_xor(es, o);
            float lse = logf(es);
            if (row < N_NODES) {
                #pragma unroll
                for (int n = 0; n < 3; ++n) {
                    int col = n * 16 + lm;
                    if (col < DOUT) out[row * DOUT + col] = v[n] - mv - lse;
                }
            }
        }
    }
}

extern "C" void kernel_launch(void* const* d_in, const int* in_sizes, int n_in,
                              void* d_out, int out_size, void* d_ws, size_t ws_size,
                              hipStream_t stream) {
    const float* x       = (const float*)d_in[0];
    const int*   esrc    = (const int*)d_in[1];
    const int*   edst    = (const int*)d_in[2];
    const float* W_in    = (const float*)d_in[3];
    const float* b_in    = (const float*)d_in[4];
    const float* ln_g    = (const float*)d_in[5];
    const float* ln_b    = (const float*)d_in[6];
    const float* cW1     = (const float*)d_in[7];
    const float* cb1     = (const float*)d_in[8];
    const float* bn_g    = (const float*)d_in[9];
    const float* bn_b    = (const float*)d_in[10];
    const float* bn_mean = (const float*)d_in[11];
    const float* bn_var  = (const float*)d_in[12];
    const float* cW2     = (const float*)d_in[13];
    const float* cb2     = (const float*)d_in[14];
    float* out = (float*)d_out;

    char* ws = (char*)d_ws;
    size_t off = 0;
    auto take = [&](size_t bytes) -> char* {
        char* p = ws + off;
        off = (off + bytes + 255) & ~(size_t)255;
        return p;
    };
    u16*   zb     = (u16*)take((size_t)MPAD * DIM * 2);
    u16*   hb     = (u16*)take((size_t)MPAD * DIM * 2);
    char*  hq     = (char*)take((size_t)N_NODES * QROW);
    float* stepr  = (float*)take((size_t)N_NODES * 4);
    u16*   WtIn   = (u16*)take((size_t)512 * 512 * 2);
    u16*   W1t    = (u16*)take((size_t)512 * 512 * 2);
    u16*   W2b    = (u16*)take((size_t)48 * 512 * 2);
    float* dinv   = (float*)take((size_t)N_NODES * 4);
    float* a0A    = (float*)take((size_t)N_NODES * 4);
    float* a1A    = (float*)take((size_t)N_NODES * 4);
    float* a0B    = (float*)take((size_t)N_NODES * 4);
    float* a1B    = (float*)take((size_t)N_NODES * 4);
    float* invn   = (float*)take((size_t)N_NODES * 4);
    float* rest   = (float*)take((size_t)N_EDGES * 4);
    int*   rowptr = (int*)take((size_t)(N_NODES + 1) * 4);
    int*   edst_s = (int*)take((size_t)N_EDGES * 4);
    uint2* tmp    = (uint2*)take((size_t)N_EDGES * 8);
    int*   Cm     = (int*)take((size_t)NBKT * NB1 * 4);
    int*   Om     = (int*)take((size_t)NBKT * NB1 * 4);
    int*   psum2  = (int*)take((size_t)NBKT * 4);
    int*   pb2    = (int*)take((size_t)NBKT * 4);

    k_transpose2<<<dim3(32, 32, 2), dim3(16, 16), 0, stream>>>(W_in, cW1, WtIn, W1t);
    k_prep_w2<<<(48 * DIM + 255) / 256, 256, 0, stream>>>(cW2, W2b);

    // multisplit CSR build (no global atomics anywhere)
    k_ms_count<<<NB1, 256, 0, stream>>>(esrc, Cm);
    k_ms_scan_partial<<<NBKT, 256, 0, stream>>>(Cm, psum2);
    k_ms_scan_base<<<1, 256, 0, stream>>>(psum2, pb2);
    k_ms_scan_add<<<NBKT, 256, 0, stream>>>(Cm, pb2, Om);
    k_ms_scatter<<<NB1, 256, 0, stream>>>(esrc, edst, Om, tmp);
    k_bucket<<<NBKT, 256, 0, stream>>>(Om, tmp, rowptr, dinv, edst_s);

    // GEMM1 reads f32 x directly (conv fused into staging)
    k_gemm<0, 1><<<dim3(MPAD / 128, 4), 256, 0, stream>>>(x, WtIn, hb, b_in,
                                                          nullptr, nullptr, nullptr, nullptr);
    k_ln<<<MPAD / 4, 256, 0, stream>>>(hb, hq, stepr, ln_g, ln_b, a0A, a1A, invn);
    k_edge_dot<<<(N_NODES + 3) / 4, 256, 0, stream>>>(rowptr, edst_s, hq, stepr, rest);

    k_layer<0><<<(N_NODES + 3) / 4, 256, 0, stream>>>(rowptr, edst_s, rest,
                                                      a0A, a1A, invn, dinv, a0B, a1B, nullptr);
    k_layer<0><<<(N_NODES + 3) / 4, 256, 0, stream>>>(rowptr, edst_s, rest,
                                                      a0B, a1B, invn, dinv, a0A, a1A, nullptr);
    k_layer<1><<<(N_NODES + 3) / 4, 256, 0, stream>>>(rowptr, edst_s, rest,
                                                      a0A, a1A, invn, dinv, a0B, a1B, hb);

    k_gemm<1, 0><<<dim3(MPAD / 128, 4), 256, 0, stream>>>(hb, W1t, zb, cb1,
                                                          bn_g, bn_b, bn_mean, bn_var);
    k_final<<<MPAD / 128, 256, 0, stream>>>(zb, W2b, cb2, out);
}

// Round 9
// 417.453 us; speedup vs baseline: 1.6843x; 1.0068x over previous
//
#include <hip/hip_runtime.h>
#include <hip/hip_bf16.h>
#include <math.h>

typedef unsigned short u16;
typedef unsigned int u32;

#define N_NODES 50000
#define N_EDGES 1600000
#define DIM     512
#define DOUT    40
#define MPAD    50048   // 391 * 128
#define QROW    256     // int4 row bytes
#define NBKT    196     // buckets = src>>8
#define NB1     256     // multisplit pass-1 blocks
#define CHUNK   6250    // edges per pass-1 block (256*6250 = 1.6M exactly)

typedef __bf16 bf16x8 __attribute__((ext_vector_type(8)));
typedef float  f32x4  __attribute__((ext_vector_type(4)));

__device__ inline u16 f2bf(float f) {
    union { float f; u32 u; } v; v.f = f;
    u32 u = v.u;
    u32 r = u + 0x7fffu + ((u >> 16) & 1u);   // RNE
    return (u16)(r >> 16);
}
__device__ inline float2 bfpair(u32 u) {
    float2 r;
    union { u32 i; float f; } lo, hi;
    lo.i = u << 16; hi.i = u & 0xffff0000u;
    r.x = lo.f; r.y = hi.f; return r;
}
__device__ inline float wave_sum(float v) {
    #pragma unroll
    for (int o = 32; o > 0; o >>= 1) v += __shfl_xor(v, o);
    return v;
}
__device__ inline float wave_max(float v) {
    #pragma unroll
    for (int o = 32; o > 0; o >>= 1) v = fmaxf(v, __shfl_xor(v, o));
    return v;
}
__device__ inline int wave_sum_i(int v) {
    #pragma unroll
    for (int o = 32; o > 0; o >>= 1) v += __shfl_xor(v, o);
    return v;
}
#if __has_builtin(__builtin_amdgcn_sdot8)
__device__ inline int dot8(int a, int b, int c) {
    return __builtin_amdgcn_sdot8(a, b, c, false);
}
#else
__device__ inline int dot8(int a, int b, int c) {
    #pragma unroll
    for (int j = 0; j < 8; ++j) {
        int av = ((int)((u32)a << (28 - 4 * j))) >> 28;
        int bv = ((int)((u32)b << (28 - 4 * j))) >> 28;
        c += av * bv;
    }
    return c;
}
#endif
// inclusive scan over a 256-thread block
__device__ inline int block_incl_scan(int v, int tid) {
    int lane = tid & 63, w = tid >> 6;
    #pragma unroll
    for (int o = 1; o < 64; o <<= 1) {
        int t = __shfl_up(v, o);
        if (lane >= o) v += t;
    }
    __shared__ int wsum[4];
    if (lane == 63) wsum[w] = v;
    __syncthreads();
    if (w > 0) v += wsum[0];
    if (w > 1) v += wsum[1];
    if (w > 2) v += wsum[2];
    return v;
}

// ---------------- weight transposes (both 512x512 in one launch) ----------------
__global__ __launch_bounds__(256) void k_transpose2(const float* __restrict__ W0,
                                                    const float* __restrict__ W1,
                                                    u16* __restrict__ T0,
                                                    u16* __restrict__ T1) {
    const float* W = blockIdx.z ? W1 : W0;
    u16* T = blockIdx.z ? T1 : T0;
    int n = blockIdx.x * 16 + threadIdx.x;
    int k = blockIdx.y * 16 + threadIdx.y;
    T[(long)n * 512 + k] = f2bf(W[(long)k * 512 + n]);
}
// cW2 [512][40] f32 -> W2b [48][512] bf16, rows 40..47 zeroed
__global__ __launch_bounds__(256) void k_prep_w2(const float* __restrict__ cW2,
                                                 u16* __restrict__ W2b) {
    int idx = blockIdx.x * 256 + threadIdx.x;   // 0 .. 48*512-1
    if (idx >= 48 * DIM) return;
    int n = idx >> 9;        // out col (0..47)
    int k = idx & 511;       // in dim
    float v = (n < DOUT) ? cW2[(long)k * DOUT + n] : 0.f;
    W2b[idx] = f2bf(v);
}

// ---------------- multisplit (no global atomics) ----------------
// C[bucket][block] layout, flat idx = bucket*NB1 + block.
__global__ __launch_bounds__(256) void k_ms_count(const int* __restrict__ esrc,
                                                  int* __restrict__ C) {
    __shared__ int bcnt[NBKT];
    int tid = threadIdx.x, blk = blockIdx.x;
    if (tid < NBKT) bcnt[tid] = 0;
    __syncthreads();
    int e0 = blk * CHUNK, e1 = e0 + CHUNK;
    for (int e = e0 + tid; e < e1; e += 256)
        atomicAdd(&bcnt[esrc[e] >> 8], 1);
    __syncthreads();
    if (tid < NBKT) C[tid * NB1 + blk] = bcnt[tid];
}
__global__ __launch_bounds__(256) void k_ms_scan_partial(const int* __restrict__ C,
                                                         int* __restrict__ psum2) {
    int v = C[blockIdx.x * 256 + threadIdx.x];
    int t = wave_sum_i(v);
    __shared__ int ws[4];
    int lane = threadIdx.x & 63, w = threadIdx.x >> 6;
    if (lane == 0) ws[w] = t;
    __syncthreads();
    if (threadIdx.x == 0) psum2[blockIdx.x] = ws[0] + ws[1] + ws[2] + ws[3];
}
__global__ __launch_bounds__(256) void k_ms_scan_base(const int* __restrict__ psum2,
                                                      int* __restrict__ pb2) {
    int tid = threadIdx.x;
    int v = (tid < NBKT) ? psum2[tid] : 0;
    int incl = block_incl_scan(v, tid);
    if (tid < NBKT) pb2[tid] = incl - v;
}
__global__ __launch_bounds__(256) void k_ms_scan_add(const int* __restrict__ C,
                                                     const int* __restrict__ pb2,
                                                     int* __restrict__ O) {
    int idx = blockIdx.x * 256 + threadIdx.x;
    int v = C[idx];
    int incl = block_incl_scan(v, threadIdx.x);
    O[idx] = pb2[blockIdx.x] + incl - v;
}
// pass 1c: write (src,dst) pairs bucket-major; per-(bucket,block) runs contiguous.
__global__ __launch_bounds__(256) void k_ms_scatter(const int* __restrict__ esrc,
                                                    const int* __restrict__ edst,
                                                    const int* __restrict__ O,
                                                    uint2* __restrict__ tmp) {
    __shared__ int cur[NBKT];
    int tid = threadIdx.x, blk = blockIdx.x;
    if (tid < NBKT) cur[tid] = O[tid * NB1 + blk];
    __syncthreads();
    int e0 = blk * CHUNK, e1 = e0 + CHUNK;
    for (int e = e0 + tid; e < e1; e += 256) {
        int s = esrc[e], d = edst[e];
        int pos = atomicAdd(&cur[s >> 8], 1);
        uint2 pr; pr.x = (u32)s; pr.y = (u32)d;
        tmp[pos] = pr;
    }
}
// fused pass 2: per-bucket LDS histogram -> rowptr + dinv + CSR scatter.
__global__ __launch_bounds__(256) void k_bucket(const int* __restrict__ Om,
                                                const uint2* __restrict__ tmp,
                                                int* __restrict__ rowptr,
                                                float* __restrict__ dinv,
                                                int* __restrict__ edst_s) {
    __shared__ int cnt[256];
    __shared__ int curs[256];
    int tid = threadIdx.x, b = blockIdx.x;
    int base = b * 256;
    int start = Om[b * NB1];
    int end = (b == NBKT - 1) ? N_EDGES : Om[(b + 1) * NB1];
    cnt[tid] = 0;
    __syncthreads();
    for (int p = start + tid; p < end; p += 256)
        atomicAdd(&cnt[(int)tmp[p].x - base], 1);
    __syncthreads();
    int c = cnt[tid];
    int incl = block_incl_scan(c, tid);
    int excl = incl - c;
    int node = base + tid;
    if (node < N_NODES) {
        rowptr[node] = start + excl;
        dinv[node] = (c > 0) ? (1.f / sqrtf((float)c)) : 0.f;
    }
    if (b == NBKT - 1 && tid == 0) rowptr[N_NODES] = N_EDGES;
    curs[tid] = start + excl;
    __syncthreads();
    for (int p = start + tid; p < end; p += 256) {
        uint2 pr = tmp[p];
        int pos = atomicAdd(&curs[(int)pr.x - base], 1);
        edst_s[pos] = (int)pr.y;
    }
}

// ---------------- bf16 MFMA GEMM: out = epilogue(A @ Bt^T) ----------------
// 1D grid of 1568 blocks, XCD-swizzled so the 4 tn-blocks sharing an A-panel
// run consecutively on ONE XCD -> A re-reads hit that XCD's L2.
// AF32=1: A is f32; converts to bf16 in staging, pad rows -> 0.
template<int EPI, int AF32>
__global__ __launch_bounds__(256) void k_gemm(const void* __restrict__ Ap,
                                              const u16* __restrict__ Bt,
                                              u16* __restrict__ outB,
                                              const float* __restrict__ bias,
                                              const float* __restrict__ bn_g,
                                              const float* __restrict__ bn_b,
                                              const float* __restrict__ bn_mean,
                                              const float* __restrict__ bn_var) {
    __shared__ u16 lds[2 * 128 * 64];  // 32 KB: A tile then B tile
    char* ldsA = (char*)lds;
    char* ldsB = (char*)lds + 16384;
    const u16* Ab = (const u16*)Ap;
    const float* Af = (const float*)Ap;

    // XCD-aware decomposition: xcd = bid & 7 (round-robin dispatch), 196 blocks
    // per XCD = 49 tms x 4 tns; same-tm blocks are consecutive on one XCD.
    const int bid = blockIdx.x;
    const int xcd = bid & 7;
    const int j = bid >> 3;              // 0..195
    const int tm = xcd * 49 + (j >> 2);  // 0..391 (391 = dummy)
    const int tn = j & 3;
    if (tm >= MPAD / 128) return;

    const int tid = threadIdx.x;
    const int l = tid & 63, wid = tid >> 6;
    const int wr = wid >> 1, wc = wid & 1;
    const int lm = l & 15, lk = l >> 4;

    const int srow0 = tid >> 3;            // staging row base (0..31)
    const int scole = (tid & 7) * 8;       // staging elem col (0..56)
    const int scolb = scole * 2;           // byte col

    f32x4 acc[4][4] = {};

    for (int kt = 0; kt < 8; ++kt) {
        const int k0 = kt * 64;
        #pragma unroll
        for (int r = 0; r < 4; ++r) {
            int row = r * 32 + srow0;
            uint4 va;
            if (AF32) {
                long gr = (long)tm * 128 + row;
                if (gr < N_NODES) {
                    const float4* src = (const float4*)(Af + gr * DIM + k0 + scole);
                    float4 f0 = src[0], f1 = src[1];
                    va.x = (u32)f2bf(f0.x) | ((u32)f2bf(f0.y) << 16);
                    va.y = (u32)f2bf(f0.z) | ((u32)f2bf(f0.w) << 16);
                    va.z = (u32)f2bf(f1.x) | ((u32)f2bf(f1.y) << 16);
                    va.w = (u32)f2bf(f1.z) | ((u32)f2bf(f1.w) << 16);
                } else {
                    va.x = va.y = va.z = va.w = 0u;
                }
            } else {
                va = *(const uint4*)(Ab + ((long)tm * 128 + row) * DIM + k0 + scole);
            }
            *(uint4*)(ldsA + row * 128 + (scolb ^ ((row & 7) << 4))) = va;
            uint4 vb = *(const uint4*)(Bt + ((long)tn * 128 + row) * DIM + k0 + scole);
            *(uint4*)(ldsB + row * 128 + (scolb ^ ((row & 7) << 4))) = vb;
        }
        __syncthreads();
        #pragma unroll
        for (int kk = 0; kk < 2; ++kk) {
            bf16x8 af[4], bfr[4];
            #pragma unroll
            for (int m = 0; m < 4; ++m) {
                int ar = wr * 64 + m * 16 + lm;
                af[m] = *(const bf16x8*)(ldsA + ar * 128 + ((kk * 64 + lk * 16) ^ ((ar & 7) << 4)));
            }
            #pragma unroll
            for (int n = 0; n < 4; ++n) {
                int br = wc * 64 + n * 16 + lm;
                bfr[n] = *(const bf16x8*)(ldsB + br * 128 + ((kk * 64 + lk * 16) ^ ((br & 7) << 4)));
            }
            #pragma unroll
            for (int m = 0; m < 4; ++m)
                #pragma unroll
                for (int n = 0; n < 4; ++n)
                    acc[m][n] = __builtin_amdgcn_mfma_f32_16x16x32_bf16(af[m], bfr[n], acc[m][n], 0, 0, 0);
        }
        __syncthreads();
    }

    #pragma unroll
    for (int n = 0; n < 4; ++n) {
        int col = tn * 128 + wc * 64 + n * 16 + lm;
        float bc = bias[col];
        float scale = 0.f, shift = 0.f;
        if (EPI == 1) {
            scale = bn_g[col] / sqrtf(bn_var[col] + 1e-5f);
            shift = bn_b[col] - bn_mean[col] * scale;
        }
        #pragma unroll
        for (int m = 0; m < 4; ++m) {
            f32x4 v = acc[m][n];
            #pragma unroll
            for (int r = 0; r < 4; ++r) {
                long row = (long)tm * 128 + wr * 64 + m * 16 + lk * 4 + r;
                float val = fmaxf(v[r] + bc, 0.f);
                if (EPI == 1) val = val * scale + shift;
                outB[row * DIM + col] = f2bf(val);
            }
        }
    }
}

// ---------------- LayerNorm (in-place on hb) + int4-quantized normalized row ----------------
__global__ __launch_bounds__(256) void k_ln(u16* __restrict__ hb,
                                            char* __restrict__ hq,
                                            float* __restrict__ stepr,
                                            const float* __restrict__ g,
                                            const float* __restrict__ b,
                                            float* __restrict__ a0,
                                            float* __restrict__ a1,
                                            float* __restrict__ inv_nrm) {
    int row = blockIdx.x * 4 + (threadIdx.x >> 6);
    int l = threadIdx.x & 63;
    u16* prow = hb + (long)row * DIM + l * 8;
    if (row >= N_NODES) {
        if (row < MPAD) { uint4 z; z.x = z.y = z.z = z.w = 0u; *(uint4*)prow = z; }
        return;
    }
    uint4 v = *(const uint4*)prow;
    float x[8];
    { float2 p;
      p = bfpair(v.x); x[0] = p.x; x[1] = p.y;
      p = bfpair(v.y); x[2] = p.x; x[3] = p.y;
      p = bfpair(v.z); x[4] = p.x; x[5] = p.y;
      p = bfpair(v.w); x[6] = p.x; x[7] = p.y; }
    float s = 0.f, sq = 0.f;
    #pragma unroll
    for (int j = 0; j < 8; ++j) { s += x[j]; sq += x[j] * x[j]; }
    #pragma unroll
    for (int o = 32; o > 0; o >>= 1) { s += __shfl_xor(s, o); sq += __shfl_xor(sq, o); }
    float mean = s * (1.f / DIM);
    float var = sq * (1.f / DIM) - mean * mean;
    float rstd = 1.f / sqrtf(var + 1e-5f);
    float y[8];
    #pragma unroll
    for (int j = 0; j < 8; ++j) {
        int c = l * 8 + j;
        y[j] = (x[j] - mean) * rstd * g[c] + b[c];
    }
    float s2 = 0.f;
    #pragma unroll
    for (int j = 0; j < 8; ++j) s2 += y[j] * y[j];
    s2 = wave_sum(s2);
    float nrm = sqrtf(s2);
    float inv = 1.f / (nrm + 1e-4f);
    // write LN output (bf16) for GEMM2
    ushort4 oh;
    oh.x = f2bf(y[0]); oh.y = f2bf(y[1]); oh.z = f2bf(y[2]); oh.w = f2bf(y[3]);
    *(ushort4*)prow = oh;
    oh.x = f2bf(y[4]); oh.y = f2bf(y[5]); oh.z = f2bf(y[6]); oh.w = f2bf(y[7]);
    *(ushort4*)(prow + 4) = oh;
    // quantize normalized row to int4 with per-row scale
    float nv[8];
    float mx = 0.f;
    #pragma unroll
    for (int j = 0; j < 8; ++j) { nv[j] = y[j] * inv; mx = fmaxf(mx, fabsf(nv[j])); }
    mx = wave_max(mx);
    float qs = (mx > 0.f) ? (7.f / mx) : 0.f;
    if (l == 0) { nv[0] = 0.f; nv[1] = 0.f; }   // exclude dims 0,1 from rest
    u32 w = 0;
    #pragma unroll
    for (int j = 0; j < 8; ++j) {
        int q = (int)rintf(nv[j] * qs);
        w |= ((u32)(q & 0xF)) << (4 * j);
    }
    *(u32*)(hq + (long)row * QROW + l * 4) = w;
    if (l == 0) {
        stepr[row] = (mx > 0.f) ? (mx * (1.f / 7.f)) : 0.f;
        a0[row] = y[0]; a1[row] = y[1]; inv_nrm[row] = inv;
    }
}

// ---------------- per-edge partial dot over dims 2..511, int4, CSR order ----------------
// wave per src node; 8 edges per iteration, 8 lanes per edge (16 gathers in flight).
__global__ __launch_bounds__(256) void k_edge_dot(const int* __restrict__ rowptr,
                                                  const int* __restrict__ edst_s,
                                                  const char* __restrict__ hq,
                                                  const float* __restrict__ stepr,
                                                  float* __restrict__ rest) {
    int node = blockIdx.x * 4 + (threadIdx.x >> 6);
    if (node >= N_NODES) return;
    int l = threadIdx.x & 63;
    int le = l & 7;         // lane within edge group
    int eg = l >> 3;        // edge slot 0..7
    int p0 = rowptr[node], p1 = rowptr[node + 1];
    if (p0 == p1) return;
    // src row: 32 B per lane (lanes 0..7 cover the 256B row; replicated x8)
    const int4* srow = (const int4*)(hq + (long)node * QROW);
    int4 s0 = srow[le * 2], s1 = srow[le * 2 + 1];
    float ss = stepr[node];
    #pragma unroll 2
    for (int base = p0; base < p1; base += 8) {
        int p = base + eg;
        bool ok = p < p1;
        int d = ok ? edst_s[p] : 0;
        const int4* drow = (const int4*)(hq + (long)d * QROW);
        int4 d0 = drow[le * 2], d1 = drow[le * 2 + 1];
        int acc = 0;
        acc = dot8(s0.x, d0.x, acc); acc = dot8(s0.y, d0.y, acc);
        acc = dot8(s0.z, d0.z, acc); acc = dot8(s0.w, d0.w, acc);
        acc = dot8(s1.x, d1.x, acc); acc = dot8(s1.y, d1.y, acc);
        acc = dot8(s1.z, d1.z, acc); acc = dot8(s1.w, d1.w, acc);
        acc += __shfl_xor(acc, 4);
        acc += __shfl_xor(acc, 2);
        acc += __shfl_xor(acc, 1);
        if (ok && le == 0) rest[p] = ss * stepr[d] * (float)acc;
    }
}

// ---------------- fused per-layer: segment-sum + rotate ----------------
template<int WRITE_HB>
__global__ __launch_bounds__(256) void k_layer(const int* __restrict__ rowptr,
                                               const int* __restrict__ edst_s,
                                               const float* __restrict__ rest,
                                               const float* __restrict__ a0i,
                                               const float* __restrict__ a1i,
                                               const float* __restrict__ invn,
                                               const float* __restrict__ dinv,
                                               float* __restrict__ a0o,
                                               float* __restrict__ a1o,
                                               u16* __restrict__ hb) {
    int node = blockIdx.x * 4 + (threadIdx.x >> 6);
    if (node >= N_NODES) return;
    int l = threadIdx.x & 63;
    int p0 = rowptr[node], p1 = rowptr[node + 1];
    float x = a0i[node], y = a1i[node];
    float si = invn[node];
    float sa0 = x * si, sa1 = y * si;
    float accum = 0.f;
    for (int p = p0 + l; p < p1; p += 64) {
        int d = edst_s[p];
        float c = rest[p] + (sa0 * a0i[d] + sa1 * a1i[d]) * invn[d];
        c = fminf(1.f, fmaxf(-1.f, c));
        accum += dinv[d] * c;
    }
    accum = wave_sum(accum);
    if (l == 0) {
        float ang = dinv[node] * accum;
        float sn, cs;
        sincosf(ang, &sn, &cs);
        float r0 = cs * x - sn * y;
        float r1 = sn * x + cs * y;
        a0o[node] = r0;
        a1o[node] = r1;
        if (WRITE_HB) {
            hb[(long)node * DIM + 0] = f2bf(r0);
            hb[(long)node * DIM + 1] = f2bf(r1);
        }
    }
}

// ---------------- final: logits (MFMA skinny GEMM) + log_softmax ----------------
__global__ __launch_bounds__(256) void k_final(const u16* __restrict__ zb,
                                               const u16* __restrict__ W2b,
                                               const float* __restrict__ cb2,
                                               float* __restrict__ out) {
    __shared__ char ldsB[48 * 1024];   // 48 KB, XOR-swizzled rows
    const int tid = threadIdx.x;
    #pragma unroll
    for (int i = 0; i < 12; ++i) {
        int unit = i * 256 + tid;          // 3072 x 16B units
        int byte = unit * 16;
        int row = byte >> 10;
        int colb = byte & 1023;
        uint4 v = *(const uint4*)((const char*)W2b + byte);
        *(uint4*)(ldsB + row * 1024 + (colb ^ ((row & 7) << 4))) = v;
    }
    __syncthreads();

    const int l = tid & 63, wid = tid >> 6;
    const int lm = l & 15, lk = l >> 4;
    const long m0 = (long)blockIdx.x * 128 + wid * 32;

    f32x4 acc[2][3] = {};
    for (int kt = 0; kt < 16; ++kt) {
        const int k0 = kt * 32;
        bf16x8 af[2], bfr[3];
        #pragma unroll
        for (int m = 0; m < 2; ++m)
            af[m] = *(const bf16x8*)(zb + (m0 + m * 16 + lm) * DIM + k0 + lk * 8);
        #pragma unroll
        for (int n = 0; n < 3; ++n) {
            int br = n * 16 + lm;
            bfr[n] = *(const bf16x8*)(ldsB + br * 1024 + ((k0 * 2 + lk * 16) ^ ((br & 7) << 4)));
        }
        #pragma unroll
        for (int m = 0; m < 2; ++m)
            #pragma unroll
            for (int n = 0; n < 3; ++n)
                acc[m][n] = __builtin_amdgcn_mfma_f32_16x16x32_bf16(af[m], bfr[n], acc[m][n], 0, 0, 0);
    }

    float bc[3];
    #pragma unroll
    for (int n = 0; n < 3; ++n) {
        int col = n * 16 + lm;
        bc[n] = (col < DOUT) ? cb2[col] : 0.f;
    }

    #pragma unroll
    for (int m = 0; m < 2; ++m) {
        #pragma unroll
        for (int r = 0; r < 4; ++r) {
            long row = m0 + m * 16 + lk * 4 + r;
            float v[3];
            float mv = -1e30f;
            #pragma unroll
            for (int n = 0; n < 3; ++n) {
                int col = n * 16 + lm;
                float t = (col < DOUT) ? (acc[m][n][r] + bc[n]) : -1e30f;
                v[n] = t;
                mv = fmaxf(mv, t);
            }
            #pragma unroll
            for (int o = 8; o > 0; o >>= 1) mv = fmaxf(mv, __shfl_xor(mv, o));
            float es = 0.f;
            #pragma unroll
            for (int n = 0; n < 3; ++n) {
                int col = n * 16 + lm;
                if (col < DOUT) es += expf(v[n] - mv);
            }
            #pragma unroll
            for (int o = 8; o > 0; o >>= 1) es += __shfl_xor(es, o);
            float lse = logf(es);
            if (row < N_NODES) {
                #pragma unroll
                for (int n = 0; n < 3; ++n) {
                    int col = n * 16 + lm;
                    if (col < DOUT) out[row * DOUT + col] = v[n] - mv - lse;
                }
            }
        }
    }
}

extern "C" void kernel_launch(void* const* d_in, const int* in_sizes, int n_in,
                              void* d_out, int out_size, void* d_ws, size_t ws_size,
                              hipStream_t stream) {
    const float* x       = (const float*)d_in[0];
    const int*   esrc    = (const int*)d_in[1];
    const int*   edst    = (const int*)d_in[2];
    const float* W_in    = (const float*)d_in[3];
    const float* b_in    = (const float*)d_in[4];
    const float* ln_g    = (const float*)d_in[5];
    const float* ln_b    = (const float*)d_in[6];
    const float* cW1     = (const float*)d_in[7];
    const float* cb1     = (const float*)d_in[8];
    const float* bn_g    = (const float*)d_in[9];
    const float* bn_b    = (const float*)d_in[10];
    const float* bn_mean = (const float*)d_in[11];
    const float* bn_var  = (const float*)d_in[12];
    const float* cW2     = (const float*)d_in[13];
    const float* cb2     = (const float*)d_in[14];
    float* out = (float*)d_out;

    char* ws = (char*)d_ws;
    size_t off = 0;
    auto take = [&](size_t bytes) -> char* {
        char* p = ws + off;
        off = (off + bytes + 255) & ~(size_t)255;
        return p;
    };
    u16*   zb     = (u16*)take((size_t)MPAD * DIM * 2);
    u16*   hb     = (u16*)take((size_t)MPAD * DIM * 2);
    char*  hq     = (char*)take((size_t)N_NODES * QROW);
    float* stepr  = (float*)take((size_t)N_NODES * 4);
    u16*   WtIn   = (u16*)take((size_t)512 * 512 * 2);
    u16*   W1t    = (u16*)take((size_t)512 * 512 * 2);
    u16*   W2b    = (u16*)take((size_t)48 * 512 * 2);
    float* dinv   = (float*)take((size_t)N_NODES * 4);
    float* a0A    = (float*)take((size_t)N_NODES * 4);
    float* a1A    = (float*)take((size_t)N_NODES * 4);
    float* a0B    = (float*)take((size_t)N_NODES * 4);
    float* a1B    = (float*)take((size_t)N_NODES * 4);
    float* invn   = (float*)take((size_t)N_NODES * 4);
    float* rest   = (float*)take((size_t)N_EDGES * 4);
    int*   rowptr = (int*)take((size_t)(N_NODES + 1) * 4);
    int*   edst_s = (int*)take((size_t)N_EDGES * 4);
    uint2* tmp    = (uint2*)take((size_t)N_EDGES * 8);
    int*   Cm     = (int*)take((size_t)NBKT * NB1 * 4);
    int*   Om     = (int*)take((size_t)NBKT * NB1 * 4);
    int*   psum2  = (int*)take((size_t)NBKT * 4);
    int*   pb2    = (int*)take((size_t)NBKT * 4);

    k_transpose2<<<dim3(32, 32, 2), dim3(16, 16), 0, stream>>>(W_in, cW1, WtIn, W1t);
    k_prep_w2<<<(48 * DIM + 255) / 256, 256, 0, stream>>>(cW2, W2b);

    // multisplit CSR build (no global atomics anywhere)
    k_ms_count<<<NB1, 256, 0, stream>>>(esrc, Cm);
    k_ms_scan_partial<<<NBKT, 256, 0, stream>>>(Cm, psum2);
    k_ms_scan_base<<<1, 256, 0, stream>>>(psum2, pb2);
    k_ms_scan_add<<<NBKT, 256, 0, stream>>>(Cm, pb2, Om);
    k_ms_scatter<<<NB1, 256, 0, stream>>>(esrc, edst, Om, tmp);
    k_bucket<<<NBKT, 256, 0, stream>>>(Om, tmp, rowptr, dinv, edst_s);

    // GEMM1 reads f32 x directly (conv fused into staging); XCD-swizzled 1D grid
    k_gemm<0, 1><<<1568, 256, 0, stream>>>(x, WtIn, hb, b_in,
                                           nullptr, nullptr, nullptr, nullptr);
    k_ln<<<MPAD / 4, 256, 0, stream>>>(hb, hq, stepr, ln_g, ln_b, a0A, a1A, invn);
    k_edge_dot<<<(N_NODES + 3) / 4, 256, 0, stream>>>(rowptr, edst_s, hq, stepr, rest);

    k_layer<0><<<(N_NODES + 3) / 4, 256, 0, stream>>>(rowptr, edst_s, rest,
                                                      a0A, a1A, invn, dinv, a0B, a1B, nullptr);
    k_layer<0><<<(N_NODES + 3) / 4, 256, 0, stream>>>(rowptr, edst_s, rest,
                                                      a0B, a1B, invn, dinv, a0A, a1A, nullptr);
    k_layer<1><<<(N_NODES + 3) / 4, 256, 0, stream>>>(rowptr, edst_s, rest,
                                                      a0A, a1A, invn, dinv, a0B, a1B, hb);

    k_gemm<1, 0><<<1568, 256, 0, stream>>>(hb, W1t, zb, cb1,
                                           bn_g, bn_b, bn_mean, bn_var);
    k_final<<<MPAD / 128, 256, 0, stream>>>(zb, W2b, cb2, out);
}

// Round 10
// 363.541 us; speedup vs baseline: 1.9341x; 1.1483x over previous
//
#include <hip/hip_runtime.h>
#include <hip/hip_bf16.h>
#include <math.h>

typedef unsigned short u16;
typedef unsigned int u32;

#define N_NODES 50000
#define N_EDGES 1600000
#define DIM     512
#define DOUT    40
#define MPAD    50048   // 391 * 128
#define QROW    256     // int4 row bytes
#define NBKT    196     // buckets = src>>8
#define NB1     256     // multisplit pass-1 blocks
#define CHUNK   6250    // edges per pass-1 block (256*6250 = 1.6M exactly)

typedef __bf16 bf16x8 __attribute__((ext_vector_type(8)));
typedef float  f32x4  __attribute__((ext_vector_type(4)));

__device__ inline u16 f2bf(float f) {
    union { float f; u32 u; } v; v.f = f;
    u32 u = v.u;
    u32 r = u + 0x7fffu + ((u >> 16) & 1u);   // RNE
    return (u16)(r >> 16);
}
__device__ inline float2 bfpair(u32 u) {
    float2 r;
    union { u32 i; float f; } lo, hi;
    lo.i = u << 16; hi.i = u & 0xffff0000u;
    r.x = lo.f; r.y = hi.f; return r;
}
__device__ inline float wave_sum(float v) {
    #pragma unroll
    for (int o = 32; o > 0; o >>= 1) v += __shfl_xor(v, o);
    return v;
}
__device__ inline float wave_max(float v) {
    #pragma unroll
    for (int o = 32; o > 0; o >>= 1) v = fmaxf(v, __shfl_xor(v, o));
    return v;
}
__device__ inline int wave_sum_i(int v) {
    #pragma unroll
    for (int o = 32; o > 0; o >>= 1) v += __shfl_xor(v, o);
    return v;
}
#if __has_builtin(__builtin_amdgcn_sdot8)
__device__ inline int dot8(int a, int b, int c) {
    return __builtin_amdgcn_sdot8(a, b, c, false);
}
#else
__device__ inline int dot8(int a, int b, int c) {
    #pragma unroll
    for (int j = 0; j < 8; ++j) {
        int av = ((int)((u32)a << (28 - 4 * j))) >> 28;
        int bv = ((int)((u32)b << (28 - 4 * j))) >> 28;
        c += av * bv;
    }
    return c;
}
#endif
// async global->LDS 16B: dest is wave-uniform base + lane*16 (linear);
// swizzled layout achieved by pre-swizzling the per-lane GLOBAL source col.
__device__ inline void gload16(const void* g, void* l) {
    __builtin_amdgcn_global_load_lds((const __attribute__((address_space(1))) u32*)g,
                                     (__attribute__((address_space(3))) u32*)l, 16, 0, 0);
}
// inclusive scan over a 256-thread block
__device__ inline int block_incl_scan(int v, int tid) {
    int lane = tid & 63, w = tid >> 6;
    #pragma unroll
    for (int o = 1; o < 64; o <<= 1) {
        int t = __shfl_up(v, o);
        if (lane >= o) v += t;
    }
    __shared__ int wsum[4];
    if (lane == 63) wsum[w] = v;
    __syncthreads();
    if (w > 0) v += wsum[0];
    if (w > 1) v += wsum[1];
    if (w > 2) v += wsum[2];
    return v;
}

// ---------------- x f32 -> bf16 (padded rows zeroed) ----------------
__global__ __launch_bounds__(256) void k_conv_x(const float* __restrict__ x,
                                                u16* __restrict__ xb) {
    long idx = (long)blockIdx.x * 256 + threadIdx.x;
    long base = idx * 4;
    if (base >= (long)MPAD * DIM) return;
    long row = base >> 9;  // /512
    float4 v;
    if (row < N_NODES) v = *(const float4*)(x + base);
    else { v.x = v.y = v.z = v.w = 0.f; }
    ushort4 o;
    o.x = f2bf(v.x); o.y = f2bf(v.y); o.z = f2bf(v.z); o.w = f2bf(v.w);
    *(ushort4*)(xb + base) = o;
}

// ---------------- weight transposes (both 512x512 in one launch) ----------------
__global__ __launch_bounds__(256) void k_transpose2(const float* __restrict__ W0,
                                                    const float* __restrict__ W1,
                                                    u16* __restrict__ T0,
                                                    u16* __restrict__ T1) {
    const float* W = blockIdx.z ? W1 : W0;
    u16* T = blockIdx.z ? T1 : T0;
    int n = blockIdx.x * 16 + threadIdx.x;
    int k = blockIdx.y * 16 + threadIdx.y;
    T[(long)n * 512 + k] = f2bf(W[(long)k * 512 + n]);
}
// cW2 [512][40] f32 -> W2b [48][512] bf16, rows 40..47 zeroed
__global__ __launch_bounds__(256) void k_prep_w2(const float* __restrict__ cW2,
                                                 u16* __restrict__ W2b) {
    int idx = blockIdx.x * 256 + threadIdx.x;   // 0 .. 48*512-1
    if (idx >= 48 * DIM) return;
    int n = idx >> 9;        // out col (0..47)
    int k = idx & 511;       // in dim
    float v = (n < DOUT) ? cW2[(long)k * DOUT + n] : 0.f;
    W2b[idx] = f2bf(v);
}

// ---------------- multisplit (no global atomics) ----------------
__global__ __launch_bounds__(256) void k_ms_count(const int* __restrict__ esrc,
                                                  int* __restrict__ C) {
    __shared__ int bcnt[NBKT];
    int tid = threadIdx.x, blk = blockIdx.x;
    if (tid < NBKT) bcnt[tid] = 0;
    __syncthreads();
    int e0 = blk * CHUNK, e1 = e0 + CHUNK;
    for (int e = e0 + tid; e < e1; e += 256)
        atomicAdd(&bcnt[esrc[e] >> 8], 1);
    __syncthreads();
    if (tid < NBKT) C[tid * NB1 + blk] = bcnt[tid];
}
__global__ __launch_bounds__(256) void k_ms_scan_partial(const int* __restrict__ C,
                                                         int* __restrict__ psum2) {
    int v = C[blockIdx.x * 256 + threadIdx.x];
    int t = wave_sum_i(v);
    __shared__ int ws[4];
    int lane = threadIdx.x & 63, w = threadIdx.x >> 6;
    if (lane == 0) ws[w] = t;
    __syncthreads();
    if (threadIdx.x == 0) psum2[blockIdx.x] = ws[0] + ws[1] + ws[2] + ws[3];
}
__global__ __launch_bounds__(256) void k_ms_scan_base(const int* __restrict__ psum2,
                                                      int* __restrict__ pb2) {
    int tid = threadIdx.x;
    int v = (tid < NBKT) ? psum2[tid] : 0;
    int incl = block_incl_scan(v, tid);
    if (tid < NBKT) pb2[tid] = incl - v;
}
__global__ __launch_bounds__(256) void k_ms_scan_add(const int* __restrict__ C,
                                                     const int* __restrict__ pb2,
                                                     int* __restrict__ O) {
    int idx = blockIdx.x * 256 + threadIdx.x;
    int v = C[idx];
    int incl = block_incl_scan(v, threadIdx.x);
    O[idx] = pb2[blockIdx.x] + incl - v;
}
__global__ __launch_bounds__(256) void k_ms_scatter(const int* __restrict__ esrc,
                                                    const int* __restrict__ edst,
                                                    const int* __restrict__ O,
                                                    uint2* __restrict__ tmp) {
    __shared__ int cur[NBKT];
    int tid = threadIdx.x, blk = blockIdx.x;
    if (tid < NBKT) cur[tid] = O[tid * NB1 + blk];
    __syncthreads();
    int e0 = blk * CHUNK, e1 = e0 + CHUNK;
    for (int e = e0 + tid; e < e1; e += 256) {
        int s = esrc[e], d = edst[e];
        int pos = atomicAdd(&cur[s >> 8], 1);
        uint2 pr; pr.x = (u32)s; pr.y = (u32)d;
        tmp[pos] = pr;
    }
}
// fused pass 2: per-bucket LDS histogram -> rowptr + dinv + CSR scatter.
__global__ __launch_bounds__(256) void k_bucket(const int* __restrict__ Om,
                                                const uint2* __restrict__ tmp,
                                                int* __restrict__ rowptr,
                                                float* __restrict__ dinv,
                                                int* __restrict__ edst_s) {
    __shared__ int cnt[256];
    __shared__ int curs[256];
    int tid = threadIdx.x, b = blockIdx.x;
    int base = b * 256;
    int start = Om[b * NB1];
    int end = (b == NBKT - 1) ? N_EDGES : Om[(b + 1) * NB1];
    cnt[tid] = 0;
    __syncthreads();
    for (int p = start + tid; p < end; p += 256)
        atomicAdd(&cnt[(int)tmp[p].x - base], 1);
    __syncthreads();
    int c = cnt[tid];
    int incl = block_incl_scan(c, tid);
    int excl = incl - c;
    int node = base + tid;
    if (node < N_NODES) {
        rowptr[node] = start + excl;
        dinv[node] = (c > 0) ? (1.f / sqrtf((float)c)) : 0.f;
    }
    if (b == NBKT - 1 && tid == 0) rowptr[N_NODES] = N_EDGES;
    curs[tid] = start + excl;
    __syncthreads();
    for (int p = start + tid; p < end; p += 256) {
        uint2 pr = tmp[p];
        int pos = atomicAdd(&curs[(int)pr.x - base], 1);
        edst_s[pos] = (int)pr.y;
    }
}

// ---------------- bf16 MFMA GEMM: out = epilogue(A @ Bt^T) ----------------
// global_load_lds width=16 staging (linear LDS dest, XOR-pre-swizzled global
// source col; reads use the matching XOR). XCD-swizzled 1D grid: the 4 tn-blocks
// sharing an A-panel run consecutively on ONE XCD.
template<int EPI>
__global__ __launch_bounds__(256) void k_gemm(const u16* __restrict__ A,
                                              const u16* __restrict__ Bt,
                                              u16* __restrict__ outB,
                                              const float* __restrict__ bias,
                                              const float* __restrict__ bn_g,
                                              const float* __restrict__ bn_b,
                                              const float* __restrict__ bn_mean,
                                              const float* __restrict__ bn_var) {
    __shared__ u16 lds[2 * 128 * 64];  // 32 KB: A tile then B tile
    char* ldsA = (char*)lds;
    char* ldsB = (char*)lds + 16384;

    const int bid = blockIdx.x;
    const int xcd = bid & 7;
    const int j = bid >> 3;              // 0..195
    const int tm = xcd * 49 + (j >> 2);
    const int tn = j & 3;
    if (tm >= MPAD / 128) return;

    const int tid = threadIdx.x;
    const int l = tid & 63, wid = tid >> 6;
    const int wr = wid >> 1, wc = wid & 1;
    const int lm = l & 15, lk = l >> 4;

    const int srow = tid >> 3;             // staging row base (0..31)
    const int kq   = tid & 7;              // 16B chunk slot in 128B stripe

    f32x4 acc[4][4] = {};

    for (int kt = 0; kt < 8; ++kt) {
        const int k0 = kt * 64;
        #pragma unroll
        for (int r = 0; r < 4; ++r) {
            int row = r * 32 + srow;
            int kc = (kq ^ (row & 7)) * 8;       // pre-swizzled source col (elems)
            const u16* ga = A + ((long)tm * 128 + row) * DIM + k0 + kc;
            const u16* gb = Bt + ((long)tn * 128 + row) * DIM + k0 + kc;
            char* la = ldsA + r * 4096 + wid * 1024;   // wave-uniform base
            char* lb = ldsB + r * 4096 + wid * 1024;
            gload16(ga, la);
            gload16(gb, lb);
        }
        __syncthreads();
        #pragma unroll
        for (int kk = 0; kk < 2; ++kk) {
            bf16x8 af[4], bfr[4];
            #pragma unroll
            for (int m = 0; m < 4; ++m) {
                int ar = wr * 64 + m * 16 + lm;
                af[m] = *(const bf16x8*)(ldsA + ar * 128 + ((kk * 64 + lk * 16) ^ ((ar & 7) << 4)));
            }
            #pragma unroll
            for (int n = 0; n < 4; ++n) {
                int br = wc * 64 + n * 16 + lm;
                bfr[n] = *(const bf16x8*)(ldsB + br * 128 + ((kk * 64 + lk * 16) ^ ((br & 7) << 4)));
            }
            #pragma unroll
            for (int m = 0; m < 4; ++m)
                #pragma unroll
                for (int n = 0; n < 4; ++n)
                    acc[m][n] = __builtin_amdgcn_mfma_f32_16x16x32_bf16(af[m], bfr[n], acc[m][n], 0, 0, 0);
        }
        __syncthreads();
    }

    #pragma unroll
    for (int n = 0; n < 4; ++n) {
        int col = tn * 128 + wc * 64 + n * 16 + lm;
        float bc = bias[col];
        float scale = 0.f, shift = 0.f;
        if (EPI == 1) {
            scale = bn_g[col] / sqrtf(bn_var[col] + 1e-5f);
            shift = bn_b[col] - bn_mean[col] * scale;
        }
        #pragma unroll
        for (int m = 0; m < 4; ++m) {
            f32x4 v = acc[m][n];
            #pragma unroll
            for (int r = 0; r < 4; ++r) {
                long row = (long)tm * 128 + wr * 64 + m * 16 + lk * 4 + r;
                float val = fmaxf(v[r] + bc, 0.f);
                if (EPI == 1) val = val * scale + shift;
                outB[row * DIM + col] = f2bf(val);
            }
        }
    }
}

// ---------------- LayerNorm (in-place on hb) + int4-quantized normalized row ----------------
__global__ __launch_bounds__(256) void k_ln(u16* __restrict__ hb,
                                            char* __restrict__ hq,
                                            float* __restrict__ stepr,
                                            const float* __restrict__ g,
                                            const float* __restrict__ b,
                                            float* __restrict__ a0,
                                            float* __restrict__ a1,
                                            float* __restrict__ inv_nrm) {
    int row = blockIdx.x * 4 + (threadIdx.x >> 6);
    int l = threadIdx.x & 63;
    u16* prow = hb + (long)row * DIM + l * 8;
    if (row >= N_NODES) {
        if (row < MPAD) { uint4 z; z.x = z.y = z.z = z.w = 0u; *(uint4*)prow = z; }
        return;
    }
    uint4 v = *(const uint4*)prow;
    float x[8];
    { float2 p;
      p = bfpair(v.x); x[0] = p.x; x[1] = p.y;
      p = bfpair(v.y); x[2] = p.x; x[3] = p.y;
      p = bfpair(v.z); x[4] = p.x; x[5] = p.y;
      p = bfpair(v.w); x[6] = p.x; x[7] = p.y; }
    float s = 0.f, sq = 0.f;
    #pragma unroll
    for (int j = 0; j < 8; ++j) { s += x[j]; sq += x[j] * x[j]; }
    #pragma unroll
    for (int o = 32; o > 0; o >>= 1) { s += __shfl_xor(s, o); sq += __shfl_xor(sq, o); }
    float mean = s * (1.f / DIM);
    float var = sq * (1.f / DIM) - mean * mean;
    float rstd = 1.f / sqrtf(var + 1e-5f);
    float y[8];
    #pragma unroll
    for (int j = 0; j < 8; ++j) {
        int c = l * 8 + j;
        y[j] = (x[j] - mean) * rstd * g[c] + b[c];
    }
    float s2 = 0.f;
    #pragma unroll
    for (int j = 0; j < 8; ++j) s2 += y[j] * y[j];
    s2 = wave_sum(s2);
    float nrm = sqrtf(s2);
    float inv = 1.f / (nrm + 1e-4f);
    // write LN output (bf16) for GEMM2
    ushort4 oh;
    oh.x = f2bf(y[0]); oh.y = f2bf(y[1]); oh.z = f2bf(y[2]); oh.w = f2bf(y[3]);
    *(ushort4*)prow = oh;
    oh.x = f2bf(y[4]); oh.y = f2bf(y[5]); oh.z = f2bf(y[6]); oh.w = f2bf(y[7]);
    *(ushort4*)(prow + 4) = oh;
    // quantize normalized row to int4 with per-row scale
    float nv[8];
    float mx = 0.f;
    #pragma unroll
    for (int j = 0; j < 8; ++j) { nv[j] = y[j] * inv; mx = fmaxf(mx, fabsf(nv[j])); }
    mx = wave_max(mx);
    float qs = (mx > 0.f) ? (7.f / mx) : 0.f;
    if (l == 0) { nv[0] = 0.f; nv[1] = 0.f; }   // exclude dims 0,1 from rest
    u32 w = 0;
    #pragma unroll
    for (int j = 0; j < 8; ++j) {
        int q = (int)rintf(nv[j] * qs);
        w |= ((u32)(q & 0xF)) << (4 * j);
    }
    *(u32*)(hq + (long)row * QROW + l * 4) = w;
    if (l == 0) {
        stepr[row] = (mx > 0.f) ? (mx * (1.f / 7.f)) : 0.f;
        a0[row] = y[0]; a1[row] = y[1]; inv_nrm[row] = inv;
    }
}

// ---------------- per-edge partial dot over dims 2..511, int4, CSR order ----------------
__global__ __launch_bounds__(256) void k_edge_dot(const int* __restrict__ rowptr,
                                                  const int* __restrict__ edst_s,
                                                  const char* __restrict__ hq,
                                                  const float* __restrict__ stepr,
                                                  float* __restrict__ rest) {
    int node = blockIdx.x * 4 + (threadIdx.x >> 6);
    if (node >= N_NODES) return;
    int l = threadIdx.x & 63;
    int le = l & 7;         // lane within edge group
    int eg = l >> 3;        // edge slot 0..7
    int p0 = rowptr[node], p1 = rowptr[node + 1];
    if (p0 == p1) return;
    const int4* srow = (const int4*)(hq + (long)node * QROW);
    int4 s0 = srow[le * 2], s1 = srow[le * 2 + 1];
    float ss = stepr[node];
    #pragma unroll 2
    for (int base = p0; base < p1; base += 8) {
        int p = base + eg;
        bool ok = p < p1;
        int d = ok ? edst_s[p] : 0;
        const int4* drow = (const int4*)(hq + (long)d * QROW);
        int4 d0 = drow[le * 2], d1 = drow[le * 2 + 1];
        int acc = 0;
        acc = dot8(s0.x, d0.x, acc); acc = dot8(s0.y, d0.y, acc);
        acc = dot8(s0.z, d0.z, acc); acc = dot8(s0.w, d0.w, acc);
        acc = dot8(s1.x, d1.x, acc); acc = dot8(s1.y, d1.y, acc);
        acc = dot8(s1.z, d1.z, acc); acc = dot8(s1.w, d1.w, acc);
        acc += __shfl_xor(acc, 4);
        acc += __shfl_xor(acc, 2);
        acc += __shfl_xor(acc, 1);
        if (ok && le == 0) rest[p] = ss * stepr[d] * (float)acc;
    }
}

// ---------------- fused per-layer: segment-sum + rotate ----------------
template<int WRITE_HB>
__global__ __launch_bounds__(256) void k_layer(const int* __restrict__ rowptr,
                                               const int* __restrict__ edst_s,
                                               const float* __restrict__ rest,
                                               const float* __restrict__ a0i,
                                               const float* __restrict__ a1i,
                                               const float* __restrict__ invn,
                                               const float* __restrict__ dinv,
                                               float* __restrict__ a0o,
                                               float* __restrict__ a1o,
                                               u16* __restrict__ hb) {
    int node = blockIdx.x * 4 + (threadIdx.x >> 6);
    if (node >= N_NODES) return;
    int l = threadIdx.x & 63;
    int p0 = rowptr[node], p1 = rowptr[node + 1];
    float x = a0i[node], y = a1i[node];
    float si = invn[node];
    float sa0 = x * si, sa1 = y * si;
    float accum = 0.f;
    for (int p = p0 + l; p < p1; p += 64) {
        int d = edst_s[p];
        float c = rest[p] + (sa0 * a0i[d] + sa1 * a1i[d]) * invn[d];
        c = fminf(1.f, fmaxf(-1.f, c));
        accum += dinv[d] * c;
    }
    accum = wave_sum(accum);
    if (l == 0) {
        float ang = dinv[node] * accum;
        float sn, cs;
        sincosf(ang, &sn, &cs);
        float r0 = cs * x - sn * y;
        float r1 = sn * x + cs * y;
        a0o[node] = r0;
        a1o[node] = r1;
        if (WRITE_HB) {
            hb[(long)node * DIM + 0] = f2bf(r0);
            hb[(long)node * DIM + 1] = f2bf(r1);
        }
    }
}

// ---------------- final: logits (MFMA skinny GEMM) + log_softmax ----------------
__global__ __launch_bounds__(256) void k_final(const u16* __restrict__ zb,
                                               const u16* __restrict__ W2b,
                                               const float* __restrict__ cb2,
                                               float* __restrict__ out) {
    __shared__ char ldsB[48 * 1024];   // 48 KB, XOR-swizzled rows
    const int tid = threadIdx.x;
    #pragma unroll
    for (int i = 0; i < 12; ++i) {
        int unit = i * 256 + tid;          // 3072 x 16B units
        int byte = unit * 16;
        int row = byte >> 10;
        int colb = byte & 1023;
        uint4 v = *(const uint4*)((const char*)W2b + byte);
        *(uint4*)(ldsB + row * 1024 + (colb ^ ((row & 7) << 4))) = v;
    }
    __syncthreads();

    const int l = tid & 63, wid = tid >> 6;
    const int lm = l & 15, lk = l >> 4;
    const long m0 = (long)blockIdx.x * 128 + wid * 32;

    f32x4 acc[2][3] = {};
    for (int kt = 0; kt < 16; ++kt) {
        const int k0 = kt * 32;
        bf16x8 af[2], bfr[3];
        #pragma unroll
        for (int m = 0; m < 2; ++m)
            af[m] = *(const bf16x8*)(zb + (m0 + m * 16 + lm) * DIM + k0 + lk * 8);
        #pragma unroll
        for (int n = 0; n < 3; ++n) {
            int br = n * 16 + lm;
            bfr[n] = *(const bf16x8*)(ldsB + br * 1024 + ((k0 * 2 + lk * 16) ^ ((br & 7) << 4)));
        }
        #pragma unroll
        for (int m = 0; m < 2; ++m)
            #pragma unroll
            for (int n = 0; n < 3; ++n)
                acc[m][n] = __builtin_amdgcn_mfma_f32_16x16x32_bf16(af[m], bfr[n], acc[m][n], 0, 0, 0);
    }

    float bc[3];
    #pragma unroll
    for (int n = 0; n < 3; ++n) {
        int col = n * 16 + lm;
        bc[n] = (col < DOUT) ? cb2[col] : 0.f;
    }

    #pragma unroll
    for (int m = 0; m < 2; ++m) {
        #pragma unroll
        for (int r = 0; r < 4; ++r) {
            long row = m0 + m * 16 + lk * 4 + r;
            float v[3];
            float mv = -1e30f;
            #pragma unroll
            for (int n = 0; n < 3; ++n) {
                int col = n * 16 + lm;
                float t = (col < DOUT) ? (acc[m][n][r] + bc[n]) : -1e30f;
                v[n] = t;
                mv = fmaxf(mv, t);
            }
            #pragma unroll
            for (int o = 8; o > 0; o >>= 1) mv = fmaxf(mv, __shfl_xor(mv, o));
            float es = 0.f;
            #pragma unroll
            for (int n = 0; n < 3; ++n) {
                int col = n * 16 + lm;
                if (col < DOUT) es += expf(v[n] - mv);
            }
            #pragma unroll
            for (int o = 8; o > 0; o >>= 1) es += __shfl_xor(es, o);
            float lse = logf(es);
            if (row < N_NODES) {
                #pragma unroll
                for (int n = 0; n < 3; ++n) {
                    int col = n * 16 + lm;
                    if (col < DOUT) out[row * DOUT + col] = v[n] - mv - lse;
                }
            }
        }
    }
}

extern "C" void kernel_launch(void* const* d_in, const int* in_sizes, int n_in,
                              void* d_out, int out_size, void* d_ws, size_t ws_size,
                              hipStream_t stream) {
    const float* x       = (const float*)d_in[0];
    const int*   esrc    = (const int*)d_in[1];
    const int*   edst    = (const int*)d_in[2];
    const float* W_in    = (const float*)d_in[3];
    const float* b_in    = (const float*)d_in[4];
    const float* ln_g    = (const float*)d_in[5];
    const float* ln_b    = (const float*)d_in[6];
    const float* cW1     = (const float*)d_in[7];
    const float* cb1     = (const float*)d_in[8];
    const float* bn_g    = (const float*)d_in[9];
    const float* bn_b    = (const float*)d_in[10];
    const float* bn_mean = (const float*)d_in[11];
    const float* bn_var  = (const float*)d_in[12];
    const float* cW2     = (const float*)d_in[13];
    const float* cb2     = (const float*)d_in[14];
    float* out = (float*)d_out;

    char* ws = (char*)d_ws;
    size_t off = 0;
    auto take = [&](size_t bytes) -> char* {
        char* p = ws + off;
        off = (off + bytes + 255) & ~(size_t)255;
        return p;
    };
    u16*   xb     = (u16*)take((size_t)MPAD * DIM * 2);   // reused as zb
    u16*   hb     = (u16*)take((size_t)MPAD * DIM * 2);
    char*  hq     = (char*)take((size_t)N_NODES * QROW);
    float* stepr  = (float*)take((size_t)N_NODES * 4);
    u16*   WtIn   = (u16*)take((size_t)512 * 512 * 2);
    u16*   W1t    = (u16*)take((size_t)512 * 512 * 2);
    u16*   W2b    = (u16*)take((size_t)48 * 512 * 2);
    float* dinv   = (float*)take((size_t)N_NODES * 4);
    float* a0A    = (float*)take((size_t)N_NODES * 4);
    float* a1A    = (float*)take((size_t)N_NODES * 4);
    float* a0B    = (float*)take((size_t)N_NODES * 4);
    float* a1B    = (float*)take((size_t)N_NODES * 4);
    float* invn   = (float*)take((size_t)N_NODES * 4);
    float* rest   = (float*)take((size_t)N_EDGES * 4);
    int*   rowptr = (int*)take((size_t)(N_NODES + 1) * 4);
    int*   edst_s = (int*)take((size_t)N_EDGES * 4);
    uint2* tmp    = (uint2*)take((size_t)N_EDGES * 8);
    int*   Cm     = (int*)take((size_t)NBKT * NB1 * 4);
    int*   Om     = (int*)take((size_t)NBKT * NB1 * 4);
    int*   psum2  = (int*)take((size_t)NBKT * 4);
    int*   pb2    = (int*)take((size_t)NBKT * 4);
    u16*   zb     = xb;

    k_conv_x<<<(MPAD * DIM / 4 + 255) / 256, 256, 0, stream>>>(x, xb);
    k_transpose2<<<dim3(32, 32, 2), dim3(16, 16), 0, stream>>>(W_in, cW1, WtIn, W1t);
    k_prep_w2<<<(48 * DIM + 255) / 256, 256, 0, stream>>>(cW2, W2b);

    // multisplit CSR build (no global atomics anywhere)
    k_ms_count<<<NB1, 256, 0, stream>>>(esrc, Cm);
    k_ms_scan_partial<<<NBKT, 256, 0, stream>>>(Cm, psum2);
    k_ms_scan_base<<<1, 256, 0, stream>>>(psum2, pb2);
    k_ms_scan_add<<<NBKT, 256, 0, stream>>>(Cm, pb2, Om);
    k_ms_scatter<<<NB1, 256, 0, stream>>>(esrc, edst, Om, tmp);
    k_bucket<<<NBKT, 256, 0, stream>>>(Om, tmp, rowptr, dinv, edst_s);

    k_gemm<0><<<1568, 256, 0, stream>>>(xb, WtIn, hb, b_in,
                                        nullptr, nullptr, nullptr, nullptr);
    k_ln<<<MPAD / 4, 256, 0, stream>>>(hb, hq, stepr, ln_g, ln_b, a0A, a1A, invn);
    k_edge_dot<<<(N_NODES + 3) / 4, 256, 0, stream>>>(rowptr, edst_s, hq, stepr, rest);

    k_layer<0><<<(N_NODES + 3) / 4, 256, 0, stream>>>(rowptr, edst_s, rest,
                                                      a0A, a1A, invn, dinv, a0B, a1B, nullptr);
    k_layer<0><<<(N_NODES + 3) / 4, 256, 0, stream>>>(rowptr, edst_s, rest,
                                                      a0B, a1B, invn, dinv, a0A, a1A, nullptr);
    k_layer<1><<<(N_NODES + 3) / 4, 256, 0, stream>>>(rowptr, edst_s, rest,
                                                      a0A, a1A, invn, dinv, a0B, a1B, hb);

    k_gemm<1><<<1568, 256, 0, stream>>>(hb, W1t, zb, cb1,
                                        bn_g, bn_b, bn_mean, bn_var);
    k_final<<<MPAD / 128, 256, 0, stream>>>(zb, W2b, cb2, out);
}

// Round 11
// 342.987 us; speedup vs baseline: 2.0500x; 1.0599x over previous
//
#include <hip/hip_runtime.h>
#include <hip/hip_bf16.h>
#include <math.h>

typedef unsigned short u16;
typedef unsigned int u32;

#define N_NODES 50000
#define N_EDGES 1600000
#define DIM     512
#define DOUT    40
#define MPAD    50048   // 391 * 128
#define QROW    256     // int4 row bytes
#define NBKT    196     // buckets = src>>8
#define NB1     256     // multisplit pass-1 blocks
#define CHUNK   6250    // edges per pass-1 block (256*6250 = 1.6M exactly)

typedef __bf16 bf16x8 __attribute__((ext_vector_type(8)));
typedef float  f32x4  __attribute__((ext_vector_type(4)));

__device__ inline u16 f2bf(float f) {
    union { float f; u32 u; } v; v.f = f;
    u32 u = v.u;
    u32 r = u + 0x7fffu + ((u >> 16) & 1u);   // RNE
    return (u16)(r >> 16);
}
__device__ inline float2 bfpair(u32 u) {
    float2 r;
    union { u32 i; float f; } lo, hi;
    lo.i = u << 16; hi.i = u & 0xffff0000u;
    r.x = lo.f; r.y = hi.f; return r;
}
__device__ inline float wave_sum(float v) {
    #pragma unroll
    for (int o = 32; o > 0; o >>= 1) v += __shfl_xor(v, o);
    return v;
}
__device__ inline float wave_max(float v) {
    #pragma unroll
    for (int o = 32; o > 0; o >>= 1) v = fmaxf(v, __shfl_xor(v, o));
    return v;
}
__device__ inline int wave_sum_i(int v) {
    #pragma unroll
    for (int o = 32; o > 0; o >>= 1) v += __shfl_xor(v, o);
    return v;
}
#if __has_builtin(__builtin_amdgcn_sdot8)
__device__ inline int dot8(int a, int b, int c) {
    return __builtin_amdgcn_sdot8(a, b, c, false);
}
#else
__device__ inline int dot8(int a, int b, int c) {
    #pragma unroll
    for (int j = 0; j < 8; ++j) {
        int av = ((int)((u32)a << (28 - 4 * j))) >> 28;
        int bv = ((int)((u32)b << (28 - 4 * j))) >> 28;
        c += av * bv;
    }
    return c;
}
#endif
// async global->LDS 16B: dest is wave-uniform base + lane*16 (linear);
// swizzled layout achieved by pre-swizzling the per-lane GLOBAL source col.
__device__ inline void gload16(const void* g, void* l) {
    __builtin_amdgcn_global_load_lds((const __attribute__((address_space(1))) u32*)g,
                                     (__attribute__((address_space(3))) u32*)l, 16, 0, 0);
}
// inclusive scan over a 256-thread block
__device__ inline int block_incl_scan(int v, int tid) {
    int lane = tid & 63, w = tid >> 6;
    #pragma unroll
    for (int o = 1; o < 64; o <<= 1) {
        int t = __shfl_up(v, o);
        if (lane >= o) v += t;
    }
    __shared__ int wsum[4];
    if (lane == 63) wsum[w] = v;
    __syncthreads();
    if (w > 0) v += wsum[0];
    if (w > 1) v += wsum[1];
    if (w > 2) v += wsum[2];
    return v;
}

// ---------------- x f32 -> bf16 (padded rows zeroed) ----------------
__global__ __launch_bounds__(256) void k_conv_x(const float* __restrict__ x,
                                                u16* __restrict__ xb) {
    long idx = (long)blockIdx.x * 256 + threadIdx.x;
    long base = idx * 4;
    if (base >= (long)MPAD * DIM) return;
    long row = base >> 9;  // /512
    float4 v;
    if (row < N_NODES) v = *(const float4*)(x + base);
    else { v.x = v.y = v.z = v.w = 0.f; }
    ushort4 o;
    o.x = f2bf(v.x); o.y = f2bf(v.y); o.z = f2bf(v.z); o.w = f2bf(v.w);
    *(ushort4*)(xb + base) = o;
}

// ---------------- weight prep: both 512x512 transposes + W2 pack ----------------
__global__ __launch_bounds__(256) void k_prep(const float* __restrict__ W_in,
                                              const float* __restrict__ cW1,
                                              const float* __restrict__ cW2,
                                              u16* __restrict__ WtIn,
                                              u16* __restrict__ W1t,
                                              u16* __restrict__ W2b) {
    int z = blockIdx.z;
    if (z < 2) {
        const float* W = z ? cW1 : W_in;
        u16* T = z ? W1t : WtIn;
        int n = blockIdx.x * 16 + threadIdx.x;
        int k = blockIdx.y * 16 + threadIdx.y;
        T[(long)n * 512 + k] = f2bf(W[(long)k * 512 + n]);
    } else {
        int idx = (blockIdx.y * 32 + blockIdx.x) * 256 + threadIdx.y * 16 + threadIdx.x;
        if (idx < 48 * DIM) {
            int n = idx >> 9;        // out col (0..47)
            int k = idx & 511;       // in dim
            float v = (n < DOUT) ? cW2[(long)k * DOUT + n] : 0.f;
            W2b[idx] = f2bf(v);
        }
    }
}

// ---------------- multisplit (no global atomics) ----------------
__global__ __launch_bounds__(256) void k_ms_count(const int* __restrict__ esrc,
                                                  int* __restrict__ C) {
    __shared__ int bcnt[NBKT];
    int tid = threadIdx.x, blk = blockIdx.x;
    if (tid < NBKT) bcnt[tid] = 0;
    __syncthreads();
    int e0 = blk * CHUNK, e1 = e0 + CHUNK;
    for (int e = e0 + tid; e < e1; e += 256)
        atomicAdd(&bcnt[esrc[e] >> 8], 1);
    __syncthreads();
    if (tid < NBKT) C[tid * NB1 + blk] = bcnt[tid];
}
__global__ __launch_bounds__(256) void k_ms_scan_partial(const int* __restrict__ C,
                                                         int* __restrict__ psum2) {
    int v = C[blockIdx.x * 256 + threadIdx.x];
    int t = wave_sum_i(v);
    __shared__ int ws[4];
    int lane = threadIdx.x & 63, w = threadIdx.x >> 6;
    if (lane == 0) ws[w] = t;
    __syncthreads();
    if (threadIdx.x == 0) psum2[blockIdx.x] = ws[0] + ws[1] + ws[2] + ws[3];
}
__global__ __launch_bounds__(256) void k_ms_scan_base(const int* __restrict__ psum2,
                                                      int* __restrict__ pb2) {
    int tid = threadIdx.x;
    int v = (tid < NBKT) ? psum2[tid] : 0;
    int incl = block_incl_scan(v, tid);
    if (tid < NBKT) pb2[tid] = incl - v;
}
__global__ __launch_bounds__(256) void k_ms_scan_add(const int* __restrict__ C,
                                                     const int* __restrict__ pb2,
                                                     int* __restrict__ O) {
    int idx = blockIdx.x * 256 + threadIdx.x;
    int v = C[idx];
    int incl = block_incl_scan(v, threadIdx.x);
    O[idx] = pb2[blockIdx.x] + incl - v;
}
// pass 1c: write packed (src_local<<16 | dst) bucket-major; per-(bucket,block)
// runs contiguous so each 64B line is completed by one block (one XCD).
__global__ __launch_bounds__(256) void k_ms_scatter(const int* __restrict__ esrc,
                                                    const int* __restrict__ edst,
                                                    const int* __restrict__ O,
                                                    u32* __restrict__ pk) {
    __shared__ int cur[NBKT];
    int tid = threadIdx.x, blk = blockIdx.x;
    if (tid < NBKT) cur[tid] = O[tid * NB1 + blk];
    __syncthreads();
    int e0 = blk * CHUNK, e1 = e0 + CHUNK;
    for (int e = e0 + tid; e < e1; e += 256) {
        int s = esrc[e], d = edst[e];
        int pos = atomicAdd(&cur[s >> 8], 1);
        pk[pos] = ((u32)(s & 255) << 16) | (u32)d;   // dst < 50000 < 2^16
    }
}
// fused pass 2: per-bucket LDS histogram -> rowptr + dinv + CSR scatter.
__global__ __launch_bounds__(256) void k_bucket(const int* __restrict__ Om,
                                                const u32* __restrict__ pk,
                                                int* __restrict__ rowptr,
                                                float* __restrict__ dinv,
                                                int* __restrict__ edst_s) {
    __shared__ int cnt[256];
    __shared__ int curs[256];
    int tid = threadIdx.x, b = blockIdx.x;
    int base = b * 256;
    int start = Om[b * NB1];
    int end = (b == NBKT - 1) ? N_EDGES : Om[(b + 1) * NB1];
    cnt[tid] = 0;
    __syncthreads();
    for (int p = start + tid; p < end; p += 256)
        atomicAdd(&cnt[pk[p] >> 16], 1);
    __syncthreads();
    int c = cnt[tid];
    int incl = block_incl_scan(c, tid);
    int excl = incl - c;
    int node = base + tid;
    if (node < N_NODES) {
        rowptr[node] = start + excl;
        dinv[node] = (c > 0) ? (1.f / sqrtf((float)c)) : 0.f;
    }
    if (b == NBKT - 1 && tid == 0) rowptr[N_NODES] = N_EDGES;
    curs[tid] = start + excl;
    __syncthreads();
    for (int p = start + tid; p < end; p += 256) {
        u32 pr = pk[p];
        int pos = atomicAdd(&curs[pr >> 16], 1);
        edst_s[pos] = (int)(pr & 0xFFFFu);
    }
}

// ---------------- bf16 MFMA GEMM: out = epilogue(A @ Bt^T) ----------------
// global_load_lds width=16 staging (linear LDS dest, XOR-pre-swizzled global
// source col; reads use the matching XOR). XCD-swizzled 1D grid: the 4 tn-blocks
// sharing an A-panel run consecutively on ONE XCD.
template<int EPI>
__global__ __launch_bounds__(256) void k_gemm(const u16* __restrict__ A,
                                              const u16* __restrict__ Bt,
                                              u16* __restrict__ outB,
                                              const float* __restrict__ bias,
                                              const float* __restrict__ bn_g,
                                              const float* __restrict__ bn_b,
                                              const float* __restrict__ bn_mean,
                                              const float* __restrict__ bn_var) {
    __shared__ u16 lds[2 * 128 * 64];  // 32 KB: A tile then B tile
    char* ldsA = (char*)lds;
    char* ldsB = (char*)lds + 16384;

    const int bid = blockIdx.x;
    const int xcd = bid & 7;
    const int j = bid >> 3;              // 0..195
    const int tm = xcd * 49 + (j >> 2);
    const int tn = j & 3;
    if (tm >= MPAD / 128) return;

    const int tid = threadIdx.x;
    const int l = tid & 63, wid = tid >> 6;
    const int wr = wid >> 1, wc = wid & 1;
    const int lm = l & 15, lk = l >> 4;

    const int srow = tid >> 3;             // staging row base (0..31)
    const int kq   = tid & 7;              // 16B chunk slot in 128B stripe

    f32x4 acc[4][4] = {};

    for (int kt = 0; kt < 8; ++kt) {
        const int k0 = kt * 64;
        #pragma unroll
        for (int r = 0; r < 4; ++r) {
            int row = r * 32 + srow;
            int kc = (kq ^ (row & 7)) * 8;       // pre-swizzled source col (elems)
            const u16* ga = A + ((long)tm * 128 + row) * DIM + k0 + kc;
            const u16* gb = Bt + ((long)tn * 128 + row) * DIM + k0 + kc;
            char* la = ldsA + r * 4096 + wid * 1024;   // wave-uniform base
            char* lb = ldsB + r * 4096 + wid * 1024;
            gload16(ga, la);
            gload16(gb, lb);
        }
        __syncthreads();
        #pragma unroll
        for (int kk = 0; kk < 2; ++kk) {
            bf16x8 af[4], bfr[4];
            #pragma unroll
            for (int m = 0; m < 4; ++m) {
                int ar = wr * 64 + m * 16 + lm;
                af[m] = *(const bf16x8*)(ldsA + ar * 128 + ((kk * 64 + lk * 16) ^ ((ar & 7) << 4)));
            }
            #pragma unroll
            for (int n = 0; n < 4; ++n) {
                int br = wc * 64 + n * 16 + lm;
                bfr[n] = *(const bf16x8*)(ldsB + br * 128 + ((kk * 64 + lk * 16) ^ ((br & 7) << 4)));
            }
            #pragma unroll
            for (int m = 0; m < 4; ++m)
                #pragma unroll
                for (int n = 0; n < 4; ++n)
                    acc[m][n] = __builtin_amdgcn_mfma_f32_16x16x32_bf16(af[m], bfr[n], acc[m][n], 0, 0, 0);
        }
        __syncthreads();
    }

    #pragma unroll
    for (int n = 0; n < 4; ++n) {
        int col = tn * 128 + wc * 64 + n * 16 + lm;
        float bc = bias[col];
        float scale = 0.f, shift = 0.f;
        if (EPI == 1) {
            scale = bn_g[col] / sqrtf(bn_var[col] + 1e-5f);
            shift = bn_b[col] - bn_mean[col] * scale;
        }
        #pragma unroll
        for (int m = 0; m < 4; ++m) {
            f32x4 v = acc[m][n];
            #pragma unroll
            for (int r = 0; r < 4; ++r) {
                long row = (long)tm * 128 + wr * 64 + m * 16 + lk * 4 + r;
                float val = fmaxf(v[r] + bc, 0.f);
                if (EPI == 1) val = val * scale + shift;
                outB[row * DIM + col] = f2bf(val);
            }
        }
    }
}

// ---------------- LayerNorm (in-place on hb) + int4-quantized normalized row ----------------
__global__ __launch_bounds__(256) void k_ln(u16* __restrict__ hb,
                                            char* __restrict__ hq,
                                            float* __restrict__ stepr,
                                            const float* __restrict__ g,
                                            const float* __restrict__ b,
                                            float* __restrict__ a0,
                                            float* __restrict__ a1,
                                            float* __restrict__ inv_nrm) {
    int row = blockIdx.x * 4 + (threadIdx.x >> 6);
    int l = threadIdx.x & 63;
    u16* prow = hb + (long)row * DIM + l * 8;
    if (row >= N_NODES) {
        if (row < MPAD) { uint4 z; z.x = z.y = z.z = z.w = 0u; *(uint4*)prow = z; }
        return;
    }
    uint4 v = *(const uint4*)prow;
    float x[8];
    { float2 p;
      p = bfpair(v.x); x[0] = p.x; x[1] = p.y;
      p = bfpair(v.y); x[2] = p.x; x[3] = p.y;
      p = bfpair(v.z); x[4] = p.x; x[5] = p.y;
      p = bfpair(v.w); x[6] = p.x; x[7] = p.y; }
    float s = 0.f, sq = 0.f;
    #pragma unroll
    for (int j = 0; j < 8; ++j) { s += x[j]; sq += x[j] * x[j]; }
    #pragma unroll
    for (int o = 32; o > 0; o >>= 1) { s += __shfl_xor(s, o); sq += __shfl_xor(sq, o); }
    float mean = s * (1.f / DIM);
    float var = sq * (1.f / DIM) - mean * mean;
    float rstd = 1.f / sqrtf(var + 1e-5f);
    float y[8];
    #pragma unroll
    for (int j = 0; j < 8; ++j) {
        int c = l * 8 + j;
        y[j] = (x[j] - mean) * rstd * g[c] + b[c];
    }
    float s2 = 0.f;
    #pragma unroll
    for (int j = 0; j < 8; ++j) s2 += y[j] * y[j];
    s2 = wave_sum(s2);
    float nrm = sqrtf(s2);
    float inv = 1.f / (nrm + 1e-4f);
    // write LN output (bf16) for GEMM2
    ushort4 oh;
    oh.x = f2bf(y[0]); oh.y = f2bf(y[1]); oh.z = f2bf(y[2]); oh.w = f2bf(y[3]);
    *(ushort4*)prow = oh;
    oh.x = f2bf(y[4]); oh.y = f2bf(y[5]); oh.z = f2bf(y[6]); oh.w = f2bf(y[7]);
    *(ushort4*)(prow + 4) = oh;
    // quantize normalized row to int4 with per-row scale
    float nv[8];
    float mx = 0.f;
    #pragma unroll
    for (int j = 0; j < 8; ++j) { nv[j] = y[j] * inv; mx = fmaxf(mx, fabsf(nv[j])); }
    mx = wave_max(mx);
    float qs = (mx > 0.f) ? (7.f / mx) : 0.f;
    if (l == 0) { nv[0] = 0.f; nv[1] = 0.f; }   // exclude dims 0,1 from rest
    u32 w = 0;
    #pragma unroll
    for (int j = 0; j < 8; ++j) {
        int q = (int)rintf(nv[j] * qs);
        w |= ((u32)(q & 0xF)) << (4 * j);
    }
    *(u32*)(hq + (long)row * QROW + l * 4) = w;
    if (l == 0) {
        stepr[row] = (mx > 0.f) ? (mx * (1.f / 7.f)) : 0.f;
        a0[row] = y[0]; a1[row] = y[1]; inv_nrm[row] = inv;
    }
}

// ---------------- fused: per-edge partial dot (int4) + LAYER-1 seg-sum + rotate ----
// wave per src node; 8 edges per iteration, 8 lanes per edge. Writes rest[] for
// layers 2,3 AND computes layer-1's delta/rotation inline (a0i/a1i = k_ln output).
__global__ __launch_bounds__(256) void k_edge_dot(const int* __restrict__ rowptr,
                                                  const int* __restrict__ edst_s,
                                                  const char* __restrict__ hq,
                                                  const float* __restrict__ stepr,
                                                  const float* __restrict__ a0i,
                                                  const float* __restrict__ a1i,
                                                  const float* __restrict__ invn,
                                                  const float* __restrict__ dinv,
                                                  float* __restrict__ rest,
                                                  float* __restrict__ a0o,
                                                  float* __restrict__ a1o) {
    int node = blockIdx.x * 4 + (threadIdx.x >> 6);
    if (node >= N_NODES) return;
    int l = threadIdx.x & 63;
    int le = l & 7;         // lane within edge group
    int eg = l >> 3;        // edge slot 0..7
    int p0 = rowptr[node], p1 = rowptr[node + 1];
    float xa = a0i[node], ya = a1i[node];
    if (p0 == p1) {
        if (l == 0) { a0o[node] = xa; a1o[node] = ya; }
        return;
    }
    const int4* srow = (const int4*)(hq + (long)node * QROW);
    int4 s0 = srow[le * 2], s1 = srow[le * 2 + 1];
    float ss = stepr[node];
    float si = invn[node];
    float sa0 = xa * si, sa1 = ya * si;
    float accum = 0.f;
    #pragma unroll 4
    for (int base = p0; base < p1; base += 8) {
        int p = base + eg;
        bool ok = p < p1;
        int d = ok ? edst_s[p] : 0;
        const int4* drow = (const int4*)(hq + (long)d * QROW);
        int4 d0 = drow[le * 2], d1 = drow[le * 2 + 1];
        int acc = 0;
        acc = dot8(s0.x, d0.x, acc); acc = dot8(s0.y, d0.y, acc);
        acc = dot8(s0.z, d0.z, acc); acc = dot8(s0.w, d0.w, acc);
        acc = dot8(s1.x, d1.x, acc); acc = dot8(s1.y, d1.y, acc);
        acc = dot8(s1.z, d1.z, acc); acc = dot8(s1.w, d1.w, acc);
        acc += __shfl_xor(acc, 4);
        acc += __shfl_xor(acc, 2);
        acc += __shfl_xor(acc, 1);
        if (ok && le == 0) {
            float r = ss * stepr[d] * (float)acc;
            rest[p] = r;
            float c = r + (sa0 * a0i[d] + sa1 * a1i[d]) * invn[d];
            c = fminf(1.f, fmaxf(-1.f, c));
            accum += dinv[d] * c;
        }
    }
    accum = wave_sum(accum);
    if (l == 0) {
        float ang = dinv[node] * accum;
        float sn, cs;
        sincosf(ang, &sn, &cs);
        a0o[node] = cs * xa - sn * ya;
        a1o[node] = sn * xa + cs * ya;
    }
}

// ---------------- fused per-layer: segment-sum + rotate (layers 2,3) ----------------
template<int WRITE_HB>
__global__ __launch_bounds__(256) void k_layer(const int* __restrict__ rowptr,
                                               const int* __restrict__ edst_s,
                                               const float* __restrict__ rest,
                                               const float* __restrict__ a0i,
                                               const float* __restrict__ a1i,
                                               const float* __restrict__ invn,
                                               const float* __restrict__ dinv,
                                               float* __restrict__ a0o,
                                               float* __restrict__ a1o,
                                               u16* __restrict__ hb) {
    int node = blockIdx.x * 4 + (threadIdx.x >> 6);
    if (node >= N_NODES) return;
    int l = threadIdx.x & 63;
    int p0 = rowptr[node], p1 = rowptr[node + 1];
    float x = a0i[node], y = a1i[node];
    float si = invn[node];
    float sa0 = x * si, sa1 = y * si;
    float accum = 0.f;
    for (int p = p0 + l; p < p1; p += 64) {
        int d = edst_s[p];
        float c = rest[p] + (sa0 * a0i[d] + sa1 * a1i[d]) * invn[d];
        c = fminf(1.f, fmaxf(-1.f, c));
        accum += dinv[d] * c;
    }
    accum = wave_sum(accum);
    if (l == 0) {
        float ang = dinv[node] * accum;
        float sn, cs;
        sincosf(ang, &sn, &cs);
        float r0 = cs * x - sn * y;
        float r1 = sn * x + cs * y;
        a0o[node] = r0;
        a1o[node] = r1;
        if (WRITE_HB) {
            hb[(long)node * DIM + 0] = f2bf(r0);
            hb[(long)node * DIM + 1] = f2bf(r1);
        }
    }
}

// ---------------- final: logits (MFMA skinny GEMM) + log_softmax ----------------
__global__ __launch_bounds__(256) void k_final(const u16* __restrict__ zb,
                                               const u16* __restrict__ W2b,
                                               const float* __restrict__ cb2,
                                               float* __restrict__ out) {
    __shared__ char ldsB[48 * 1024];   // 48 KB, XOR-swizzled rows
    const int tid = threadIdx.x;
    #pragma unroll
    for (int i = 0; i < 12; ++i) {
        int unit = i * 256 + tid;          // 3072 x 16B units
        int byte = unit * 16;
        int row = byte >> 10;
        int colb = byte & 1023;
        uint4 v = *(const uint4*)((const char*)W2b + byte);
        *(uint4*)(ldsB + row * 1024 + (colb ^ ((row & 7) << 4))) = v;
    }
    __syncthreads();

    const int l = tid & 63, wid = tid >> 6;
    const int lm = l & 15, lk = l >> 4;
    const long m0 = (long)blockIdx.x * 128 + wid * 32;

    f32x4 acc[2][3] = {};
    for (int kt = 0; kt < 16; ++kt) {
        const int k0 = kt * 32;
        bf16x8 af[2], bfr[3];
        #pragma unroll
        for (int m = 0; m < 2; ++m)
            af[m] = *(const bf16x8*)(zb + (m0 + m * 16 + lm) * DIM + k0 + lk * 8);
        #pragma unroll
        for (int n = 0; n < 3; ++n) {
            int br = n * 16 + lm;
            bfr[n] = *(const bf16x8*)(ldsB + br * 1024 + ((k0 * 2 + lk * 16) ^ ((br & 7) << 4)));
        }
        #pragma unroll
        for (int m = 0; m < 2; ++m)
            #pragma unroll
            for (int n = 0; n < 3; ++n)
                acc[m][n] = __builtin_amdgcn_mfma_f32_16x16x32_bf16(af[m], bfr[n], acc[m][n], 0, 0, 0);
    }

    float bc[3];
    #pragma unroll
    for (int n = 0; n < 3; ++n) {
        int col = n * 16 + lm;
        bc[n] = (col < DOUT) ? cb2[col] : 0.f;
    }

    #pragma unroll
    for (int m = 0; m < 2; ++m) {
        #pragma unroll
        for (int r = 0; r < 4; ++r) {
            long row = m0 + m * 16 + lk * 4 + r;
            float v[3];
            float mv = -1e30f;
            #pragma unroll
            for (int n = 0; n < 3; ++n) {
                int col = n * 16 + lm;
                float t = (col < DOUT) ? (acc[m][n][r] + bc[n]) : -1e30f;
                v[n] = t;
                mv = fmaxf(mv, t);
            }
            #pragma unroll
            for (int o = 8; o > 0; o >>= 1) mv = fmaxf(mv, __shfl_xor(mv, o));
            float es = 0.f;
            #pragma unroll
            for (int n = 0; n < 3; ++n) {
                int col = n * 16 + lm;
                if (col < DOUT) es += expf(v[n] - mv);
            }
            #pragma unroll
            for (int o = 8; o > 0; o >>= 1) es += __shfl_xor(es, o);
            float lse = logf(es);
            if (row < N_NODES) {
                #pragma unroll
                for (int n = 0; n < 3; ++n) {
                    int col = n * 16 + lm;
                    if (col < DOUT) out[row * DOUT + col] = v[n] - mv - lse;
                }
            }
        }
    }
}

extern "C" void kernel_launch(void* const* d_in, const int* in_sizes, int n_in,
                              void* d_out, int out_size, void* d_ws, size_t ws_size,
                              hipStream_t stream) {
    const float* x       = (const float*)d_in[0];
    const int*   esrc    = (const int*)d_in[1];
    const int*   edst    = (const int*)d_in[2];
    const float* W_in    = (const float*)d_in[3];
    const float* b_in    = (const float*)d_in[4];
    const float* ln_g    = (const float*)d_in[5];
    const float* ln_b    = (const float*)d_in[6];
    const float* cW1     = (const float*)d_in[7];
    const float* cb1     = (const float*)d_in[8];
    const float* bn_g    = (const float*)d_in[9];
    const float* bn_b    = (const float*)d_in[10];
    const float* bn_mean = (const float*)d_in[11];
    const float* bn_var  = (const float*)d_in[12];
    const float* cW2     = (const float*)d_in[13];
    const float* cb2     = (const float*)d_in[14];
    float* out = (float*)d_out;

    char* ws = (char*)d_ws;
    size_t off = 0;
    auto take = [&](size_t bytes) -> char* {
        char* p = ws + off;
        off = (off + bytes + 255) & ~(size_t)255;
        return p;
    };
    u16*   xb     = (u16*)take((size_t)MPAD * DIM * 2);   // reused as zb
    u16*   hb     = (u16*)take((size_t)MPAD * DIM * 2);
    char*  hq     = (char*)take((size_t)N_NODES * QROW);
    float* stepr  = (float*)take((size_t)N_NODES * 4);
    u16*   WtIn   = (u16*)take((size_t)512 * 512 * 2);
    u16*   W1t    = (u16*)take((size_t)512 * 512 * 2);
    u16*   W2b    = (u16*)take((size_t)48 * 512 * 2);
    float* dinv   = (float*)take((size_t)N_NODES * 4);
    float* a0A    = (float*)take((size_t)N_NODES * 4);
    float* a1A    = (float*)take((size_t)N_NODES * 4);
    float* a0B    = (float*)take((size_t)N_NODES * 4);
    float* a1B    = (float*)take((size_t)N_NODES * 4);
    float* invn   = (float*)take((size_t)N_NODES * 4);
    float* rest   = (float*)take((size_t)N_EDGES * 4);
    int*   rowptr = (int*)take((size_t)(N_NODES + 1) * 4);
    int*   edst_s = (int*)take((size_t)N_EDGES * 4);
    u32*   pk     = (u32*)take((size_t)N_EDGES * 4);
    int*   Cm     = (int*)take((size_t)NBKT * NB1 * 4);
    int*   Om     = (int*)take((size_t)NBKT * NB1 * 4);
    int*   psum2  = (int*)take((size_t)NBKT * 4);
    int*   pb2    = (int*)take((size_t)NBKT * 4);
    u16*   zb     = xb;

    k_conv_x<<<(MPAD * DIM / 4 + 255) / 256, 256, 0, stream>>>(x, xb);
    k_prep<<<dim3(32, 32, 3), dim3(16, 16), 0, stream>>>(W_in, cW1, cW2, WtIn, W1t, W2b);

    // multisplit CSR build (no global atomics anywhere)
    k_ms_count<<<NB1, 256, 0, stream>>>(esrc, Cm);
    k_ms_scan_partial<<<NBKT, 256, 0, stream>>>(Cm, psum2);
    k_ms_scan_base<<<1, 256, 0, stream>>>(psum2, pb2);
    k_ms_scan_add<<<NBKT, 256, 0, stream>>>(Cm, pb2, Om);
    k_ms_scatter<<<NB1, 256, 0, stream>>>(esrc, edst, Om, pk);
    k_bucket<<<NBKT, 256, 0, stream>>>(Om, pk, rowptr, dinv, edst_s);

    k_gemm<0><<<1568, 256, 0, stream>>>(xb, WtIn, hb, b_in,
                                        nullptr, nullptr, nullptr, nullptr);
    k_ln<<<MPAD / 4, 256, 0, stream>>>(hb, hq, stepr, ln_g, ln_b, a0A, a1A, invn);
    // edge dot + layer 1 fused: reads a0A (pre-rotation), writes a0B
    k_edge_dot<<<(N_NODES + 3) / 4, 256, 0, stream>>>(rowptr, edst_s, hq, stepr,
                                                      a0A, a1A, invn, dinv, rest, a0B, a1B);
    // layer 2: B -> A ; layer 3: A -> B (+ hb write)
    k_layer<0><<<(N_NODES + 3) / 4, 256, 0, stream>>>(rowptr, edst_s, rest,
                                                      a0B, a1B, invn, dinv, a0A, a1A, nullptr);
    k_layer<1><<<(N_NODES + 3) / 4, 256, 0, stream>>>(rowptr, edst_s, rest,
                                                      a0A, a1A, invn, dinv, a0B, a1B, hb);

    k_gemm<1><<<1568, 256, 0, stream>>>(hb, W1t, zb, cb1,
                                        bn_g, bn_b, bn_mean, bn_var);
    k_final<<<MPAD / 128, 256, 0, stream>>>(zb, W2b, cb2, out);
}

// Round 12
// 307.670 us; speedup vs baseline: 2.2853x; 1.1148x over previous
//
#include <hip/hip_runtime.h>
#include <hip/hip_bf16.h>
#include <math.h>

typedef unsigned short u16;
typedef unsigned int u32;

#define N_NODES 50000
#define N_EDGES 1600000
#define DIM     512
#define DOUT    40
#define MPAD    50048   // 391 * 128
#define QROW    256     // int4 row bytes
#define NBKT    196     // buckets = src>>8
#define NB1     256     // multisplit pass-1 blocks
#define CHUNK   6250    // edges per pass-1 block (256*6250 = 1.6M exactly)

typedef __bf16 bf16x8 __attribute__((ext_vector_type(8)));
typedef float  f32x4  __attribute__((ext_vector_type(4)));

__device__ inline u16 f2bf(float f) {
    union { float f; u32 u; } v; v.f = f;
    u32 u = v.u;
    u32 r = u + 0x7fffu + ((u >> 16) & 1u);   // RNE
    return (u16)(r >> 16);
}
__device__ inline float2 bfpair(u32 u) {
    float2 r;
    union { u32 i; float f; } lo, hi;
    lo.i = u << 16; hi.i = u & 0xffff0000u;
    r.x = lo.f; r.y = hi.f; return r;
}
__device__ inline float wave_sum(float v) {
    #pragma unroll
    for (int o = 32; o > 0; o >>= 1) v += __shfl_xor(v, o);
    return v;
}
__device__ inline float wave_max(float v) {
    #pragma unroll
    for (int o = 32; o > 0; o >>= 1) v = fmaxf(v, __shfl_xor(v, o));
    return v;
}
__device__ inline int wave_sum_i(int v) {
    #pragma unroll
    for (int o = 32; o > 0; o >>= 1) v += __shfl_xor(v, o);
    return v;
}
#if __has_builtin(__builtin_amdgcn_sdot8)
__device__ inline int dot8(int a, int b, int c) {
    return __builtin_amdgcn_sdot8(a, b, c, false);
}
#else
__device__ inline int dot8(int a, int b, int c) {
    #pragma unroll
    for (int j = 0; j < 8; ++j) {
        int av = ((int)((u32)a << (28 - 4 * j))) >> 28;
        int bv = ((int)((u32)b << (28 - 4 * j))) >> 28;
        c += av * bv;
    }
    return c;
}
#endif
// async global->LDS 16B: dest is wave-uniform base + lane*16 (linear);
// swizzled layout achieved by pre-swizzling the per-lane GLOBAL source col.
__device__ inline void gload16(const void* g, void* l) {
    __builtin_amdgcn_global_load_lds((const __attribute__((address_space(1))) u32*)g,
                                     (__attribute__((address_space(3))) u32*)l, 16, 0, 0);
}
// inclusive scan over a 256-thread block
__device__ inline int block_incl_scan(int v, int tid) {
    int lane = tid & 63, w = tid >> 6;
    #pragma unroll
    for (int o = 1; o < 64; o <<= 1) {
        int t = __shfl_up(v, o);
        if (lane >= o) v += t;
    }
    __shared__ int wsum[4];
    if (lane == 63) wsum[w] = v;
    __syncthreads();
    if (w > 0) v += wsum[0];
    if (w > 1) v += wsum[1];
    if (w > 2) v += wsum[2];
    return v;
}

// ---------------- x f32 -> bf16 (padded rows zeroed) ----------------
__global__ __launch_bounds__(256) void k_conv_x(const float* __restrict__ x,
                                                u16* __restrict__ xb) {
    long idx = (long)blockIdx.x * 256 + threadIdx.x;
    long base = idx * 4;
    if (base >= (long)MPAD * DIM) return;
    long row = base >> 9;  // /512
    float4 v;
    if (row < N_NODES) v = *(const float4*)(x + base);
    else { v.x = v.y = v.z = v.w = 0.f; }
    ushort4 o;
    o.x = f2bf(v.x); o.y = f2bf(v.y); o.z = f2bf(v.z); o.w = f2bf(v.w);
    *(ushort4*)(xb + base) = o;
}

// ---------------- weight prep: both 512x512 transposes + W2 pack ----------------
__global__ __launch_bounds__(256) void k_prep(const float* __restrict__ W_in,
                                              const float* __restrict__ cW1,
                                              const float* __restrict__ cW2,
                                              u16* __restrict__ WtIn,
                                              u16* __restrict__ W1t,
                                              u16* __restrict__ W2b) {
    int z = blockIdx.z;
    if (z < 2) {
        const float* W = z ? cW1 : W_in;
        u16* T = z ? W1t : WtIn;
        int n = blockIdx.x * 16 + threadIdx.x;
        int k = blockIdx.y * 16 + threadIdx.y;
        T[(long)n * 512 + k] = f2bf(W[(long)k * 512 + n]);
    } else {
        int idx = (blockIdx.y * 32 + blockIdx.x) * 256 + threadIdx.y * 16 + threadIdx.x;
        if (idx < 48 * DIM) {
            int n = idx >> 9;        // out col (0..47)
            int k = idx & 511;       // in dim
            float v = (n < DOUT) ? cW2[(long)k * DOUT + n] : 0.f;
            W2b[idx] = f2bf(v);
        }
    }
}

// ---------------- multisplit (no global atomics) ----------------
__global__ __launch_bounds__(256) void k_ms_count(const int* __restrict__ esrc,
                                                  int* __restrict__ C) {
    __shared__ int bcnt[NBKT];
    int tid = threadIdx.x, blk = blockIdx.x;
    if (tid < NBKT) bcnt[tid] = 0;
    __syncthreads();
    int e0 = blk * CHUNK, e1 = e0 + CHUNK;
    for (int e = e0 + tid; e < e1; e += 256)
        atomicAdd(&bcnt[esrc[e] >> 8], 1);
    __syncthreads();
    if (tid < NBKT) C[tid * NB1 + blk] = bcnt[tid];
}
__global__ __launch_bounds__(256) void k_ms_scan_partial(const int* __restrict__ C,
                                                         int* __restrict__ psum2) {
    int v = C[blockIdx.x * 256 + threadIdx.x];
    int t = wave_sum_i(v);
    __shared__ int ws[4];
    int lane = threadIdx.x & 63, w = threadIdx.x >> 6;
    if (lane == 0) ws[w] = t;
    __syncthreads();
    if (threadIdx.x == 0) psum2[blockIdx.x] = ws[0] + ws[1] + ws[2] + ws[3];
}
__global__ __launch_bounds__(256) void k_ms_scan_base(const int* __restrict__ psum2,
                                                      int* __restrict__ pb2) {
    int tid = threadIdx.x;
    int v = (tid < NBKT) ? psum2[tid] : 0;
    int incl = block_incl_scan(v, tid);
    if (tid < NBKT) pb2[tid] = incl - v;
}
__global__ __launch_bounds__(256) void k_ms_scan_add(const int* __restrict__ C,
                                                     const int* __restrict__ pb2,
                                                     int* __restrict__ O) {
    int idx = blockIdx.x * 256 + threadIdx.x;
    int v = C[idx];
    int incl = block_incl_scan(v, threadIdx.x);
    O[idx] = pb2[blockIdx.x] + incl - v;
}
// pass 1c: write packed (src_local<<16 | dst) bucket-major; per-(bucket,block)
// runs contiguous so each 64B line is completed by one block (one XCD).
__global__ __launch_bounds__(256) void k_ms_scatter(const int* __restrict__ esrc,
                                                    const int* __restrict__ edst,
                                                    const int* __restrict__ O,
                                                    u32* __restrict__ pk) {
    __shared__ int cur[NBKT];
    int tid = threadIdx.x, blk = blockIdx.x;
    if (tid < NBKT) cur[tid] = O[tid * NB1 + blk];
    __syncthreads();
    int e0 = blk * CHUNK, e1 = e0 + CHUNK;
    for (int e = e0 + tid; e < e1; e += 256) {
        int s = esrc[e], d = edst[e];
        int pos = atomicAdd(&cur[s >> 8], 1);
        pk[pos] = ((u32)(s & 255) << 16) | (u32)d;   // dst < 50000 < 2^16
    }
}
// fused pass 2: per-bucket LDS histogram -> rowptr + dinv + CSR scatter (u16 dst).
__global__ __launch_bounds__(256) void k_bucket(const int* __restrict__ Om,
                                                const u32* __restrict__ pk,
                                                int* __restrict__ rowptr,
                                                float* __restrict__ dinv,
                                                u16* __restrict__ edst_s) {
    __shared__ int cnt[256];
    __shared__ int curs[256];
    int tid = threadIdx.x, b = blockIdx.x;
    int base = b * 256;
    int start = Om[b * NB1];
    int end = (b == NBKT - 1) ? N_EDGES : Om[(b + 1) * NB1];
    cnt[tid] = 0;
    __syncthreads();
    for (int p = start + tid; p < end; p += 256)
        atomicAdd(&cnt[pk[p] >> 16], 1);
    __syncthreads();
    int c = cnt[tid];
    int incl = block_incl_scan(c, tid);
    int excl = incl - c;
    int node = base + tid;
    if (node < N_NODES) {
        rowptr[node] = start + excl;
        dinv[node] = (c > 0) ? (1.f / sqrtf((float)c)) : 0.f;
    }
    if (b == NBKT - 1 && tid == 0) rowptr[N_NODES] = N_EDGES;
    curs[tid] = start + excl;
    __syncthreads();
    for (int p = start + tid; p < end; p += 256) {
        u32 pr = pk[p];
        int pos = atomicAdd(&curs[pr >> 16], 1);
        edst_s[pos] = (u16)(pr & 0xFFFFu);
    }
}

// ---------------- bf16 MFMA GEMM: out = epilogue(A @ Bt^T) ----------------
// global_load_lds width=16 staging (linear LDS dest, XOR-pre-swizzled global
// source col; reads use the matching XOR). XCD-swizzled 1D grid: the 4 tn-blocks
// sharing an A-panel run consecutively on ONE XCD.
template<int EPI>
__global__ __launch_bounds__(256) void k_gemm(const u16* __restrict__ A,
                                              const u16* __restrict__ Bt,
                                              u16* __restrict__ outB,
                                              const float* __restrict__ bias,
                                              const float* __restrict__ bn_g,
                                              const float* __restrict__ bn_b,
                                              const float* __restrict__ bn_mean,
                                              const float* __restrict__ bn_var) {
    __shared__ u16 lds[2 * 128 * 64];  // 32 KB: A tile then B tile
    char* ldsA = (char*)lds;
    char* ldsB = (char*)lds + 16384;

    const int bid = blockIdx.x;
    const int xcd = bid & 7;
    const int j = bid >> 3;              // 0..195
    const int tm = xcd * 49 + (j >> 2);
    const int tn = j & 3;
    if (tm >= MPAD / 128) return;

    const int tid = threadIdx.x;
    const int l = tid & 63, wid = tid >> 6;
    const int wr = wid >> 1, wc = wid & 1;
    const int lm = l & 15, lk = l >> 4;

    const int srow = tid >> 3;             // staging row base (0..31)
    const int kq   = tid & 7;              // 16B chunk slot in 128B stripe

    f32x4 acc[4][4] = {};

    for (int kt = 0; kt < 8; ++kt) {
        const int k0 = kt * 64;
        #pragma unroll
        for (int r = 0; r < 4; ++r) {
            int row = r * 32 + srow;
            int kc = (kq ^ (row & 7)) * 8;       // pre-swizzled source col (elems)
            const u16* ga = A + ((long)tm * 128 + row) * DIM + k0 + kc;
            const u16* gb = Bt + ((long)tn * 128 + row) * DIM + k0 + kc;
            char* la = ldsA + r * 4096 + wid * 1024;   // wave-uniform base
            char* lb = ldsB + r * 4096 + wid * 1024;
            gload16(ga, la);
            gload16(gb, lb);
        }
        __syncthreads();
        #pragma unroll
        for (int kk = 0; kk < 2; ++kk) {
            bf16x8 af[4], bfr[4];
            #pragma unroll
            for (int m = 0; m < 4; ++m) {
                int ar = wr * 64 + m * 16 + lm;
                af[m] = *(const bf16x8*)(ldsA + ar * 128 + ((kk * 64 + lk * 16) ^ ((ar & 7) << 4)));
            }
            #pragma unroll
            for (int n = 0; n < 4; ++n) {
                int br = wc * 64 + n * 16 + lm;
                bfr[n] = *(const bf16x8*)(ldsB + br * 128 + ((kk * 64 + lk * 16) ^ ((br & 7) << 4)));
            }
            #pragma unroll
            for (int m = 0; m < 4; ++m)
                #pragma unroll
                for (int n = 0; n < 4; ++n)
                    acc[m][n] = __builtin_amdgcn_mfma_f32_16x16x32_bf16(af[m], bfr[n], acc[m][n], 0, 0, 0);
        }
        __syncthreads();
    }

    #pragma unroll
    for (int n = 0; n < 4; ++n) {
        int col = tn * 128 + wc * 64 + n * 16 + lm;
        float bc = bias[col];
        float scale = 0.f, shift = 0.f;
        if (EPI == 1) {
            scale = bn_g[col] / sqrtf(bn_var[col] + 1e-5f);
            shift = bn_b[col] - bn_mean[col] * scale;
        }
        #pragma unroll
        for (int m = 0; m < 4; ++m) {
            f32x4 v = acc[m][n];
            #pragma unroll
            for (int r = 0; r < 4; ++r) {
                long row = (long)tm * 128 + wr * 64 + m * 16 + lk * 4 + r;
                float val = fmaxf(v[r] + bc, 0.f);
                if (EPI == 1) val = val * scale + shift;
                outB[row * DIM + col] = f2bf(val);
            }
        }
    }
}

// ---------------- LayerNorm (in-place on hb) + int4 quant + nd pack ----------------
// nd[row] = {na0, na1, dinv, stepr} where na = a * invn.
__global__ __launch_bounds__(256) void k_ln(u16* __restrict__ hb,
                                            char* __restrict__ hq,
                                            const float* __restrict__ dinv,
                                            const float* __restrict__ g,
                                            const float* __restrict__ b,
                                            float* __restrict__ a0,
                                            float* __restrict__ a1,
                                            float* __restrict__ inv_nrm,
                                            float4* __restrict__ nd) {
    int row = blockIdx.x * 4 + (threadIdx.x >> 6);
    int l = threadIdx.x & 63;
    u16* prow = hb + (long)row * DIM + l * 8;
    if (row >= N_NODES) {
        if (row < MPAD) { uint4 z; z.x = z.y = z.z = z.w = 0u; *(uint4*)prow = z; }
        return;
    }
    uint4 v = *(const uint4*)prow;
    float x[8];
    { float2 p;
      p = bfpair(v.x); x[0] = p.x; x[1] = p.y;
      p = bfpair(v.y); x[2] = p.x; x[3] = p.y;
      p = bfpair(v.z); x[4] = p.x; x[5] = p.y;
      p = bfpair(v.w); x[6] = p.x; x[7] = p.y; }
    float s = 0.f, sq = 0.f;
    #pragma unroll
    for (int j = 0; j < 8; ++j) { s += x[j]; sq += x[j] * x[j]; }
    #pragma unroll
    for (int o = 32; o > 0; o >>= 1) { s += __shfl_xor(s, o); sq += __shfl_xor(sq, o); }
    float mean = s * (1.f / DIM);
    float var = sq * (1.f / DIM) - mean * mean;
    float rstd = 1.f / sqrtf(var + 1e-5f);
    float y[8];
    #pragma unroll
    for (int j = 0; j < 8; ++j) {
        int c = l * 8 + j;
        y[j] = (x[j] - mean) * rstd * g[c] + b[c];
    }
    float s2 = 0.f;
    #pragma unroll
    for (int j = 0; j < 8; ++j) s2 += y[j] * y[j];
    s2 = wave_sum(s2);
    float nrm = sqrtf(s2);
    float inv = 1.f / (nrm + 1e-4f);
    // write LN output (bf16) for GEMM2
    ushort4 oh;
    oh.x = f2bf(y[0]); oh.y = f2bf(y[1]); oh.z = f2bf(y[2]); oh.w = f2bf(y[3]);
    *(ushort4*)prow = oh;
    oh.x = f2bf(y[4]); oh.y = f2bf(y[5]); oh.z = f2bf(y[6]); oh.w = f2bf(y[7]);
    *(ushort4*)(prow + 4) = oh;
    // quantize normalized row to int4 with per-row scale
    float nv[8];
    float mx = 0.f;
    #pragma unroll
    for (int j = 0; j < 8; ++j) { nv[j] = y[j] * inv; mx = fmaxf(mx, fabsf(nv[j])); }
    mx = wave_max(mx);
    float qs = (mx > 0.f) ? (7.f / mx) : 0.f;
    if (l == 0) { nv[0] = 0.f; nv[1] = 0.f; }   // exclude dims 0,1 from rest
    u32 w = 0;
    #pragma unroll
    for (int j = 0; j < 8; ++j) {
        int q = (int)rintf(nv[j] * qs);
        w |= ((u32)(q & 0xF)) << (4 * j);
    }
    *(u32*)(hq + (long)row * QROW + l * 4) = w;
    if (l == 0) {
        float st = (mx > 0.f) ? (mx * (1.f / 7.f)) : 0.f;
        a0[row] = y[0]; a1[row] = y[1]; inv_nrm[row] = inv;
        float4 n4; n4.x = y[0] * inv; n4.y = y[1] * inv; n4.z = dinv[row]; n4.w = st;
        nd[row] = n4;
    }
}

// ---------------- fused: per-edge partial dot (int4) + LAYER-1 seg-sum + rotate ----
// wave per src node; 8 edges per iteration, 8 lanes per edge. Writes rest[] for
// layers 2,3 AND computes layer-1's delta/rotation inline. nd = {na0,na1,dinv,stepr}.
__global__ __launch_bounds__(256) void k_edge_dot(const int* __restrict__ rowptr,
                                                  const u16* __restrict__ edst_s,
                                                  const char* __restrict__ hq,
                                                  const float4* __restrict__ ndI,
                                                  const float* __restrict__ a0i,
                                                  const float* __restrict__ a1i,
                                                  const float* __restrict__ invn,
                                                  float* __restrict__ rest,
                                                  float* __restrict__ a0o,
                                                  float* __restrict__ a1o,
                                                  float4* __restrict__ ndO) {
    int node = blockIdx.x * 4 + (threadIdx.x >> 6);
    if (node >= N_NODES) return;
    int l = threadIdx.x & 63;
    int le = l & 7;         // lane within edge group
    int eg = l >> 3;        // edge slot 0..7
    int p0 = rowptr[node], p1 = rowptr[node + 1];
    float4 own = ndI[node];                   // {na0, na1, dinv, stepr}
    float xa = a0i[node], ya = a1i[node];
    if (p0 == p1) {
        if (l == 0) { a0o[node] = xa; a1o[node] = ya; ndO[node] = own; }
        return;
    }
    const int4* srow = (const int4*)(hq + (long)node * QROW);
    int4 s0 = srow[le * 2], s1 = srow[le * 2 + 1];
    float ss = own.w;
    float sa0 = own.x, sa1 = own.y;
    float accum = 0.f;
    #pragma unroll 4
    for (int base = p0; base < p1; base += 8) {
        int p = base + eg;
        bool ok = p < p1;
        int d = ok ? (int)edst_s[p] : 0;
        const int4* drow = (const int4*)(hq + (long)d * QROW);
        int4 d0 = drow[le * 2], d1 = drow[le * 2 + 1];
        int acc = 0;
        acc = dot8(s0.x, d0.x, acc); acc = dot8(s0.y, d0.y, acc);
        acc = dot8(s0.z, d0.z, acc); acc = dot8(s0.w, d0.w, acc);
        acc = dot8(s1.x, d1.x, acc); acc = dot8(s1.y, d1.y, acc);
        acc = dot8(s1.z, d1.z, acc); acc = dot8(s1.w, d1.w, acc);
        acc += __shfl_xor(acc, 4);
        acc += __shfl_xor(acc, 2);
        acc += __shfl_xor(acc, 1);
        if (ok && le == 0) {
            float4 ndd = ndI[d];
            float r = ss * ndd.w * (float)acc;
            rest[p] = r;
            float c = r + sa0 * ndd.x + sa1 * ndd.y;
            c = fminf(1.f, fmaxf(-1.f, c));
            accum += ndd.z * c;
        }
    }
    accum = wave_sum(accum);
    if (l == 0) {
        float ang = own.z * accum;
        float sn, cs;
        sincosf(ang, &sn, &cs);
        float r0 = cs * xa - sn * ya;
        float r1 = sn * xa + cs * ya;
        a0o[node] = r0;
        a1o[node] = r1;
        float inv = invn[node];
        float4 n4; n4.x = r0 * inv; n4.y = r1 * inv; n4.z = own.z; n4.w = own.w;
        ndO[node] = n4;
    }
}

// ---------------- fused per-layer: segment-sum + rotate (layers 2,3) ----------------
// WRITE_HB=1 (last layer): writes hb, skips nd/a out.
template<int WRITE_HB>
__global__ __launch_bounds__(256) void k_layer(const int* __restrict__ rowptr,
                                               const u16* __restrict__ edst_s,
                                               const float* __restrict__ rest,
                                               const float4* __restrict__ ndI,
                                               const float* __restrict__ a0i,
                                               const float* __restrict__ a1i,
                                               const float* __restrict__ invn,
                                               float* __restrict__ a0o,
                                               float* __restrict__ a1o,
                                               float4* __restrict__ ndO,
                                               u16* __restrict__ hb) {
    int node = blockIdx.x * 4 + (threadIdx.x >> 6);
    if (node >= N_NODES) return;
    int l = threadIdx.x & 63;
    int p0 = rowptr[node], p1 = rowptr[node + 1];
    float4 own = ndI[node];
    float x = a0i[node], y = a1i[node];
    float sa0 = own.x, sa1 = own.y;
    float accum = 0.f;
    for (int p = p0 + l; p < p1; p += 64) {
        int d = (int)edst_s[p];
        float4 ndd = ndI[d];
        float c = rest[p] + sa0 * ndd.x + sa1 * ndd.y;
        c = fminf(1.f, fmaxf(-1.f, c));
        accum += ndd.z * c;
    }
    accum = wave_sum(accum);
    if (l == 0) {
        float ang = own.z * accum;
        float sn, cs;
        sincosf(ang, &sn, &cs);
        float r0 = cs * x - sn * y;
        float r1 = sn * x + cs * y;
        if (WRITE_HB) {
            hb[(long)node * DIM + 0] = f2bf(r0);
            hb[(long)node * DIM + 1] = f2bf(r1);
        } else {
            a0o[node] = r0;
            a1o[node] = r1;
            float inv = invn[node];
            float4 n4; n4.x = r0 * inv; n4.y = r1 * inv; n4.z = own.z; n4.w = own.w;
            ndO[node] = n4;
        }
    }
}

// ---------------- final: logits (MFMA skinny GEMM) + log_softmax ----------------
__global__ __launch_bounds__(256) void k_final(const u16* __restrict__ zb,
                                               const u16* __restrict__ W2b,
                                               const float* __restrict__ cb2,
                                               float* __restrict__ out) {
    __shared__ char ldsB[48 * 1024];   // 48 KB, XOR-swizzled rows
    const int tid = threadIdx.x;
    #pragma unroll
    for (int i = 0; i < 12; ++i) {
        int unit = i * 256 + tid;          // 3072 x 16B units
        int byte = unit * 16;
        int row = byte >> 10;
        int colb = byte & 1023;
        uint4 v = *(const uint4*)((const char*)W2b + byte);
        *(uint4*)(ldsB + row * 1024 + (colb ^ ((row & 7) << 4))) = v;
    }
    __syncthreads();

    const int l = tid & 63, wid = tid >> 6;
    const int lm = l & 15, lk = l >> 4;
    const long m0 = (long)blockIdx.x * 128 + wid * 32;

    f32x4 acc[2][3] = {};
    for (int kt = 0; kt < 16; ++kt) {
        const int k0 = kt * 32;
        bf16x8 af[2], bfr[3];
        #pragma unroll
        for (int m = 0; m < 2; ++m)
            af[m] = *(const bf16x8*)(zb + (m0 + m * 16 + lm) * DIM + k0 + lk * 8);
        #pragma unroll
        for (int n = 0; n < 3; ++n) {
            int br = n * 16 + lm;
            bfr[n] = *(const bf16x8*)(ldsB + br * 1024 + ((k0 * 2 + lk * 16) ^ ((br & 7) << 4)));
        }
        #pragma unroll
        for (int m = 0; m < 2; ++m)
            #pragma unroll
            for (int n = 0; n < 3; ++n)
                acc[m][n] = __builtin_amdgcn_mfma_f32_16x16x32_bf16(af[m], bfr[n], acc[m][n], 0, 0, 0);
    }

    float bc[3];
    #pragma unroll
    for (int n = 0; n < 3; ++n) {
        int col = n * 16 + lm;
        bc[n] = (col < DOUT) ? cb2[col] : 0.f;
    }

    #pragma unroll
    for (int m = 0; m < 2; ++m) {
        #pragma unroll
        for (int r = 0; r < 4; ++r) {
            long row = m0 + m * 16 + lk * 4 + r;
            float v[3];
            float mv = -1e30f;
            #pragma unroll
            for (int n = 0; n < 3; ++n) {
                int col = n * 16 + lm;
                float t = (col < DOUT) ? (acc[m][n][r] + bc[n]) : -1e30f;
                v[n] = t;
                mv = fmaxf(mv, t);
            }
            #pragma unroll
            for (int o = 8; o > 0; o >>= 1) mv = fmaxf(mv, __shfl_xor(mv, o));
            float es = 0.f;
            #pragma unroll
            for (int n = 0; n < 3; ++n) {
                int col = n * 16 + lm;
                if (col < DOUT) es += expf(v[n] - mv);
            }
            #pragma unroll
            for (int o = 8; o > 0; o >>= 1) es += __shfl_xor(es, o);
            float lse = logf(es);
            if (row < N_NODES) {
                #pragma unroll
                for (int n = 0; n < 3; ++n) {
                    int col = n * 16 + lm;
                    if (col < DOUT) out[row * DOUT + col] = v[n] - mv - lse;
                }
            }
        }
    }
}

extern "C" void kernel_launch(void* const* d_in, const int* in_sizes, int n_in,
                              void* d_out, int out_size, void* d_ws, size_t ws_size,
                              hipStream_t stream) {
    const float* x       = (const float*)d_in[0];
    const int*   esrc    = (const int*)d_in[1];
    const int*   edst    = (const int*)d_in[2];
    const float* W_in    = (const float*)d_in[3];
    const float* b_in    = (const float*)d_in[4];
    const float* ln_g    = (const float*)d_in[5];
    const float* ln_b    = (const float*)d_in[6];
    const float* cW1     = (const float*)d_in[7];
    const float* cb1     = (const float*)d_in[8];
    const float* bn_g    = (const float*)d_in[9];
    const float* bn_b    = (const float*)d_in[10];
    const float* bn_mean = (const float*)d_in[11];
    const float* bn_var  = (const float*)d_in[12];
    const float* cW2     = (const float*)d_in[13];
    const float* cb2     = (const float*)d_in[14];
    float* out = (float*)d_out;

    char* ws = (char*)d_ws;
    size_t off = 0;
    auto take = [&](size_t bytes) -> char* {
        char* p = ws + off;
        off = (off + bytes + 255) & ~(size_t)255;
        return p;
    };
    u16*    xb     = (u16*)take((size_t)MPAD * DIM * 2);   // reused as zb
    u16*    hb     = (u16*)take((size_t)MPAD * DIM * 2);
    char*   hq     = (char*)take((size_t)N_NODES * QROW);
    u16*    WtIn   = (u16*)take((size_t)512 * 512 * 2);
    u16*    W1t    = (u16*)take((size_t)512 * 512 * 2);
    u16*    W2b    = (u16*)take((size_t)48 * 512 * 2);
    float*  dinv   = (float*)take((size_t)N_NODES * 4);
    float*  a0A    = (float*)take((size_t)N_NODES * 4);
    float*  a1A    = (float*)take((size_t)N_NODES * 4);
    float*  a0B    = (float*)take((size_t)N_NODES * 4);
    float*  a1B    = (float*)take((size_t)N_NODES * 4);
    float*  invn   = (float*)take((size_t)N_NODES * 4);
    float4* ndA    = (float4*)take((size_t)N_NODES * 16);
    float4* ndB    = (float4*)take((size_t)N_NODES * 16);
    float*  rest   = (float*)take((size_t)N_EDGES * 4);
    int*    rowptr = (int*)take((size_t)(N_NODES + 1) * 4);
    u16*    edst_s = (u16*)take((size_t)N_EDGES * 2);
    u32*    pk     = (u32*)take((size_t)N_EDGES * 4);
    int*    Cm     = (int*)take((size_t)NBKT * NB1 * 4);
    int*    Om     = (int*)take((size_t)NBKT * NB1 * 4);
    int*    psum2  = (int*)take((size_t)NBKT * 4);
    int*    pb2    = (int*)take((size_t)NBKT * 4);
    u16*    zb     = xb;

    k_conv_x<<<(MPAD * DIM / 4 + 255) / 256, 256, 0, stream>>>(x, xb);
    k_prep<<<dim3(32, 32, 3), dim3(16, 16), 0, stream>>>(W_in, cW1, cW2, WtIn, W1t, W2b);

    // multisplit CSR build (no global atomics anywhere)
    k_ms_count<<<NB1, 256, 0, stream>>>(esrc, Cm);
    k_ms_scan_partial<<<NBKT, 256, 0, stream>>>(Cm, psum2);
    k_ms_scan_base<<<1, 256, 0, stream>>>(psum2, pb2);
    k_ms_scan_add<<<NBKT, 256, 0, stream>>>(Cm, pb2, Om);
    k_ms_scatter<<<NB1, 256, 0, stream>>>(esrc, edst, Om, pk);
    k_bucket<<<NBKT, 256, 0, stream>>>(Om, pk, rowptr, dinv, edst_s);

    k_gemm<0><<<1568, 256, 0, stream>>>(xb, WtIn, hb, b_in,
                                        nullptr, nullptr, nullptr, nullptr);
    k_ln<<<MPAD / 4, 256, 0, stream>>>(hb, hq, dinv, ln_g, ln_b, a0A, a1A, invn, ndA);
    // edge dot + layer 1 fused: ndA -> ndB
    k_edge_dot<<<(N_NODES + 3) / 4, 256, 0, stream>>>(rowptr, edst_s, hq, ndA,
                                                      a0A, a1A, invn, rest, a0B, a1B, ndB);
    // layer 2: ndB -> ndA ; layer 3: ndA -> hb
    k_layer<0><<<(N_NODES + 3) / 4, 256, 0, stream>>>(rowptr, edst_s, rest, ndB,
                                                      a0B, a1B, invn, a0A, a1A, ndA, nullptr);
    k_layer<1><<<(N_NODES + 3) / 4, 256, 0, stream>>>(rowptr, edst_s, rest, ndA,
                                                      a0A, a1A, invn, nullptr, nullptr, nullptr, hb);

    k_gemm<1><<<1568, 256, 0, stream>>>(hb, W1t, zb, cb1,
                                        bn_g, bn_b, bn_mean, bn_var);
    k_final<<<MPAD / 128, 256, 0, stream>>>(zb, W2b, cb2, out);
}

// Round 13
// 293.593 us; speedup vs baseline: 2.3948x; 1.0479x over previous
//
#include <hip/hip_runtime.h>
#include <hip/hip_bf16.h>
#include <math.h>

typedef unsigned short u16;
typedef unsigned int u32;

#define N_NODES 50000
#define N_EDGES 1600000
#define DIM     512
#define DOUT    40
#define MPAD    50048   // 391 * 128
#define QROW    256     // int4 row bytes
#define NBKT    196     // buckets = src>>8
#define NB1     250     // multisplit pass-1 blocks
#define CHUNK   6400    // edges per pass-1 block (250*6400 = 1.6M exactly, 16B-aligned)

typedef __bf16 bf16x8 __attribute__((ext_vector_type(8)));
typedef float  f32x4  __attribute__((ext_vector_type(4)));

__device__ inline u16 f2bf(float f) {
    union { float f; u32 u; } v; v.f = f;
    u32 u = v.u;
    u32 r = u + 0x7fffu + ((u >> 16) & 1u);   // RNE
    return (u16)(r >> 16);
}
__device__ inline float bf2f(u16 u) {
    union { u32 i; float f; } v; v.i = ((u32)u) << 16; return v.f;
}
__device__ inline float2 bfpair(u32 u) {
    float2 r;
    union { u32 i; float f; } lo, hi;
    lo.i = u << 16; hi.i = u & 0xffff0000u;
    r.x = lo.f; r.y = hi.f; return r;
}
__device__ inline float wave_sum(float v) {
    #pragma unroll
    for (int o = 32; o > 0; o >>= 1) v += __shfl_xor(v, o);
    return v;
}
__device__ inline float wave_max(float v) {
    #pragma unroll
    for (int o = 32; o > 0; o >>= 1) v = fmaxf(v, __shfl_xor(v, o));
    return v;
}
__device__ inline int wave_sum_i(int v) {
    #pragma unroll
    for (int o = 32; o > 0; o >>= 1) v += __shfl_xor(v, o);
    return v;
}
#if __has_builtin(__builtin_amdgcn_sdot8)
__device__ inline int dot8(int a, int b, int c) {
    return __builtin_amdgcn_sdot8(a, b, c, false);
}
#else
__device__ inline int dot8(int a, int b, int c) {
    #pragma unroll
    for (int j = 0; j < 8; ++j) {
        int av = ((int)((u32)a << (28 - 4 * j))) >> 28;
        int bv = ((int)((u32)b << (28 - 4 * j))) >> 28;
        c += av * bv;
    }
    return c;
}
#endif
// async global->LDS 16B: dest is wave-uniform base + lane*16 (linear);
// swizzled layout achieved by pre-swizzling the per-lane GLOBAL source col.
__device__ inline void gload16(const void* g, void* l) {
    __builtin_amdgcn_global_load_lds((const __attribute__((address_space(1))) u32*)g,
                                     (__attribute__((address_space(3))) u32*)l, 16, 0, 0);
}
// inclusive scan over a 256-thread block
__device__ inline int block_incl_scan(int v, int tid) {
    int lane = tid & 63, w = tid >> 6;
    #pragma unroll
    for (int o = 1; o < 64; o <<= 1) {
        int t = __shfl_up(v, o);
        if (lane >= o) v += t;
    }
    __shared__ int wsum[4];
    if (lane == 63) wsum[w] = v;
    __syncthreads();
    if (w > 0) v += wsum[0];
    if (w > 1) v += wsum[1];
    if (w > 2) v += wsum[2];
    return v;
}

// ---------------- fused prep: x f32->bf16 conv + weight transposes + W2 pack -------
// block ranges: [0,25024) conv_x ; [25024,27072) transposes ; [27072,27168) W2.
#define CONV_BLKS 25024
__global__ __launch_bounds__(256) void k_prep(const float* __restrict__ x,
                                              u16* __restrict__ xb,
                                              const float* __restrict__ W_in,
                                              const float* __restrict__ cW1,
                                              const float* __restrict__ cW2,
                                              u16* __restrict__ WtIn,
                                              u16* __restrict__ W1t,
                                              u16* __restrict__ W2b) {
    int b = blockIdx.x, tid = threadIdx.x;
    if (b < CONV_BLKS) {
        long idx = (long)b * 256 + tid;
        long base = idx * 4;
        long row = base >> 9;  // /512
        float4 v;
        if (row < N_NODES) v = *(const float4*)(x + base);
        else { v.x = v.y = v.z = v.w = 0.f; }
        ushort4 o;
        o.x = f2bf(v.x); o.y = f2bf(v.y); o.z = f2bf(v.z); o.w = f2bf(v.w);
        *(ushort4*)(xb + base) = o;
    } else if (b < CONV_BLKS + 2048) {
        int t = b - CONV_BLKS;
        int z = t >> 10;                 // 0 or 1
        int q = t & 1023;
        const float* W = z ? cW1 : W_in;
        u16* T = z ? W1t : WtIn;
        int n = (q & 31) * 16 + (tid & 15);
        int k = (q >> 5) * 16 + (tid >> 4);
        T[(long)n * 512 + k] = f2bf(W[(long)k * 512 + n]);
    } else {
        int idx = (b - CONV_BLKS - 2048) * 256 + tid;
        if (idx < 48 * DIM) {
            int n = idx >> 9;        // out col (0..47)
            int k = idx & 511;       // in dim
            float v = (n < DOUT) ? cW2[(long)k * DOUT + n] : 0.f;
            W2b[idx] = f2bf(v);
        }
    }
}

// ---------------- multisplit (no global atomics) ----------------
// C[bucket][block] layout, flat idx = bucket*NB1 + block.
__global__ __launch_bounds__(256) void k_ms_count(const int* __restrict__ esrc,
                                                  int* __restrict__ C) {
    __shared__ int bcnt[NBKT];
    int tid = threadIdx.x, blk = blockIdx.x;
    if (tid < NBKT) bcnt[tid] = 0;
    __syncthreads();
    const int4* e4 = (const int4*)(esrc + blk * CHUNK);   // 16B-aligned
    for (int i = tid; i < CHUNK / 4; i += 256) {
        int4 v = e4[i];
        atomicAdd(&bcnt[v.x >> 8], 1);
        atomicAdd(&bcnt[v.y >> 8], 1);
        atomicAdd(&bcnt[v.z >> 8], 1);
        atomicAdd(&bcnt[v.w >> 8], 1);
    }
    __syncthreads();
    if (tid < NBKT) C[tid * NB1 + blk] = bcnt[tid];
}
__global__ __launch_bounds__(256) void k_ms_scan_partial(const int* __restrict__ C,
                                                         int* __restrict__ psum2) {
    int idx = blockIdx.x * NB1 + threadIdx.x;
    int v = (threadIdx.x < NB1) ? C[idx] : 0;
    int t = wave_sum_i(v);
    __shared__ int ws[4];
    int lane = threadIdx.x & 63, w = threadIdx.x >> 6;
    if (lane == 0) ws[w] = t;
    __syncthreads();
    if (threadIdx.x == 0) psum2[blockIdx.x] = ws[0] + ws[1] + ws[2] + ws[3];
}
__global__ __launch_bounds__(256) void k_ms_scan_base(const int* __restrict__ psum2,
                                                      int* __restrict__ pb2) {
    int tid = threadIdx.x;
    int v = (tid < NBKT) ? psum2[tid] : 0;
    int incl = block_incl_scan(v, tid);
    if (tid < NBKT) pb2[tid] = incl - v;
}
__global__ __launch_bounds__(256) void k_ms_scan_add(const int* __restrict__ C,
                                                     const int* __restrict__ pb2,
                                                     int* __restrict__ O) {
    int tid = threadIdx.x;
    int v = (tid < NB1) ? C[blockIdx.x * NB1 + tid] : 0;
    int incl = block_incl_scan(v, tid);
    if (tid < NB1) O[blockIdx.x * NB1 + tid] = pb2[blockIdx.x] + incl - v;
}
// pass 1c: write packed (src_local<<16 | dst) bucket-major; per-(bucket,block)
// runs contiguous so each 64B line is completed by one block (one XCD).
__global__ __launch_bounds__(256) void k_ms_scatter(const int* __restrict__ esrc,
                                                    const int* __restrict__ edst,
                                                    const int* __restrict__ O,
                                                    u32* __restrict__ pk) {
    __shared__ int cur[NBKT];
    int tid = threadIdx.x, blk = blockIdx.x;
    if (tid < NBKT) cur[tid] = O[tid * NB1 + blk];
    __syncthreads();
    const int4* s4 = (const int4*)(esrc + blk * CHUNK);
    const int4* d4 = (const int4*)(edst + blk * CHUNK);
    for (int i = tid; i < CHUNK / 4; i += 256) {
        int4 s = s4[i], d = d4[i];
        int pos;
        pos = atomicAdd(&cur[s.x >> 8], 1); pk[pos] = ((u32)(s.x & 255) << 16) | (u32)d.x;
        pos = atomicAdd(&cur[s.y >> 8], 1); pk[pos] = ((u32)(s.y & 255) << 16) | (u32)d.y;
        pos = atomicAdd(&cur[s.z >> 8], 1); pk[pos] = ((u32)(s.z & 255) << 16) | (u32)d.z;
        pos = atomicAdd(&cur[s.w >> 8], 1); pk[pos] = ((u32)(s.w & 255) << 16) | (u32)d.w;
    }
}
// fused pass 2: per-bucket LDS histogram -> rowptr + dinv + CSR scatter (u16 dst).
__global__ __launch_bounds__(256) void k_bucket(const int* __restrict__ Om,
                                                const u32* __restrict__ pk,
                                                int* __restrict__ rowptr,
                                                float* __restrict__ dinv,
                                                u16* __restrict__ edst_s) {
    __shared__ int cnt[256];
    __shared__ int curs[256];
    int tid = threadIdx.x, b = blockIdx.x;
    int base = b * 256;
    int start = Om[b * NB1];
    int end = (b == NBKT - 1) ? N_EDGES : Om[(b + 1) * NB1];
    cnt[tid] = 0;
    __syncthreads();
    for (int p = start + tid; p < end; p += 256)
        atomicAdd(&cnt[pk[p] >> 16], 1);
    __syncthreads();
    int c = cnt[tid];
    int incl = block_incl_scan(c, tid);
    int excl = incl - c;
    int node = base + tid;
    if (node < N_NODES) {
        rowptr[node] = start + excl;
        dinv[node] = (c > 0) ? (1.f / sqrtf((float)c)) : 0.f;
    }
    if (b == NBKT - 1 && tid == 0) rowptr[N_NODES] = N_EDGES;
    curs[tid] = start + excl;
    __syncthreads();
    for (int p = start + tid; p < end; p += 256) {
        u32 pr = pk[p];
        int pos = atomicAdd(&curs[pr >> 16], 1);
        edst_s[pos] = (u16)(pr & 0xFFFFu);
    }
}

// ---------------- bf16 MFMA GEMM: out = epilogue(A @ Bt^T) ----------------
// global_load_lds width=16 staging (linear LDS dest, XOR-pre-swizzled global
// source col; reads use the matching XOR). XCD-swizzled 1D grid: the 4 tn-blocks
// sharing an A-panel run consecutively on ONE XCD.
template<int EPI>
__global__ __launch_bounds__(256) void k_gemm(const u16* __restrict__ A,
                                              const u16* __restrict__ Bt,
                                              u16* __restrict__ outB,
                                              const float* __restrict__ bias,
                                              const float* __restrict__ bn_g,
                                              const float* __restrict__ bn_b,
                                              const float* __restrict__ bn_mean,
                                              const float* __restrict__ bn_var) {
    __shared__ u16 lds[2 * 128 * 64];  // 32 KB: A tile then B tile
    char* ldsA = (char*)lds;
    char* ldsB = (char*)lds + 16384;

    const int bid = blockIdx.x;
    const int xcd = bid & 7;
    const int j = bid >> 3;              // 0..195
    const int tm = xcd * 49 + (j >> 2);
    const int tn = j & 3;
    if (tm >= MPAD / 128) return;

    const int tid = threadIdx.x;
    const int l = tid & 63, wid = tid >> 6;
    const int wr = wid >> 1, wc = wid & 1;
    const int lm = l & 15, lk = l >> 4;

    const int srow = tid >> 3;             // staging row base (0..31)
    const int kq   = tid & 7;              // 16B chunk slot in 128B stripe

    f32x4 acc[4][4] = {};

    for (int kt = 0; kt < 8; ++kt) {
        const int k0 = kt * 64;
        #pragma unroll
        for (int r = 0; r < 4; ++r) {
            int row = r * 32 + srow;
            int kc = (kq ^ (row & 7)) * 8;       // pre-swizzled source col (elems)
            const u16* ga = A + ((long)tm * 128 + row) * DIM + k0 + kc;
            const u16* gb = Bt + ((long)tn * 128 + row) * DIM + k0 + kc;
            char* la = ldsA + r * 4096 + wid * 1024;   // wave-uniform base
            char* lb = ldsB + r * 4096 + wid * 1024;
            gload16(ga, la);
            gload16(gb, lb);
        }
        __syncthreads();
        #pragma unroll
        for (int kk = 0; kk < 2; ++kk) {
            bf16x8 af[4], bfr[4];
            #pragma unroll
            for (int m = 0; m < 4; ++m) {
                int ar = wr * 64 + m * 16 + lm;
                af[m] = *(const bf16x8*)(ldsA + ar * 128 + ((kk * 64 + lk * 16) ^ ((ar & 7) << 4)));
            }
            #pragma unroll
            for (int n = 0; n < 4; ++n) {
                int br = wc * 64 + n * 16 + lm;
                bfr[n] = *(const bf16x8*)(ldsB + br * 128 + ((kk * 64 + lk * 16) ^ ((br & 7) << 4)));
            }
            #pragma unroll
            for (int m = 0; m < 4; ++m)
                #pragma unroll
                for (int n = 0; n < 4; ++n)
                    acc[m][n] = __builtin_amdgcn_mfma_f32_16x16x32_bf16(af[m], bfr[n], acc[m][n], 0, 0, 0);
        }
        __syncthreads();
    }

    #pragma unroll
    for (int n = 0; n < 4; ++n) {
        int col = tn * 128 + wc * 64 + n * 16 + lm;
        float bc = bias[col];
        float scale = 0.f, shift = 0.f;
        if (EPI == 1) {
            scale = bn_g[col] / sqrtf(bn_var[col] + 1e-5f);
            shift = bn_b[col] - bn_mean[col] * scale;
        }
        #pragma unroll
        for (int m = 0; m < 4; ++m) {
            f32x4 v = acc[m][n];
            #pragma unroll
            for (int r = 0; r < 4; ++r) {
                long row = (long)tm * 128 + wr * 64 + m * 16 + lk * 4 + r;
                float val = fmaxf(v[r] + bc, 0.f);
                if (EPI == 1) val = val * scale + shift;
                outB[row * DIM + col] = f2bf(val);
            }
        }
    }
}

// ---------------- LayerNorm (in-place on hb) + int4 quant + nd pack ----------------
// nd[row] = {na0, na1, dinv, stepr} where na = a * invn.
__global__ __launch_bounds__(256) void k_ln(u16* __restrict__ hb,
                                            char* __restrict__ hq,
                                            const float* __restrict__ dinv,
                                            const float* __restrict__ g,
                                            const float* __restrict__ b,
                                            float* __restrict__ a0,
                                            float* __restrict__ a1,
                                            float* __restrict__ inv_nrm,
                                            float4* __restrict__ nd) {
    int row = blockIdx.x * 4 + (threadIdx.x >> 6);
    int l = threadIdx.x & 63;
    u16* prow = hb + (long)row * DIM + l * 8;
    if (row >= N_NODES) {
        if (row < MPAD) { uint4 z; z.x = z.y = z.z = z.w = 0u; *(uint4*)prow = z; }
        return;
    }
    uint4 v = *(const uint4*)prow;
    float x[8];
    { float2 p;
      p = bfpair(v.x); x[0] = p.x; x[1] = p.y;
      p = bfpair(v.y); x[2] = p.x; x[3] = p.y;
      p = bfpair(v.z); x[4] = p.x; x[5] = p.y;
      p = bfpair(v.w); x[6] = p.x; x[7] = p.y; }
    float s = 0.f, sq = 0.f;
    #pragma unroll
    for (int j = 0; j < 8; ++j) { s += x[j]; sq += x[j] * x[j]; }
    #pragma unroll
    for (int o = 32; o > 0; o >>= 1) { s += __shfl_xor(s, o); sq += __shfl_xor(sq, o); }
    float mean = s * (1.f / DIM);
    float var = sq * (1.f / DIM) - mean * mean;
    float rstd = 1.f / sqrtf(var + 1e-5f);
    float y[8];
    #pragma unroll
    for (int j = 0; j < 8; ++j) {
        int c = l * 8 + j;
        y[j] = (x[j] - mean) * rstd * g[c] + b[c];
    }
    float s2 = 0.f;
    #pragma unroll
    for (int j = 0; j < 8; ++j) s2 += y[j] * y[j];
    s2 = wave_sum(s2);
    float nrm = sqrtf(s2);
    float inv = 1.f / (nrm + 1e-4f);
    // write LN output (bf16) for GEMM2
    ushort4 oh;
    oh.x = f2bf(y[0]); oh.y = f2bf(y[1]); oh.z = f2bf(y[2]); oh.w = f2bf(y[3]);
    *(ushort4*)prow = oh;
    oh.x = f2bf(y[4]); oh.y = f2bf(y[5]); oh.z = f2bf(y[6]); oh.w = f2bf(y[7]);
    *(ushort4*)(prow + 4) = oh;
    // quantize normalized row to int4 with per-row scale
    float nv[8];
    float mx = 0.f;
    #pragma unroll
    for (int j = 0; j < 8; ++j) { nv[j] = y[j] * inv; mx = fmaxf(mx, fabsf(nv[j])); }
    mx = wave_max(mx);
    float qs = (mx > 0.f) ? (7.f / mx) : 0.f;
    if (l == 0) { nv[0] = 0.f; nv[1] = 0.f; }   // exclude dims 0,1 from rest
    u32 w = 0;
    #pragma unroll
    for (int j = 0; j < 8; ++j) {
        int q = (int)rintf(nv[j] * qs);
        w |= ((u32)(q & 0xF)) << (4 * j);
    }
    *(u32*)(hq + (long)row * QROW + l * 4) = w;
    if (l == 0) {
        float st = (mx > 0.f) ? (mx * (1.f / 7.f)) : 0.f;
        a0[row] = y[0]; a1[row] = y[1]; inv_nrm[row] = inv;
        float4 n4; n4.x = y[0] * inv; n4.y = y[1] * inv; n4.z = dinv[row]; n4.w = st;
        nd[row] = n4;
    }
}

// ---------------- fused: per-edge partial dot (int4) + LAYER-1 seg-sum + rotate ----
// wave per src node; 8 edges per iteration, 8 lanes per edge. Writes rest[] (bf16)
// for layers 2,3 AND computes layer-1's delta/rotation inline.
__global__ __launch_bounds__(256) void k_edge_dot(const int* __restrict__ rowptr,
                                                  const u16* __restrict__ edst_s,
                                                  const char* __restrict__ hq,
                                                  const float4* __restrict__ ndI,
                                                  const float* __restrict__ a0i,
                                                  const float* __restrict__ a1i,
                                                  const float* __restrict__ invn,
                                                  u16* __restrict__ rest,
                                                  float* __restrict__ a0o,
                                                  float* __restrict__ a1o,
                                                  float4* __restrict__ ndO) {
    int node = blockIdx.x * 4 + (threadIdx.x >> 6);
    if (node >= N_NODES) return;
    int l = threadIdx.x & 63;
    int le = l & 7;         // lane within edge group
    int eg = l >> 3;        // edge slot 0..7
    int p0 = rowptr[node], p1 = rowptr[node + 1];
    float4 own = ndI[node];                   // {na0, na1, dinv, stepr}
    float xa = a0i[node], ya = a1i[node];
    if (p0 == p1) {
        if (l == 0) { a0o[node] = xa; a1o[node] = ya; ndO[node] = own; }
        return;
    }
    const int4* srow = (const int4*)(hq + (long)node * QROW);
    int4 s0 = srow[le * 2], s1 = srow[le * 2 + 1];
    float ss = own.w;
    float sa0 = own.x, sa1 = own.y;
    float accum = 0.f;
    #pragma unroll 4
    for (int base = p0; base < p1; base += 8) {
        int p = base + eg;
        bool ok = p < p1;
        int d = ok ? (int)edst_s[p] : 0;
        const int4* drow = (const int4*)(hq + (long)d * QROW);
        int4 d0 = drow[le * 2], d1 = drow[le * 2 + 1];
        int acc = 0;
        acc = dot8(s0.x, d0.x, acc); acc = dot8(s0.y, d0.y, acc);
        acc = dot8(s0.z, d0.z, acc); acc = dot8(s0.w, d0.w, acc);
        acc = dot8(s1.x, d1.x, acc); acc = dot8(s1.y, d1.y, acc);
        acc = dot8(s1.z, d1.z, acc); acc = dot8(s1.w, d1.w, acc);
        acc += __shfl_xor(acc, 4);
        acc += __shfl_xor(acc, 2);
        acc += __shfl_xor(acc, 1);
        if (ok && le == 0) {
            float4 ndd = ndI[d];
            float r = ss * ndd.w * (float)acc;
            rest[p] = f2bf(r);
            float c = r + sa0 * ndd.x + sa1 * ndd.y;
            c = fminf(1.f, fmaxf(-1.f, c));
            accum += ndd.z * c;
        }
    }
    accum = wave_sum(accum);
    if (l == 0) {
        float ang = own.z * accum;
        float sn, cs;
        sincosf(ang, &sn, &cs);
        float r0 = cs * xa - sn * ya;
        float r1 = sn * xa + cs * ya;
        a0o[node] = r0;
        a1o[node] = r1;
        float inv = invn[node];
        float4 n4; n4.x = r0 * inv; n4.y = r1 * inv; n4.z = own.z; n4.w = own.w;
        ndO[node] = n4;
    }
}

// ---------------- fused per-layer: segment-sum + rotate (layers 2,3) ----------------
// WRITE_HB=1 (last layer): writes hb, skips nd/a out.
template<int WRITE_HB>
__global__ __launch_bounds__(256) void k_layer(const int* __restrict__ rowptr,
                                               const u16* __restrict__ edst_s,
                                               const u16* __restrict__ rest,
                                               const float4* __restrict__ ndI,
                                               const float* __restrict__ a0i,
                                               const float* __restrict__ a1i,
                                               const float* __restrict__ invn,
                                               float* __restrict__ a0o,
                                               float* __restrict__ a1o,
                                               float4* __restrict__ ndO,
                                               u16* __restrict__ hb) {
    int node = blockIdx.x * 4 + (threadIdx.x >> 6);
    if (node >= N_NODES) return;
    int l = threadIdx.x & 63;
    int p0 = rowptr[node], p1 = rowptr[node + 1];
    float4 own = ndI[node];
    float x = a0i[node], y = a1i[node];
    float sa0 = own.x, sa1 = own.y;
    float accum = 0.f;
    for (int p = p0 + l; p < p1; p += 64) {
        int d = (int)edst_s[p];
        float4 ndd = ndI[d];
        float c = bf2f(rest[p]) + sa0 * ndd.x + sa1 * ndd.y;
        c = fminf(1.f, fmaxf(-1.f, c));
        accum += ndd.z * c;
    }
    accum = wave_sum(accum);
    if (l == 0) {
        float ang = own.z * accum;
        float sn, cs;
        sincosf(ang, &sn, &cs);
        float r0 = cs * x - sn * y;
        float r1 = sn * x + cs * y;
        if (WRITE_HB) {
            hb[(long)node * DIM + 0] = f2bf(r0);
            hb[(long)node * DIM + 1] = f2bf(r1);
        } else {
            a0o[node] = r0;
            a1o[node] = r1;
            float inv = invn[node];
            float4 n4; n4.x = r0 * inv; n4.y = r1 * inv; n4.z = own.z; n4.w = own.w;
            ndO[node] = n4;
        }
    }
}

// ---------------- final: logits (MFMA skinny GEMM) + log_softmax ----------------
__global__ __launch_bounds__(256) void k_final(const u16* __restrict__ zb,
                                               const u16* __restrict__ W2b,
                                               const float* __restrict__ cb2,
                                               float* __restrict__ out) {
    __shared__ char ldsB[48 * 1024];   // 48 KB, XOR-swizzled rows
    const int tid = threadIdx.x;
    #pragma unroll
    for (int i = 0; i < 12; ++i) {
        int unit = i * 256 + tid;          // 3072 x 16B units
        int byte = unit * 16;
        int row = byte >> 10;
        int colb = byte & 1023;
        uint4 v = *(const uint4*)((const char*)W2b + byte);
        *(uint4*)(ldsB + row * 1024 + (colb ^ ((row & 7) << 4))) = v;
    }
    __syncthreads();

    const int l = tid & 63, wid = tid >> 6;
    const int lm = l & 15, lk = l >> 4;
    const long m0 = (long)blockIdx.x * 128 + wid * 32;

    f32x4 acc[2][3] = {};
    for (int kt = 0; kt < 16; ++kt) {
        const int k0 = kt * 32;
        bf16x8 af[2], bfr[3];
        #pragma unroll
        for (int m = 0; m < 2; ++m)
            af[m] = *(const bf16x8*)(zb + (m0 + m * 16 + lm) * DIM + k0 + lk * 8);
        #pragma unroll
        for (int n = 0; n < 3; ++n) {
            int br = n * 16 + lm;
            bfr[n] = *(const bf16x8*)(ldsB + br * 1024 + ((k0 * 2 + lk * 16) ^ ((br & 7) << 4)));
        }
        #pragma unroll
        for (int m = 0; m < 2; ++m)
            #pragma unroll
            for (int n = 0; n < 3; ++n)
                acc[m][n] = __builtin_amdgcn_mfma_f32_16x16x32_bf16(af[m], bfr[n], acc[m][n], 0, 0, 0);
    }

    float bc[3];
    #pragma unroll
    for (int n = 0; n < 3; ++n) {
        int col = n * 16 + lm;
        bc[n] = (col < DOUT) ? cb2[col] : 0.f;
    }

    #pragma unroll
    for (int m = 0; m < 2; ++m) {
        #pragma unroll
        for (int r = 0; r < 4; ++r) {
            long row = m0 + m * 16 + lk * 4 + r;
            float v[3];
            float mv = -1e30f;
            #pragma unroll
            for (int n = 0; n < 3; ++n) {
                int col = n * 16 + lm;
                float t = (col < DOUT) ? (acc[m][n][r] + bc[n]) : -1e30f;
                v[n] = t;
                mv = fmaxf(mv, t);
            }
            #pragma unroll
            for (int o = 8; o > 0; o >>= 1) mv = fmaxf(mv, __shfl_xor(mv, o));
            float es = 0.f;
            #pragma unroll
            for (int n = 0; n < 3; ++n) {
                int col = n * 16 + lm;
                if (col < DOUT) es += expf(v[n] - mv);
            }
            #pragma unroll
            for (int o = 8; o > 0; o >>= 1) es += __shfl_xor(es, o);
            float lse = logf(es);
            if (row < N_NODES) {
                #pragma unroll
                for (int n = 0; n < 3; ++n) {
                    int col = n * 16 + lm;
                    if (col < DOUT) out[row * DOUT + col] = v[n] - mv - lse;
                }
            }
        }
    }
}

extern "C" void kernel_launch(void* const* d_in, const int* in_sizes, int n_in,
                              void* d_out, int out_size, void* d_ws, size_t ws_size,
                              hipStream_t stream) {
    const float* x       = (const float*)d_in[0];
    const int*   esrc    = (const int*)d_in[1];
    const int*   edst    = (const int*)d_in[2];
    const float* W_in    = (const float*)d_in[3];
    const float* b_in    = (const float*)d_in[4];
    const float* ln_g    = (const float*)d_in[5];
    const float* ln_b    = (const float*)d_in[6];
    const float* cW1     = (const float*)d_in[7];
    const float* cb1     = (const float*)d_in[8];
    const float* bn_g    = (const float*)d_in[9];
    const float* bn_b    = (const float*)d_in[10];
    const float* bn_mean = (const float*)d_in[11];
    const float* bn_var  = (const float*)d_in[12];
    const float* cW2     = (const float*)d_in[13];
    const float* cb2     = (const float*)d_in[14];
    float* out = (float*)d_out;

    char* ws = (char*)d_ws;
    size_t off = 0;
    auto take = [&](size_t bytes) -> char* {
        char* p = ws + off;
        off = (off + bytes + 255) & ~(size_t)255;
        return p;
    };
    u16*    xb     = (u16*)take((size_t)MPAD * DIM * 2);   // reused as zb
    u16*    hb     = (u16*)take((size_t)MPAD * DIM * 2);
    char*   hq     = (char*)take((size_t)N_NODES * QROW);
    u16*    WtIn   = (u16*)take((size_t)512 * 512 * 2);
    u16*    W1t    = (u16*)take((size_t)512 * 512 * 2);
    u16*    W2b    = (u16*)take((size_t)48 * 512 * 2);
    float*  dinv   = (float*)take((size_t)N_NODES * 4);
    float*  a0A    = (float*)take((size_t)N_NODES * 4);
    float*  a1A    = (float*)take((size_t)N_NODES * 4);
    float*  a0B    = (float*)take((size_t)N_NODES * 4);
    float*  a1B    = (float*)take((size_t)N_NODES * 4);
    float*  invn   = (float*)take((size_t)N_NODES * 4);
    float4* ndA    = (float4*)take((size_t)N_NODES * 16);
    float4* ndB    = (float4*)take((size_t)N_NODES * 16);
    u16*    rest   = (u16*)take((size_t)N_EDGES * 2);
    int*    rowptr = (int*)take((size_t)(N_NODES + 1) * 4);
    u16*    edst_s = (u16*)take((size_t)N_EDGES * 2);
    u32*    pk     = (u32*)take((size_t)N_EDGES * 4);
    int*    Cm     = (int*)take((size_t)NBKT * NB1 * 4);
    int*    Om     = (int*)take((size_t)NBKT * NB1 * 4);
    int*    psum2  = (int*)take((size_t)NBKT * 4);
    int*    pb2    = (int*)take((size_t)NBKT * 4);
    u16*    zb     = xb;

    k_prep<<<CONV_BLKS + 2048 + 96, 256, 0, stream>>>(x, xb, W_in, cW1, cW2,
                                                      WtIn, W1t, W2b);

    // multisplit CSR build (no global atomics anywhere)
    k_ms_count<<<NB1, 256, 0, stream>>>(esrc, Cm);
    k_ms_scan_partial<<<NBKT, 256, 0, stream>>>(Cm, psum2);
    k_ms_scan_base<<<1, 256, 0, stream>>>(psum2, pb2);
    k_ms_scan_add<<<NBKT, 256, 0, stream>>>(Cm, pb2, Om);
    k_ms_scatter<<<NB1, 256, 0, stream>>>(esrc, edst, Om, pk);
    k_bucket<<<NBKT, 256, 0, stream>>>(Om, pk, rowptr, dinv, edst_s);

    k_gemm<0><<<1568, 256, 0, stream>>>(xb, WtIn, hb, b_in,
                                        nullptr, nullptr, nullptr, nullptr);
    k_ln<<<MPAD / 4, 256, 0, stream>>>(hb, hq, dinv, ln_g, ln_b, a0A, a1A, invn, ndA);
    // edge dot + layer 1 fused: ndA -> ndB
    k_edge_dot<<<(N_NODES + 3) / 4, 256, 0, stream>>>(rowptr, edst_s, hq, ndA,
                                                      a0A, a1A, invn, rest, a0B, a1B, ndB);
    // layer 2: ndB -> ndA ; layer 3: ndA -> hb
    k_layer<0><<<(N_NODES + 3) / 4, 256, 0, stream>>>(rowptr, edst_s, rest, ndB,
                                                      a0B, a1B, invn, a0A, a1A, ndA, nullptr);
    k_layer<1><<<(N_NODES + 3) / 4, 256, 0, stream>>>(rowptr, edst_s, rest, ndA,
                                                      a0A, a1A, invn, nullptr, nullptr, nullptr, hb);

    k_gemm<1><<<1568, 256, 0, stream>>>(hb, W1t, zb, cb1,
                                        bn_g, bn_b, bn_mean, bn_var);
    k_final<<<MPAD / 128, 256, 0, stream>>>(zb, W2b, cb2, out);
}